// Round 2
// baseline (11878.323 us; speedup 1.0000x reference)
//
#include <hip/hip_runtime.h>
#include <math.h>

#define NN 50000
#define EE 800000
#define GG 256

typedef unsigned short u16;
typedef unsigned int u32;

__device__ __forceinline__ float elu_f(float x) { return x > 0.f ? x : expm1f(x); }

__device__ __forceinline__ unsigned fenc(float f) {
  unsigned b = __float_as_uint(f);
  return (b & 0x80000000u) ? ~b : (b | 0x80000000u);
}
__device__ __forceinline__ float fdec(unsigned u) {
  return __uint_as_float((u & 0x80000000u) ? (u ^ 0x80000000u) : ~u);
}
__device__ __forceinline__ float b2f(u16 u) { return __uint_as_float(((u32)u) << 16); }
__device__ __forceinline__ u16 f2b(float f) {
  u32 u = __float_as_uint(f);
  u32 r = (u + 0x7fffu + ((u >> 16) & 1u)) >> 16;
  return (u16)r;
}
__device__ __forceinline__ float lo2f(u32 p) { return __uint_as_float(p << 16); }
__device__ __forceinline__ float hi2f(u32 p) { return __uint_as_float(p & 0xffff0000u); }

__device__ __forceinline__ float wred64(float v) {
#pragma unroll
  for (int m = 32; m; m >>= 1) v += __shfl_xor(v, m, 64);
  return v;
}

// ---------------- generic tiled GEMM: C = act(A[M,K]@B[K,N] + bias (+C)) ----------------
// obf=1 -> C region holds u16 bf16 outputs (no accum allowed with obf).
__global__ __launch_bounds__(256) void gemm_kernel(
    const float* __restrict__ A, const float* __restrict__ B,
    const float* __restrict__ bias, float* __restrict__ C,
    int M, int Nn, int K, int act, int accum, int obf) {
  __shared__ float As[16][68];
  __shared__ float Bs[16][68];
  const int bm = blockIdx.y * 64;
  const int bn = blockIdx.x * 64;
  const int tid = threadIdx.x;
  const int tx = tid & 15, ty = tid >> 4;
  const int lr = tid >> 2;        // 0..63  (A row within tile)
  const int lk = (tid & 3) << 2;  // 0,4,8,12 (A k-offset)
  float acc[4][4] = {};
  for (int k0 = 0; k0 < K; k0 += 16) {
    int arow = bm + lr;
    float4 a4 = {0.f, 0.f, 0.f, 0.f};
    if (arow < M) a4 = *reinterpret_cast<const float4*>(A + (size_t)arow * K + k0 + lk);
    As[lk + 0][lr] = a4.x; As[lk + 1][lr] = a4.y;
    As[lk + 2][lr] = a4.z; As[lk + 3][lr] = a4.w;
    float4 b4 = *reinterpret_cast<const float4*>(B + (size_t)(k0 + ty) * Nn + bn + tx * 4);
    *reinterpret_cast<float4*>(&Bs[ty][tx * 4]) = b4;
    __syncthreads();
#pragma unroll
    for (int kk = 0; kk < 16; ++kk) {
      float4 av = *reinterpret_cast<const float4*>(&As[kk][ty * 4]);
      float4 bv = *reinterpret_cast<const float4*>(&Bs[kk][tx * 4]);
      float a_[4] = {av.x, av.y, av.z, av.w};
      float b_[4] = {bv.x, bv.y, bv.z, bv.w};
#pragma unroll
      for (int ii = 0; ii < 4; ++ii)
#pragma unroll
        for (int jj = 0; jj < 4; ++jj)
          acc[ii][jj] = fmaf(a_[ii], b_[jj], acc[ii][jj]);
    }
    __syncthreads();
  }
#pragma unroll
  for (int ii = 0; ii < 4; ++ii) {
    int row = bm + ty * 4 + ii;
    if (row < M) {
#pragma unroll
      for (int jj = 0; jj < 4; ++jj) {
        int col = bn + tx * 4 + jj;
        float val = acc[ii][jj];
        if (bias) val += bias[col];
        if (accum) val += C[(size_t)row * Nn + col];
        if (act) val = elu_f(val);
        if (obf) ((u16*)C)[(size_t)row * Nn + col] = f2b(val);
        else C[(size_t)row * Nn + col] = val;
      }
    }
  }
}

// ---------------- graph LayerNorm ----------------
__global__ __launch_bounds__(256) void ln_stats(const float* __restrict__ h,
                                                const int* __restrict__ batch,
                                                float* __restrict__ gstat) {
  int w = (blockIdx.x * blockDim.x + threadIdx.x) >> 6;
  if (w >= NN) return;
  int lane = threadIdx.x & 63;
  float x0 = h[(size_t)w * 128 + lane], x1 = h[(size_t)w * 128 + 64 + lane];
  float s = wred64(x0 + x1);
  float ss = wred64(x0 * x0 + x1 * x1);
  if (lane == 0) {
    int g = batch[w];
    atomicAdd(&gstat[g], 1.0f);
    atomicAdd(&gstat[GG + g], s);
    atomicAdd(&gstat[2 * GG + g], ss);
  }
}

__global__ void ln_final(const float* __restrict__ gstat, float* __restrict__ gmean,
                         float* __restrict__ grstd) {
  int t = threadIdx.x;
  if (t < GG) {
    float cnt = fmaxf(gstat[t] * 128.f, 1.0f);
    float mean = gstat[GG + t] / cnt;
    float var = fmaxf(gstat[2 * GG + t] / cnt - mean * mean, 0.f);
    gmean[t] = mean;
    grstd[t] = rsqrtf(var + 1e-5f);
  }
}

__global__ __launch_bounds__(256) void ln_apply(const float* __restrict__ in, float* __restrict__ out,
                                                const int* __restrict__ batch,
                                                const float* __restrict__ gmean,
                                                const float* __restrict__ grstd,
                                                const float* __restrict__ gamma,
                                                const float* __restrict__ beta) {
  int idx = blockIdx.x * blockDim.x + threadIdx.x;  // one float4 each
  if (idx >= NN * 32) return;
  int n = idx >> 5, c4 = (idx & 31) * 4;
  int g = batch[n];
  float mean = gmean[g], rstd = grstd[g];
  float4 xv = *reinterpret_cast<const float4*>(in + (size_t)n * 128 + c4);
  float4 gv = *reinterpret_cast<const float4*>(gamma + c4);
  float4 bv = *reinterpret_cast<const float4*>(beta + c4);
  float4 ov;
  ov.x = elu_f((xv.x - mean) * rstd * gv.x + bv.x);
  ov.y = elu_f((xv.y - mean) * rstd * gv.y + bv.y);
  ov.z = elu_f((xv.z - mean) * rstd * gv.z + bv.z);
  ov.w = elu_f((xv.w - mean) * rstd * gv.w + bv.w);
  *reinterpret_cast<float4*>(out + (size_t)n * 128 + c4) = ov;
}

// ---------------- per-layer weight transforms ----------------
// BD[h*64+j, c] = we[j, c] if head(c)==h else 0   (for hn += r @ BD)
__global__ void build_bd(const float* __restrict__ we, float* __restrict__ BD) {
  int idx = blockIdx.x * blockDim.x + threadIdx.x;
  if (idx >= 128 * 128) return;
  int rr = idx >> 7, cc = idx & 127;
  BD[idx] = ((rr >> 6) == (cc >> 6)) ? we[(rr & 63) * 128 + cc] : 0.f;
}

// WQE[row, h*64+j] = sum_c wq[row, h*64+c] * we[j, h*64+c]; row==128 writes bqe from bq.
__global__ void build_wqe(const float* __restrict__ wq, const float* __restrict__ bq,
                          const float* __restrict__ we, float* __restrict__ WQE,
                          float* __restrict__ bqe) {
  int col = threadIdx.x;  // 0..127
  int row = blockIdx.x;   // 0..128
  int hh = col >> 6, j = col & 63;
  const float* wrow = (row < 128) ? (wq + (size_t)row * 128) : bq;
  float acc = 0.f;
  for (int c = 0; c < 64; ++c) acc += wrow[hh * 64 + c] * we[(size_t)j * 128 + hh * 64 + c];
  if (row < 128) WQE[(size_t)row * 128 + col] = acc;
  else bqe[col] = acc;
}

// ---------------- attention ----------------
__global__ __launch_bounds__(256) void attn_logits(const u16* __restrict__ q,
                                                   const u16* __restrict__ k,
                                                   const u16* __restrict__ qe,
                                                   const u16* __restrict__ ea,
                                                   const int* __restrict__ src,
                                                   const int* __restrict__ dst,
                                                   float* __restrict__ alpha,
                                                   unsigned* __restrict__ mnode) {
  int e = (blockIdx.x * blockDim.x + threadIdx.x) >> 6;
  if (e >= EE) return;
  int lane = threadIdx.x & 63;
  int s = src[e], d = dst[e];
  u32 qv = ((const u32*)(q + (size_t)d * 128))[lane];
  u32 kv = ((const u32*)(k + (size_t)s * 128))[lane];
  u32 qev = ((const u32*)(qe + (size_t)d * 128))[lane];
  u32 eav = ((const u32*)(ea + (size_t)e * 64))[lane & 31];
  float p = lo2f(qv) * lo2f(kv) + hi2f(qv) * hi2f(kv) +
            lo2f(qev) * lo2f(eav) + hi2f(qev) * hi2f(eav);
#pragma unroll
  for (int m = 16; m; m >>= 1) p += __shfl_xor(p, m, 64);  // reduce within 32-lane halves
  if ((lane & 31) == 0) {
    int hh = lane >> 5;
    float l = p * 0.125f;  // / sqrt(64)
    alpha[(size_t)e * 2 + hh] = l;
    atomicMax(&mnode[d * 2 + hh], fenc(l));
  }
}

__global__ __launch_bounds__(256) void attn_expsum(float* __restrict__ alpha,
                                                   const int* __restrict__ dst,
                                                   const unsigned* __restrict__ mnode,
                                                   float* __restrict__ snode) {
  int idx = blockIdx.x * blockDim.x + threadIdx.x;
  if (idx >= 2 * EE) return;
  int e = idx >> 1, hh = idx & 1;
  int d = dst[e];
  float p = expf(alpha[idx] - fdec(mnode[d * 2 + hh]));
  alpha[idx] = p;
  atomicAdd(&snode[d * 2 + hh], p);
}

__global__ __launch_bounds__(256) void attn_scatter(const float* __restrict__ alpha,
                                                    const float* __restrict__ snode,
                                                    const u16* __restrict__ v,
                                                    const u16* __restrict__ ea,
                                                    const int* __restrict__ src,
                                                    const int* __restrict__ dst,
                                                    float* __restrict__ hn,
                                                    float* __restrict__ r) {
  int e = (blockIdx.x * blockDim.x + threadIdx.x) >> 6;
  if (e >= EE) return;
  int lane = threadIdx.x & 63;
  int s = src[e], d = dst[e];
  int hh = lane >> 5;
  float w = alpha[(size_t)e * 2 + hh] / snode[d * 2 + hh];
  u32 vv = ((const u32*)(v + (size_t)s * 128))[lane];
  u32 eav = ((const u32*)(ea + (size_t)e * 64))[lane & 31];
  int c = lane * 2;
  atomicAdd(&hn[(size_t)d * 128 + c], w * lo2f(vv));
  atomicAdd(&hn[(size_t)d * 128 + c + 1], w * hi2f(vv));
  atomicAdd(&r[(size_t)d * 128 + c], w * lo2f(eav));
  atomicAdd(&r[(size_t)d * 128 + c + 1], w * hi2f(eav));
}

// ---------------- edge MLP update (bf16 in/out); optional per-graph pre-elu sum ----------------
__global__ __launch_bounds__(256) void ea_update(u16* __restrict__ ea,
                                                 const float* __restrict__ up,
                                                 const float* __restrict__ ub,
                                                 const int* __restrict__ src,
                                                 const int* __restrict__ batch,
                                                 float* __restrict__ gsum_e, int emb_flag) {
  int lane = threadIdx.x & 63;
  float upc[64];
#pragma unroll
  for (int j = 0; j < 64; ++j) upc[j] = up[j * 64 + lane];
  float bl = ub[lane];
  int wg = (blockIdx.x * blockDim.x + threadIdx.x) >> 6;
  int nw = (gridDim.x * blockDim.x) >> 6;
  for (int e = wg; e < EE; e += nw) {
    float x = b2f(ea[(size_t)e * 64 + lane]);
    float acc = bl;
#pragma unroll
    for (int j = 0; j < 64; ++j) acc = fmaf(__shfl(x, j, 64), upc[j], acc);
    if (emb_flag) atomicAdd(&gsum_e[(size_t)batch[src[e]] * 64 + lane], acc);
    ea[(size_t)e * 64 + lane] = f2b(elu_f(acc));
  }
}

// ---------------- SAG pooling ----------------
__global__ __launch_bounds__(256) void aggr_scatter(const float* __restrict__ h,
                                                    const int* __restrict__ src,
                                                    const int* __restrict__ dst,
                                                    float* __restrict__ aggr) {
  int e = (blockIdx.x * blockDim.x + threadIdx.x) >> 6;
  if (e >= EE) return;
  int lane = threadIdx.x & 63;
  int s = src[e], d = dst[e];
  float2 hv = ((const float2*)(h + (size_t)s * 128))[lane];
  atomicAdd(&aggr[(size_t)d * 128 + lane * 2], hv.x);
  atomicAdd(&aggr[(size_t)d * 128 + lane * 2 + 1], hv.y);
}

__global__ __launch_bounds__(256) void sag_sc(const float* __restrict__ aggr,
                                              const float* __restrict__ h,
                                              const float* __restrict__ wrel,
                                              const float* __restrict__ brel,
                                              const float* __restrict__ wroot,
                                              const int* __restrict__ batch,
                                              float* __restrict__ sc, unsigned* __restrict__ gm) {
  int w = (blockIdx.x * blockDim.x + threadIdx.x) >> 6;
  if (w >= NN) return;
  int lane = threadIdx.x & 63;
  float t = aggr[(size_t)w * 128 + lane] * wrel[lane] +
            aggr[(size_t)w * 128 + 64 + lane] * wrel[64 + lane] +
            h[(size_t)w * 128 + lane] * wroot[lane] +
            h[(size_t)w * 128 + 64 + lane] * wroot[64 + lane];
  t = wred64(t);
  if (lane == 0) {
    float s = t + brel[0];
    sc[w] = s;
    atomicMax(&gm[batch[w]], fenc(s));
  }
}

__global__ __launch_bounds__(256) void sag_exp(const float* __restrict__ sc,
                                               const int* __restrict__ batch,
                                               const unsigned* __restrict__ gm,
                                               float* __restrict__ gs, float* __restrict__ scp) {
  int n = blockIdx.x * blockDim.x + threadIdx.x;
  if (n >= NN) return;
  int g = batch[n];
  float p = expf(sc[n] - fdec(gm[g]));
  scp[n] = p;
  atomicAdd(&gs[g], p);
}

__global__ __launch_bounds__(256) void sag_emb(const float* __restrict__ h,
                                               const float* __restrict__ scp,
                                               const float* __restrict__ gs,
                                               const int* __restrict__ batch,
                                               float* __restrict__ embtmp) {
  int n = (blockIdx.x * blockDim.x + threadIdx.x) >> 6;
  if (n >= NN) return;
  int lane = threadIdx.x & 63;
  int g = batch[n];
  float w = scp[n] / gs[g];
  float2 hv = ((const float2*)(h + (size_t)n * 128))[lane];
  atomicAdd(&embtmp[(size_t)g * 128 + lane * 2], hv.x * w);
  atomicAdd(&embtmp[(size_t)g * 128 + lane * 2 + 1], hv.y * w);
}

__global__ void emb_fin(const float* __restrict__ embtmp, const float* __restrict__ embE,
                        float* __restrict__ dst) {
  __shared__ float part[2];
  int g = blockIdx.x, c = threadIdx.x;
  float v = embtmp[(size_t)g * 128 + c] * embE[(size_t)g * 128 + c];
  float sq = wred64(v * v);
  if ((c & 63) == 0) part[c >> 6] = sq;
  __syncthreads();
  float nrm = sqrtf(part[0] + part[1]);
  float s = 1.f / fmaxf(nrm, 1e-12f);
  dst[(size_t)g * 128 + c] = elu_f(v * s);
}

__global__ void final_combine(const float* __restrict__ e0, const float* __restrict__ e1,
                              float* __restrict__ out) {
  int idx = blockIdx.x * blockDim.x + threadIdx.x;
  if (idx >= GG * 128) return;
  out[idx] = 0.6f * e0[idx] + 0.4f * e1[idx];
}

// =====================================================================
extern "C" void kernel_launch(void* const* d_in, const int* in_sizes, int n_in,
                              void* d_out, int out_size, void* d_ws, size_t ws_size,
                              hipStream_t stream) {
  const float* x = (const float*)d_in[0];
  const float* edge_attr = (const float*)d_in[1];
  const int* edge_index = (const int*)d_in[2];
  const int* batch = (const int*)d_in[3];
  const float* w0 = (const float*)d_in[4];
  const float* b0 = (const float*)d_in[5];
  const float* we0 = (const float*)d_in[6];
  const float* be0 = (const float*)d_in[7];
  const float* ln0_g = (const float*)d_in[8];
  const float* ln0_b = (const float*)d_in[9];
  const float* qkv_w = (const float*)d_in[10];
  const float* qkv_b = (const float*)d_in[11];
  const float* edge_w = (const float*)d_in[12];
  const float* skip_w = (const float*)d_in[13];
  const float* skip_b = (const float*)d_in[14];
  const float* up_w = (const float*)d_in[15];
  const float* up_b = (const float*)d_in[16];
  const float* ng = (const float*)d_in[17];
  const float* nbeta = (const float*)d_in[18];
  const float* sag_wrel = (const float*)d_in[19];
  const float* sag_brel = (const float*)d_in[20];
  const float* sag_wroot = (const float*)d_in[21];
  const float* re_w = (const float*)d_in[22];
  const float* re_b = (const float*)d_in[23];
  const int* srcp = edge_index;
  const int* dstp = edge_index + EE;
  float* out = (float*)d_out;
  (void)in_sizes; (void)n_in;

  float* ws = (float*)d_ws;
  size_t o = 0;
  auto alloc = [&](size_t n) { float* p = ws + o; o += n; return p; };
  float* h = alloc((size_t)NN * 128);
  float* hn = alloc((size_t)NN * 128);
  float* racc = alloc((size_t)NN * 128);          // r (tconv) / aggr (SAG) — Z start
  unsigned* mnode = (unsigned*)alloc(NN * 2);
  float* snode = alloc(NN * 2);                   // --- Z1 end
  float* embtmp = alloc(GG * 128);
  unsigned* gm = (unsigned*)alloc(GG);
  float* gs = alloc(GG);
  float* gsum_e = alloc(GG * 64);                 // --- Z2 end
  u16* q = (u16*)alloc((size_t)NN * 64);          // NN*128 bf16
  u16* k = (u16*)alloc((size_t)NN * 64);
  u16* v = (u16*)alloc((size_t)NN * 64);
  u16* qe = (u16*)alloc((size_t)NN * 64);
  float* alpha = alloc((size_t)EE * 2);
  u16* ea = (u16*)alloc((size_t)EE * 32);         // EE*64 bf16
  float* gstat = alloc(GG * 3);
  float* gmean = alloc(GG);
  float* grstd = alloc(GG);
  float* BD = alloc(128 * 128);
  float* WQE = alloc(128 * 128);
  float* bqe = alloc(128);
  float* sc = alloc(NN);
  float* scp = alloc(NN);
  float* embE = alloc(GG * 128);
  float* embs0 = alloc(GG * 128);
  float* embs1 = alloc(GG * 128);

  const size_t need = o * sizeof(float);
  if (ws_size < need) {  // diagnostic: clean zero-output instead of OOB crash
    hipMemsetAsync(d_out, 0, (size_t)out_size * sizeof(float), stream);
    return;
  }

  const size_t Z1_bytes = (char*)(snode + NN * 2) - (char*)racc;
  const size_t Z2_bytes = (char*)(gsum_e + GG * 64) - (char*)racc;

  auto gemm = [&](const float* A, const float* B, const float* bias, float* C,
                  int M, int Nn, int K, int act, int accum, int obf) {
    dim3 g(Nn / 64, (M + 63) / 64);
    gemm_kernel<<<g, 256, 0, stream>>>(A, B, bias, C, M, Nn, K, act, accum, obf);
  };
  auto graph_ln = [&](const float* in, float* outp, const float* gamma, const float* beta) {
    hipMemsetAsync(gstat, 0, 3 * GG * sizeof(float), stream);
    ln_stats<<<NN / 4, 256, 0, stream>>>(in, batch, gstat);
    ln_final<<<1, 256, 0, stream>>>(gstat, gmean, grstd);
    ln_apply<<<NN * 32 / 256, 256, 0, stream>>>(in, outp, batch, gmean, grstd, gamma, beta);
  };
  auto tconv = [&](int il) {
    const float* wq = qkv_w + (size_t)(il * 3 + 0) * 128 * 128;
    const float* wk = qkv_w + (size_t)(il * 3 + 1) * 128 * 128;
    const float* wv = qkv_w + (size_t)(il * 3 + 2) * 128 * 128;
    const float* bq = qkv_b + (il * 3 + 0) * 128;
    const float* bk = qkv_b + (il * 3 + 1) * 128;
    const float* bv = qkv_b + (il * 3 + 2) * 128;
    const float* we = edge_w + (size_t)il * 64 * 128;
    const float* wsk = skip_w + (size_t)il * 128 * 128;
    const float* bsk = skip_b + il * 128;
    gemm(h, wsk, bsk, hn, NN, 128, 128, 0, 0, 0);        // hn = skip (f32)
    gemm(h, wq, bq, (float*)q, NN, 128, 128, 0, 0, 1);   // bf16 out
    gemm(h, wk, bk, (float*)k, NN, 128, 128, 0, 0, 1);
    gemm(h, wv, bv, (float*)v, NN, 128, 128, 0, 0, 1);
    build_bd<<<64, 256, 0, stream>>>(we, BD);
    build_wqe<<<129, 128, 0, stream>>>(wq, bq, we, WQE, bqe);
    gemm(h, WQE, bqe, (float*)qe, NN, 128, 128, 0, 0, 1);  // qe = h@WQE + bqe (bf16)
    hipMemsetAsync(racc, 0, Z1_bytes, stream);             // r, mnode, snode
    attn_logits<<<EE / 4, 256, 0, stream>>>(q, k, qe, ea, srcp, dstp, alpha, mnode);
    attn_expsum<<<EE * 2 / 256, 256, 0, stream>>>(alpha, dstp, mnode, snode);
    attn_scatter<<<EE / 4, 256, 0, stream>>>(alpha, snode, v, ea, srcp, dstp, hn, racc);
    gemm(racc, BD, nullptr, hn, NN, 128, 128, 0, 1, 0);    // hn += r @ BD
  };

  // initial node / edge encoders
  gemm(x, w0, b0, hn, NN, 128, 64, 0, 0, 0);
  graph_ln(hn, h, ln0_g, ln0_b);
  gemm(edge_attr, we0, be0, (float*)ea, EE, 64, 16, 1, 0, 1);

  for (int i = 0; i < 2; ++i) {
    tconv(i * 2 + 0);
    graph_ln(hn, h, ng + (i * 2) * 128, nbeta + (i * 2) * 128);
    ea_update<<<2048, 256, 0, stream>>>(ea, up_w + (size_t)(i * 2) * 4096,
                                        up_b + (i * 2) * 64, srcp, batch, gsum_e, 0);
    tconv(i * 2 + 1);
    // SAG pooling (uses pre-LN conv2 output hn and pre-elu ea2)
    hipMemsetAsync(racc, 0, Z2_bytes, stream);  // aggr, mnode/snode, embtmp, gm, gs, gsum_e
    ea_update<<<2048, 256, 0, stream>>>(ea, up_w + (size_t)(i * 2 + 1) * 4096,
                                        up_b + (i * 2 + 1) * 64, srcp, batch, gsum_e, 1);
    aggr_scatter<<<EE / 4, 256, 0, stream>>>(hn, srcp, dstp, racc);
    sag_sc<<<NN / 4, 256, 0, stream>>>(racc, hn, sag_wrel + i * 128, sag_brel + i,
                                       sag_wroot + i * 128, batch, sc, gm);
    sag_exp<<<(NN + 255) / 256, 256, 0, stream>>>(sc, batch, gm, gs, scp);
    sag_emb<<<NN / 4, 256, 0, stream>>>(hn, scp, gs, batch, embtmp);
    gemm(gsum_e, re_w + (size_t)i * 64 * 128, re_b + i * 128, embE, GG, 128, 64, 1, 0, 0);
    emb_fin<<<GG, 128, 0, stream>>>(embtmp, embE, i == 0 ? embs0 : embs1);
    graph_ln(hn, h, ng + (i * 2 + 1) * 128, nbeta + (i * 2 + 1) * 128);
  }
  final_combine<<<GG * 128 / 256, 256, 0, stream>>>(embs0, embs1, out);
}

// Round 3
// 4264.885 us; speedup vs baseline: 2.7851x; 2.7851x over previous
//
#include <hip/hip_runtime.h>
#include <math.h>

#define NN 50000
#define EE 800000
#define GG 256

typedef unsigned short u16;
typedef unsigned int u32;

__device__ __forceinline__ float elu_f(float x) { return x > 0.f ? x : expm1f(x); }

__device__ __forceinline__ unsigned fenc(float f) {
  unsigned b = __float_as_uint(f);
  return (b & 0x80000000u) ? ~b : (b | 0x80000000u);
}
__device__ __forceinline__ float fdec(unsigned u) {
  return __uint_as_float((u & 0x80000000u) ? (u ^ 0x80000000u) : ~u);
}
__device__ __forceinline__ u16 f2b(float f) {
  u32 u = __float_as_uint(f);
  u32 r = (u + 0x7fffu + ((u >> 16) & 1u)) >> 16;
  return (u16)r;
}
__device__ __forceinline__ float lo2f(u32 p) { return __uint_as_float(p << 16); }
__device__ __forceinline__ float hi2f(u32 p) { return __uint_as_float(p & 0xffff0000u); }

__device__ __forceinline__ float wred64(float v) {
#pragma unroll
  for (int m = 32; m; m >>= 1) v += __shfl_xor(v, m, 64);
  return v;
}

// ---------------- generic tiled GEMM ----------------
// mode 0: C = act(A@B + bias (+C)), f32 out, stride Nn
// mode 2: fused qkv/qe/skip: col<512 -> bf16 C2[row*512+col]; col>=512 -> f32 C[row*128+col-512]
__global__ __launch_bounds__(256) void gemm_kernel(
    const float* __restrict__ A, const float* __restrict__ B,
    const float* __restrict__ bias, float* __restrict__ C, u16* __restrict__ C2,
    int M, int Nn, int K, int act, int accum, int mode) {
  __shared__ float As[16][68];
  __shared__ float Bs[16][68];
  const int bm = blockIdx.y * 64;
  const int bn = blockIdx.x * 64;
  const int tid = threadIdx.x;
  const int tx = tid & 15, ty = tid >> 4;
  const int lr = tid >> 2;
  const int lk = (tid & 3) << 2;
  float acc[4][4] = {};
  for (int k0 = 0; k0 < K; k0 += 16) {
    int arow = bm + lr;
    float4 a4 = {0.f, 0.f, 0.f, 0.f};
    if (arow < M) a4 = *reinterpret_cast<const float4*>(A + (size_t)arow * K + k0 + lk);
    As[lk + 0][lr] = a4.x; As[lk + 1][lr] = a4.y;
    As[lk + 2][lr] = a4.z; As[lk + 3][lr] = a4.w;
    float4 b4 = *reinterpret_cast<const float4*>(B + (size_t)(k0 + ty) * Nn + bn + tx * 4);
    *reinterpret_cast<float4*>(&Bs[ty][tx * 4]) = b4;
    __syncthreads();
#pragma unroll
    for (int kk = 0; kk < 16; ++kk) {
      float4 av = *reinterpret_cast<const float4*>(&As[kk][ty * 4]);
      float4 bv = *reinterpret_cast<const float4*>(&Bs[kk][tx * 4]);
      float a_[4] = {av.x, av.y, av.z, av.w};
      float b_[4] = {bv.x, bv.y, bv.z, bv.w};
#pragma unroll
      for (int ii = 0; ii < 4; ++ii)
#pragma unroll
        for (int jj = 0; jj < 4; ++jj)
          acc[ii][jj] = fmaf(a_[ii], b_[jj], acc[ii][jj]);
    }
    __syncthreads();
  }
#pragma unroll
  for (int ii = 0; ii < 4; ++ii) {
    int row = bm + ty * 4 + ii;
    if (row >= M) continue;
#pragma unroll
    for (int jj = 0; jj < 4; ++jj) {
      int col = bn + tx * 4 + jj;
      float val = acc[ii][jj];
      if (bias) val += bias[col];
      if (mode == 0) {
        if (accum) val += C[(size_t)row * Nn + col];
        if (act) val = elu_f(val);
        C[(size_t)row * Nn + col] = val;
      } else {  // mode 2
        if (col < 512) C2[(size_t)row * 512 + col] = f2b(val);
        else C[(size_t)row * 128 + col - 512] = val;
      }
    }
  }
}

// ---------------- CSR build ----------------
__global__ void csr_hist(const int* __restrict__ dst, int* __restrict__ deg) {
  int e = blockIdx.x * blockDim.x + threadIdx.x;
  if (e < EE) atomicAdd(&deg[dst[e]], 1);
}

__global__ void csr_scan(const int* __restrict__ deg, int* __restrict__ row_start,
                         int* __restrict__ cursor) {
  __shared__ int sums[256];
  int t = threadIdx.x;
  const int CH = (NN + 255) / 256;  // 196
  int base = t * CH;
  int local = 0;
  for (int i = 0; i < CH; ++i) {
    int idx = base + i;
    if (idx < NN) local += deg[idx];
  }
  sums[t] = local;
  __syncthreads();
  for (int off = 1; off < 256; off <<= 1) {
    int tmp = (t >= off) ? sums[t - off] : 0;
    __syncthreads();
    sums[t] += tmp;
    __syncthreads();
  }
  int run = sums[t] - local;  // exclusive prefix
  for (int i = 0; i < CH; ++i) {
    int idx = base + i;
    if (idx < NN) {
      row_start[idx] = run;
      cursor[idx] = run;
      run += deg[idx];
    }
  }
  if (t == 255) row_start[NN] = run;
}

__global__ void gstart_build(const int* __restrict__ batch, int* __restrict__ gstart) {
  int n = blockIdx.x * blockDim.x + threadIdx.x;
  if (n > NN) return;
  int b = (n < NN) ? batch[n] : GG;
  int pb = (n == 0) ? -1 : batch[n - 1];
  for (int g = pb + 1; g <= b; ++g) gstart[g] = n;
}

// edge encoder: compute elu(edge_attr[e] @ we0 + be0), place at CSR position, record csr_src
__global__ __launch_bounds__(256) void ea_enc(const float* __restrict__ edge_attr,
                                              const float* __restrict__ we0,
                                              const float* __restrict__ be0,
                                              const int* __restrict__ src,
                                              const int* __restrict__ dst,
                                              int* __restrict__ cursor,
                                              int* __restrict__ csr_src,
                                              u16* __restrict__ ea) {
  int lane = threadIdx.x & 63;
  float wc[16];
#pragma unroll
  for (int j = 0; j < 16; ++j) wc[j] = we0[j * 64 + lane];
  float bl = be0[lane];
  int wg = (blockIdx.x * blockDim.x + threadIdx.x) >> 6;
  int nw = (gridDim.x * blockDim.x) >> 6;
  for (int e = wg; e < EE; e += nw) {
    float xr = edge_attr[(size_t)e * 16 + (lane & 15)];
    int pos = 0;
    if (lane == 0) pos = atomicAdd(&cursor[dst[e]], 1);
    pos = __shfl(pos, 0, 64);
    if (lane == 0) csr_src[pos] = src[e];
    float acc = bl;
#pragma unroll
    for (int j = 0; j < 16; ++j) acc = fmaf(__shfl(xr, j, 64), wc[j], acc);
    ea[(size_t)pos * 64 + lane] = f2b(elu_f(acc));
  }
}

// ---------------- graph LayerNorm (block per graph, deterministic) ----------------
__global__ __launch_bounds__(256) void ln_stats_block(const float* __restrict__ h,
                                                      const int* __restrict__ gstart,
                                                      float* __restrict__ gmean,
                                                      float* __restrict__ grstd) {
  __shared__ float ls[4], lss[4];
  int g = blockIdx.x, t = threadIdx.x;
  int n0 = gstart[g], n1 = gstart[g + 1];
  int total4 = (n1 - n0) * 32;
  const float4* base = (const float4*)(h + (size_t)n0 * 128);
  float s = 0.f, ss = 0.f;
  for (int i = t; i < total4; i += 256) {
    float4 v = base[i];
    s += v.x + v.y + v.z + v.w;
    ss += v.x * v.x + v.y * v.y + v.z * v.z + v.w * v.w;
  }
  s = wred64(s);
  ss = wred64(ss);
  if ((t & 63) == 0) { ls[t >> 6] = s; lss[t >> 6] = ss; }
  __syncthreads();
  if (t == 0) {
    float S = ls[0] + ls[1] + ls[2] + ls[3];
    float SS = lss[0] + lss[1] + lss[2] + lss[3];
    float cnt = fmaxf((float)(n1 - n0) * 128.f, 1.0f);
    float mean = S / cnt;
    float var = fmaxf(SS / cnt - mean * mean, 0.f);
    gmean[g] = mean;
    grstd[g] = rsqrtf(var + 1e-5f);
  }
}

__global__ __launch_bounds__(256) void ln_apply(const float* __restrict__ in, float* __restrict__ out,
                                                const int* __restrict__ batch,
                                                const float* __restrict__ gmean,
                                                const float* __restrict__ grstd,
                                                const float* __restrict__ gamma,
                                                const float* __restrict__ beta) {
  int idx = blockIdx.x * blockDim.x + threadIdx.x;
  if (idx >= NN * 32) return;
  int n = idx >> 5, c4 = (idx & 31) * 4;
  int g = batch[n];
  float mean = gmean[g], rstd = grstd[g];
  float4 xv = *reinterpret_cast<const float4*>(in + (size_t)n * 128 + c4);
  float4 gv = *reinterpret_cast<const float4*>(gamma + c4);
  float4 bv = *reinterpret_cast<const float4*>(beta + c4);
  float4 ov;
  ov.x = elu_f((xv.x - mean) * rstd * gv.x + bv.x);
  ov.y = elu_f((xv.y - mean) * rstd * gv.y + bv.y);
  ov.z = elu_f((xv.z - mean) * rstd * gv.z + bv.z);
  ov.w = elu_f((xv.w - mean) * rstd * gv.w + bv.w);
  *reinterpret_cast<float4*>(out + (size_t)n * 128 + c4) = ov;
}

// ---------------- per-layer weight transforms ----------------
__global__ void build_bd(const float* __restrict__ we, float* __restrict__ BD) {
  int idx = blockIdx.x * blockDim.x + threadIdx.x;
  if (idx >= 128 * 128) return;
  int rr = idx >> 7, cc = idx & 127;
  BD[idx] = ((rr >> 6) == (cc >> 6)) ? we[(rr & 63) * 128 + cc] : 0.f;
}

__global__ void build_wqe(const float* __restrict__ wq, const float* __restrict__ bq,
                          const float* __restrict__ we, float* __restrict__ WQE,
                          float* __restrict__ bqe) {
  int col = threadIdx.x;
  int row = blockIdx.x;
  int hh = col >> 6, j = col & 63;
  const float* wrow = (row < 128) ? (wq + (size_t)row * 128) : bq;
  float acc = 0.f;
  for (int c = 0; c < 64; ++c) acc += wrow[hh * 64 + c] * we[(size_t)j * 128 + hh * 64 + c];
  if (row < 128) WQE[(size_t)row * 128 + col] = acc;
  else bqe[col] = acc;
}

__global__ void build_wall(const float* __restrict__ wq, const float* __restrict__ wk,
                           const float* __restrict__ wv, const float* __restrict__ WQE,
                           const float* __restrict__ wsk,
                           const float* __restrict__ bq, const float* __restrict__ bk,
                           const float* __restrict__ bv, const float* __restrict__ bqe,
                           const float* __restrict__ bsk,
                           float* __restrict__ Wall, float* __restrict__ ball) {
  int idx = blockIdx.x * 256 + threadIdx.x;
  if (idx < 128 * 640) {
    int rr = idx / 640, cc = idx % 640;
    int sel = cc >> 7, c = cc & 127;
    const float* s = sel == 0 ? wq : sel == 1 ? wk : sel == 2 ? wv : sel == 3 ? WQE : wsk;
    Wall[idx] = s[rr * 128 + c];
  }
  if (idx < 640) {
    int sel = idx >> 7, c = idx & 127;
    const float* s = sel == 0 ? bq : sel == 1 ? bk : sel == 2 ? bv : sel == 3 ? bqe : bsk;
    ball[idx] = s[c];
  }
}

// ---------------- fused flash-style attention, one wave per dst node ----------------
// nodebuf u32-view: row n at n*256: [q:0..63 | k:64..127 | v:128..191 | qe:192..255]
__global__ __launch_bounds__(256) void attn_node(const u32* __restrict__ nodebuf,
                                                 const u16* __restrict__ ea,
                                                 const int* __restrict__ row_start,
                                                 const int* __restrict__ csr_src,
                                                 float* __restrict__ hn,
                                                 float* __restrict__ r) {
  int d = (blockIdx.x * blockDim.x + threadIdx.x) >> 6;
  if (d >= NN) return;
  int lane = threadIdx.x & 63;
  int p0 = row_start[d], p1 = row_start[d + 1];
  size_t ob = (size_t)d * 128 + lane * 2;
  if (p0 == p1) {  // no in-edges: out = skip only, r = 0
    r[ob] = 0.f;
    r[ob + 1] = 0.f;
    return;
  }
  size_t dbase = (size_t)d * 256;
  u32 qv = nodebuf[dbase + lane];
  u32 qev = nodebuf[dbase + 192 + lane];
  float m = -3.4e38f, ssum = 0.f, a0 = 0.f, a1 = 0.f, r0 = 0.f, r1 = 0.f;
  for (int pos = p0; pos < p1; ++pos) {
    int s = csr_src[pos];
    u32 kv = nodebuf[(size_t)s * 256 + 64 + lane];
    u32 vv = nodebuf[(size_t)s * 256 + 128 + lane];
    u32 eav = ((const u32*)ea)[(size_t)pos * 32 + (lane & 31)];
    float p = lo2f(qv) * lo2f(kv) + hi2f(qv) * hi2f(kv) +
              lo2f(qev) * lo2f(eav) + hi2f(qev) * hi2f(eav);
#pragma unroll
    for (int mm = 16; mm; mm >>= 1) p += __shfl_xor(p, mm, 64);  // per-32-half (per-head) sum
    float l = p * 0.125f;  // / sqrt(64)
    float mn = fmaxf(m, l);
    float f = __expf(m - mn);
    float w = __expf(l - mn);
    ssum = ssum * f + w;
    a0 = a0 * f + w * lo2f(vv);
    a1 = a1 * f + w * hi2f(vv);
    r0 = r0 * f + w * lo2f(eav);
    r1 = r1 * f + w * hi2f(eav);
    m = mn;
  }
  float inv = 1.f / ssum;
  hn[ob] += a0 * inv;
  hn[ob + 1] += a1 * inv;
  r[ob] = r0 * inv;
  r[ob + 1] = r1 * inv;
}

// ---------------- edge MLP update (bf16, CSR order); optional per-graph pre-elu sum ----------------
__global__ __launch_bounds__(256) void ea_update(u16* __restrict__ ea,
                                                 const float* __restrict__ up,
                                                 const float* __restrict__ ub,
                                                 const int* __restrict__ csr_src,
                                                 const int* __restrict__ batch,
                                                 float* __restrict__ gsum_e, int emb_flag) {
  int lane = threadIdx.x & 63;
  float upc[64];
#pragma unroll
  for (int j = 0; j < 64; ++j) upc[j] = up[j * 64 + lane];
  float bl = ub[lane];
  int wg = (blockIdx.x * blockDim.x + threadIdx.x) >> 6;
  int nw = (gridDim.x * blockDim.x) >> 6;
  for (int e = wg; e < EE; e += nw) {
    float x = __uint_as_float(((u32)ea[(size_t)e * 64 + lane]) << 16);
    float acc = bl;
#pragma unroll
    for (int j = 0; j < 64; ++j) acc = fmaf(__shfl(x, j, 64), upc[j], acc);
    if (emb_flag) atomicAdd(&gsum_e[(size_t)batch[csr_src[e]] * 64 + lane], acc);
    ea[(size_t)e * 64 + lane] = f2b(elu_f(acc));
  }
}

// ---------------- SAG pooling ----------------
__global__ __launch_bounds__(256) void node_dots(const float* __restrict__ hn,
                                                 const float* __restrict__ wrel,
                                                 const float* __restrict__ wroot,
                                                 float* __restrict__ hrel,
                                                 float* __restrict__ troot) {
  int n = (blockIdx.x * blockDim.x + threadIdx.x) >> 6;
  if (n >= NN) return;
  int lane = threadIdx.x & 63;
  float x0 = hn[(size_t)n * 128 + lane], x1 = hn[(size_t)n * 128 + 64 + lane];
  float tr = wred64(x0 * wrel[lane] + x1 * wrel[64 + lane]);
  float tt = wred64(x0 * wroot[lane] + x1 * wroot[64 + lane]);
  if (lane == 0) { hrel[n] = tr; troot[n] = tt; }
}

__global__ __launch_bounds__(256) void sag_gather(const float* __restrict__ hrel,
                                                  const float* __restrict__ troot,
                                                  const float* __restrict__ brel,
                                                  const int* __restrict__ row_start,
                                                  const int* __restrict__ csr_src,
                                                  const int* __restrict__ batch,
                                                  float* __restrict__ sc, unsigned* __restrict__ gm) {
  int n = blockIdx.x * blockDim.x + threadIdx.x;
  if (n >= NN) return;
  float s = 0.f;
  int p1 = row_start[n + 1];
  for (int pos = row_start[n]; pos < p1; ++pos) s += hrel[csr_src[pos]];
  float v = s + troot[n] + brel[0];
  sc[n] = v;
  atomicMax(&gm[batch[n]], fenc(v));
}

__global__ __launch_bounds__(256) void sag_exp(const float* __restrict__ sc,
                                               const int* __restrict__ batch,
                                               const unsigned* __restrict__ gm,
                                               float* __restrict__ gs, float* __restrict__ scp) {
  int n = blockIdx.x * blockDim.x + threadIdx.x;
  if (n >= NN) return;
  int g = batch[n];
  float p = __expf(sc[n] - fdec(gm[g]));
  scp[n] = p;
  atomicAdd(&gs[g], p);
}

// block per graph: emb = elu(normalize((Σ h·w) * embE))
__global__ void emb_block(const float* __restrict__ hn, const float* __restrict__ scp,
                          const float* __restrict__ gs, const int* __restrict__ gstart,
                          const float* __restrict__ embE, float* __restrict__ dstv) {
  __shared__ float part[2];
  int g = blockIdx.x, c = threadIdx.x;  // 128 threads
  int n0 = gstart[g], n1 = gstart[g + 1];
  float invg = 1.f / gs[g];
  float acc = 0.f;
  for (int n = n0; n < n1; ++n) acc = fmaf(hn[(size_t)n * 128 + c], scp[n] * invg, acc);
  float val = acc * embE[(size_t)g * 128 + c];
  float sq = val * val;
#pragma unroll
  for (int mm = 32; mm; mm >>= 1) sq += __shfl_xor(sq, mm, 64);
  if ((c & 63) == 0) part[c >> 6] = sq;
  __syncthreads();
  float nrm = sqrtf(part[0] + part[1]);
  dstv[(size_t)g * 128 + c] = elu_f(val / fmaxf(nrm, 1e-12f));
}

__global__ void final_combine(const float* __restrict__ e0, const float* __restrict__ e1,
                              float* __restrict__ out) {
  int idx = blockIdx.x * blockDim.x + threadIdx.x;
  if (idx >= GG * 128) return;
  out[idx] = 0.6f * e0[idx] + 0.4f * e1[idx];
}

// =====================================================================
extern "C" void kernel_launch(void* const* d_in, const int* in_sizes, int n_in,
                              void* d_out, int out_size, void* d_ws, size_t ws_size,
                              hipStream_t stream) {
  const float* x = (const float*)d_in[0];
  const float* edge_attr = (const float*)d_in[1];
  const int* edge_index = (const int*)d_in[2];
  const int* batch = (const int*)d_in[3];
  const float* w0 = (const float*)d_in[4];
  const float* b0 = (const float*)d_in[5];
  const float* we0 = (const float*)d_in[6];
  const float* be0 = (const float*)d_in[7];
  const float* ln0_g = (const float*)d_in[8];
  const float* ln0_b = (const float*)d_in[9];
  const float* qkv_w = (const float*)d_in[10];
  const float* qkv_b = (const float*)d_in[11];
  const float* edge_w = (const float*)d_in[12];
  const float* skip_w = (const float*)d_in[13];
  const float* skip_b = (const float*)d_in[14];
  const float* up_w = (const float*)d_in[15];
  const float* up_b = (const float*)d_in[16];
  const float* ng = (const float*)d_in[17];
  const float* nbeta = (const float*)d_in[18];
  const float* sag_wrel = (const float*)d_in[19];
  const float* sag_brel = (const float*)d_in[20];
  const float* sag_wroot = (const float*)d_in[21];
  const float* re_w = (const float*)d_in[22];
  const float* re_b = (const float*)d_in[23];
  const int* srcp = edge_index;
  const int* dstp = edge_index + EE;
  float* out = (float*)d_out;
  (void)in_sizes; (void)n_in;

  float* ws = (float*)d_ws;
  size_t o = 0;
  auto alloc = [&](size_t n) { float* p = ws + o; o += n; return p; };
  float* h = alloc((size_t)NN * 128);
  float* hn = alloc((size_t)NN * 128);
  float* racc = alloc((size_t)NN * 128);
  u16* nodebuf = (u16*)alloc((size_t)NN * 256);   // NN x 512 bf16 (q|k|v|qe)
  u16* ea = (u16*)alloc((size_t)EE * 32);         // EE x 64 bf16, CSR order
  int* csr_src = (int*)alloc(EE);
  int* deg = (int*)alloc(NN);
  int* row_start = (int*)alloc(NN + 1);
  int* cursor = (int*)alloc(NN);
  int* gstart = (int*)alloc(GG + 1);
  float* gsum_e = alloc(GG * 64);                 // --- zero-block start
  unsigned* gm = (unsigned*)alloc(GG);
  float* gs = alloc(GG);                          // --- zero-block end
  float* gmean = alloc(GG);
  float* grstd = alloc(GG);
  float* BD = alloc(128 * 128);
  float* WQE = alloc(128 * 128);
  float* bqe = alloc(128);
  float* Wall = alloc(128 * 640);
  float* ball = alloc(640);
  float* hrel = alloc(NN);
  float* troot = alloc(NN);
  float* sc = alloc(NN);
  float* scp = alloc(NN);
  float* embE = alloc(GG * 128);
  float* embs0 = alloc(GG * 128);
  float* embs1 = alloc(GG * 128);

  const size_t need = o * sizeof(float);
  if (ws_size < need) {  // diagnostic: clean zero-output instead of OOB crash
    hipMemsetAsync(d_out, 0, (size_t)out_size * sizeof(float), stream);
    return;
  }
  const size_t ZB = (GG * 64 + GG + GG) * sizeof(float);  // gsum_e, gm, gs

  auto gemm = [&](const float* A, const float* B, const float* bias, float* C, u16* C2,
                  int M, int Nn, int K, int act, int accum, int mode) {
    dim3 g((Nn + 63) / 64, (M + 63) / 64);
    gemm_kernel<<<g, 256, 0, stream>>>(A, B, bias, C, C2, M, Nn, K, act, accum, mode);
  };
  auto graph_ln = [&](const float* in, float* outp, const float* gamma, const float* beta) {
    ln_stats_block<<<GG, 256, 0, stream>>>(in, gstart, gmean, grstd);
    ln_apply<<<NN * 32 / 256, 256, 0, stream>>>(in, outp, batch, gmean, grstd, gamma, beta);
  };
  auto tconv = [&](int il) {
    const float* wq = qkv_w + (size_t)(il * 3 + 0) * 128 * 128;
    const float* wk = qkv_w + (size_t)(il * 3 + 1) * 128 * 128;
    const float* wv = qkv_w + (size_t)(il * 3 + 2) * 128 * 128;
    const float* bq = qkv_b + (il * 3 + 0) * 128;
    const float* bk = qkv_b + (il * 3 + 1) * 128;
    const float* bv = qkv_b + (il * 3 + 2) * 128;
    const float* we = edge_w + (size_t)il * 64 * 128;
    const float* wsk = skip_w + (size_t)il * 128 * 128;
    const float* bsk = skip_b + il * 128;
    build_wqe<<<129, 128, 0, stream>>>(wq, bq, we, WQE, bqe);
    build_wall<<<320, 256, 0, stream>>>(wq, wk, wv, WQE, wsk, bq, bk, bv, bqe, bsk, Wall, ball);
    build_bd<<<64, 256, 0, stream>>>(we, BD);
    gemm(h, Wall, ball, hn, nodebuf, NN, 640, 128, 0, 0, 2);  // q|k|v|qe (bf16) + skip->hn
    attn_node<<<NN / 4, 256, 0, stream>>>((const u32*)nodebuf, ea, row_start, csr_src, hn, racc);
    gemm(racc, BD, nullptr, hn, nullptr, NN, 128, 128, 0, 1, 0);  // hn += r @ BD
  };

  // CSR build (edge topology constant across the whole net)
  hipMemsetAsync(deg, 0, NN * sizeof(int), stream);
  csr_hist<<<(EE + 255) / 256, 256, 0, stream>>>(dstp, deg);
  csr_scan<<<1, 256, 0, stream>>>(deg, row_start, cursor);
  gstart_build<<<(NN + 256) / 256, 256, 0, stream>>>(batch, gstart);
  // edge encoder directly into CSR layout
  ea_enc<<<2048, 256, 0, stream>>>(edge_attr, we0, be0, srcp, dstp, cursor, csr_src, ea);
  // node encoder + first LN
  gemm(x, w0, b0, hn, nullptr, NN, 128, 64, 0, 0, 0);
  graph_ln(hn, h, ln0_g, ln0_b);

  for (int i = 0; i < 2; ++i) {
    tconv(i * 2 + 0);
    graph_ln(hn, h, ng + (i * 2) * 128, nbeta + (i * 2) * 128);
    ea_update<<<2048, 256, 0, stream>>>(ea, up_w + (size_t)(i * 2) * 4096,
                                        up_b + (i * 2) * 64, csr_src, batch, gsum_e, 0);
    tconv(i * 2 + 1);
    // SAG pooling on pre-LN conv2 output hn; ea2 pre-elu sums for emb_e
    hipMemsetAsync(gsum_e, 0, ZB, stream);  // gsum_e, gm, gs
    ea_update<<<2048, 256, 0, stream>>>(ea, up_w + (size_t)(i * 2 + 1) * 4096,
                                        up_b + (i * 2 + 1) * 64, csr_src, batch, gsum_e, 1);
    node_dots<<<NN / 4, 256, 0, stream>>>(hn, sag_wrel + i * 128, sag_wroot + i * 128, hrel, troot);
    sag_gather<<<(NN + 255) / 256, 256, 0, stream>>>(hrel, troot, sag_brel + i, row_start,
                                                     csr_src, batch, sc, gm);
    sag_exp<<<(NN + 255) / 256, 256, 0, stream>>>(sc, batch, gm, gs, scp);
    gemm(gsum_e, re_w + (size_t)i * 64 * 128, re_b + i * 128, embE, nullptr, GG, 128, 64, 1, 0, 0);
    emb_block<<<GG, 128, 0, stream>>>(hn, scp, gs, gstart, embE, i == 0 ? embs0 : embs1);
    graph_ln(hn, h, ng + (i * 2 + 1) * 128, nbeta + (i * 2 + 1) * 128);
  }
  final_combine<<<GG * 128 / 256, 256, 0, stream>>>(embs0, embs1, out);
}

// Round 4
// 3417.086 us; speedup vs baseline: 3.4762x; 1.2481x over previous
//
#include <hip/hip_runtime.h>
#include <math.h>

#define NN 50000
#define EE 800000
#define GG 256

typedef unsigned short u16;
typedef unsigned int u32;
typedef __attribute__((ext_vector_type(4))) float f32x4;
typedef __attribute__((ext_vector_type(8))) short bf16x8;

__device__ __forceinline__ float elu_f(float x) { return x > 0.f ? x : expm1f(x); }

__device__ __forceinline__ unsigned fenc(float f) {
  unsigned b = __float_as_uint(f);
  return (b & 0x80000000u) ? ~b : (b | 0x80000000u);
}
__device__ __forceinline__ float fdec(unsigned u) {
  return __uint_as_float((u & 0x80000000u) ? (u ^ 0x80000000u) : ~u);
}
__device__ __forceinline__ u16 f2b(float f) {
  u32 u = __float_as_uint(f);
  u32 r = (u + 0x7fffu + ((u >> 16) & 1u)) >> 16;
  return (u16)r;
}
__device__ __forceinline__ float lo2f(u32 p) { return __uint_as_float(p << 16); }
__device__ __forceinline__ float hi2f(u32 p) { return __uint_as_float(p & 0xffff0000u); }

__device__ __forceinline__ float wred64(float v) {
#pragma unroll
  for (int m = 32; m; m >>= 1) v += __shfl_xor(v, m, 64);
  return v;
}

// ---------------- generic tiled GEMM ----------------
// mode 0: C = act(A@B + bias (+C)), f32 out, stride Nn
// mode 2: fused qkv/qe/skip: col<512 -> bf16 C2[row*512+col]; col>=512 -> f32 C[row*128+col-512]
__global__ __launch_bounds__(256) void gemm_kernel(
    const float* __restrict__ A, const float* __restrict__ B,
    const float* __restrict__ bias, float* __restrict__ C, u16* __restrict__ C2,
    int M, int Nn, int K, int act, int accum, int mode) {
  __shared__ float As[16][68];
  __shared__ float Bs[16][68];
  const int bm = blockIdx.y * 64;
  const int bn = blockIdx.x * 64;
  const int tid = threadIdx.x;
  const int tx = tid & 15, ty = tid >> 4;
  const int lr = tid >> 2;
  const int lk = (tid & 3) << 2;
  float acc[4][4] = {};
  for (int k0 = 0; k0 < K; k0 += 16) {
    int arow = bm + lr;
    float4 a4 = {0.f, 0.f, 0.f, 0.f};
    if (arow < M) a4 = *reinterpret_cast<const float4*>(A + (size_t)arow * K + k0 + lk);
    As[lk + 0][lr] = a4.x; As[lk + 1][lr] = a4.y;
    As[lk + 2][lr] = a4.z; As[lk + 3][lr] = a4.w;
    float4 b4 = *reinterpret_cast<const float4*>(B + (size_t)(k0 + ty) * Nn + bn + tx * 4);
    *reinterpret_cast<float4*>(&Bs[ty][tx * 4]) = b4;
    __syncthreads();
#pragma unroll
    for (int kk = 0; kk < 16; ++kk) {
      float4 av = *reinterpret_cast<const float4*>(&As[kk][ty * 4]);
      float4 bv = *reinterpret_cast<const float4*>(&Bs[kk][tx * 4]);
      float a_[4] = {av.x, av.y, av.z, av.w};
      float b_[4] = {bv.x, bv.y, bv.z, bv.w};
#pragma unroll
      for (int ii = 0; ii < 4; ++ii)
#pragma unroll
        for (int jj = 0; jj < 4; ++jj)
          acc[ii][jj] = fmaf(a_[ii], b_[jj], acc[ii][jj]);
    }
    __syncthreads();
  }
#pragma unroll
  for (int ii = 0; ii < 4; ++ii) {
    int row = bm + ty * 4 + ii;
    if (row >= M) continue;
#pragma unroll
    for (int jj = 0; jj < 4; ++jj) {
      int col = bn + tx * 4 + jj;
      float val = acc[ii][jj];
      if (bias) val += bias[col];
      if (mode == 0) {
        if (accum) val += C[(size_t)row * Nn + col];
        if (act) val = elu_f(val);
        C[(size_t)row * Nn + col] = val;
      } else {  // mode 2
        if (col < 512) C2[(size_t)row * 512 + col] = f2b(val);
        else C[(size_t)row * 128 + col - 512] = val;
      }
    }
  }
}

// ---------------- CSR build ----------------
__global__ void csr_hist(const int* __restrict__ dst, int* __restrict__ deg) {
  int e = blockIdx.x * blockDim.x + threadIdx.x;
  if (e < EE) atomicAdd(&deg[dst[e]], 1);
}

__global__ void csr_scan(const int* __restrict__ deg, int* __restrict__ row_start,
                         int* __restrict__ cursor) {
  __shared__ int sums[256];
  int t = threadIdx.x;
  const int CH = (NN + 255) / 256;
  int base = t * CH;
  int local = 0;
  for (int i = 0; i < CH; ++i) {
    int idx = base + i;
    if (idx < NN) local += deg[idx];
  }
  sums[t] = local;
  __syncthreads();
  for (int off = 1; off < 256; off <<= 1) {
    int tmp = (t >= off) ? sums[t - off] : 0;
    __syncthreads();
    sums[t] += tmp;
    __syncthreads();
  }
  int run = sums[t] - local;
  for (int i = 0; i < CH; ++i) {
    int idx = base + i;
    if (idx < NN) {
      row_start[idx] = run;
      cursor[idx] = run;
      run += deg[idx];
    }
  }
  if (t == 255) row_start[NN] = run;
}

__global__ void gstart_build(const int* __restrict__ batch, int* __restrict__ gstart) {
  int n = blockIdx.x * blockDim.x + threadIdx.x;
  if (n > NN) return;
  int b = (n < NN) ? batch[n] : GG;
  int pb = (n == 0) ? -1 : batch[n - 1];
  for (int g = pb + 1; g <= b; ++g) gstart[g] = n;
}

// src-graph buckets: positions (CSR order) grouped by batch[csr_src[pos]]
__global__ void sg_hist(const int* __restrict__ csr_src, const int* __restrict__ batch,
                        int* __restrict__ scnt) {
  int pos = blockIdx.x * blockDim.x + threadIdx.x;
  if (pos < EE) atomicAdd(&scnt[batch[csr_src[pos]]], 1);
}

__global__ void sg_scan(const int* __restrict__ scnt, int* __restrict__ sg_start,
                        int* __restrict__ sg_cursor, float* __restrict__ cntf) {
  __shared__ int s[256];
  int t = threadIdx.x;
  int v = scnt[t];
  s[t] = v;
  __syncthreads();
  for (int off = 1; off < 256; off <<= 1) {
    int tmp = (t >= off) ? s[t - off] : 0;
    __syncthreads();
    s[t] += tmp;
    __syncthreads();
  }
  sg_start[t] = s[t] - v;
  sg_cursor[t] = s[t] - v;
  cntf[t] = (float)v;
  if (t == 255) sg_start[256] = s[255];
}

__global__ void sg_fill(const int* __restrict__ csr_src, const int* __restrict__ batch,
                        int* __restrict__ sg_cursor, int* __restrict__ sg_perm) {
  int pos = blockIdx.x * blockDim.x + threadIdx.x;
  if (pos < EE) {
    int slot = atomicAdd(&sg_cursor[batch[csr_src[pos]]], 1);
    sg_perm[slot] = pos;
  }
}

// edge encoder: elu(edge_attr[e] @ we0 + be0) placed at CSR position
__global__ __launch_bounds__(256) void ea_enc(const float* __restrict__ edge_attr,
                                              const float* __restrict__ we0,
                                              const float* __restrict__ be0,
                                              const int* __restrict__ src,
                                              const int* __restrict__ dst,
                                              int* __restrict__ cursor,
                                              int* __restrict__ csr_src,
                                              u16* __restrict__ ea) {
  int lane = threadIdx.x & 63;
  float wc[16];
#pragma unroll
  for (int j = 0; j < 16; ++j) wc[j] = we0[j * 64 + lane];
  float bl = be0[lane];
  int wg = (blockIdx.x * blockDim.x + threadIdx.x) >> 6;
  int nw = (gridDim.x * blockDim.x) >> 6;
  for (int e = wg; e < EE; e += nw) {
    float xr = edge_attr[(size_t)e * 16 + (lane & 15)];
    int pos = 0;
    if (lane == 0) pos = atomicAdd(&cursor[dst[e]], 1);
    pos = __shfl(pos, 0, 64);
    if (lane == 0) csr_src[pos] = src[e];
    float acc = bl;
#pragma unroll
    for (int j = 0; j < 16; ++j) acc = fmaf(__shfl(xr, j, 64), wc[j], acc);
    ea[(size_t)pos * 64 + lane] = f2b(elu_f(acc));
  }
}

// ---------------- graph LayerNorm ----------------
__global__ __launch_bounds__(256) void ln_stats_block(const float* __restrict__ h,
                                                      const int* __restrict__ gstart,
                                                      float* __restrict__ gmean,
                                                      float* __restrict__ grstd) {
  __shared__ float ls[4], lss[4];
  int g = blockIdx.x, t = threadIdx.x;
  int n0 = gstart[g], n1 = gstart[g + 1];
  int total4 = (n1 - n0) * 32;
  const float4* base = (const float4*)(h + (size_t)n0 * 128);
  float s = 0.f, ss = 0.f;
  for (int i = t; i < total4; i += 256) {
    float4 v = base[i];
    s += v.x + v.y + v.z + v.w;
    ss += v.x * v.x + v.y * v.y + v.z * v.z + v.w * v.w;
  }
  s = wred64(s);
  ss = wred64(ss);
  if ((t & 63) == 0) { ls[t >> 6] = s; lss[t >> 6] = ss; }
  __syncthreads();
  if (t == 0) {
    float S = ls[0] + ls[1] + ls[2] + ls[3];
    float SS = lss[0] + lss[1] + lss[2] + lss[3];
    float cnt = fmaxf((float)(n1 - n0) * 128.f, 1.0f);
    float mean = S / cnt;
    float var = fmaxf(SS / cnt - mean * mean, 0.f);
    gmean[g] = mean;
    grstd[g] = rsqrtf(var + 1e-5f);
  }
}

__global__ __launch_bounds__(256) void ln_apply(const float* __restrict__ in, float* __restrict__ out,
                                                const int* __restrict__ batch,
                                                const float* __restrict__ gmean,
                                                const float* __restrict__ grstd,
                                                const float* __restrict__ gamma,
                                                const float* __restrict__ beta) {
  int idx = blockIdx.x * blockDim.x + threadIdx.x;
  if (idx >= NN * 32) return;
  int n = idx >> 5, c4 = (idx & 31) * 4;
  int g = batch[n];
  float mean = gmean[g], rstd = grstd[g];
  float4 xv = *reinterpret_cast<const float4*>(in + (size_t)n * 128 + c4);
  float4 gv = *reinterpret_cast<const float4*>(gamma + c4);
  float4 bv = *reinterpret_cast<const float4*>(beta + c4);
  float4 ov;
  ov.x = elu_f((xv.x - mean) * rstd * gv.x + bv.x);
  ov.y = elu_f((xv.y - mean) * rstd * gv.y + bv.y);
  ov.z = elu_f((xv.z - mean) * rstd * gv.z + bv.z);
  ov.w = elu_f((xv.w - mean) * rstd * gv.w + bv.w);
  *reinterpret_cast<float4*>(out + (size_t)n * 128 + c4) = ov;
}

// ---------------- per-layer weight transforms ----------------
__global__ void build_bd(const float* __restrict__ we, float* __restrict__ BD) {
  int idx = blockIdx.x * blockDim.x + threadIdx.x;
  if (idx >= 128 * 128) return;
  int rr = idx >> 7, cc = idx & 127;
  BD[idx] = ((rr >> 6) == (cc >> 6)) ? we[(rr & 63) * 128 + cc] : 0.f;
}

__global__ void build_wqe(const float* __restrict__ wq, const float* __restrict__ bq,
                          const float* __restrict__ we, float* __restrict__ WQE,
                          float* __restrict__ bqe) {
  int col = threadIdx.x;
  int row = blockIdx.x;
  int hh = col >> 6, j = col & 63;
  const float* wrow = (row < 128) ? (wq + (size_t)row * 128) : bq;
  float acc = 0.f;
  for (int c = 0; c < 64; ++c) acc += wrow[hh * 64 + c] * we[(size_t)j * 128 + hh * 64 + c];
  if (row < 128) WQE[(size_t)row * 128 + col] = acc;
  else bqe[col] = acc;
}

__global__ void build_wall(const float* __restrict__ wq, const float* __restrict__ wk,
                           const float* __restrict__ wv, const float* __restrict__ WQE,
                           const float* __restrict__ wsk,
                           const float* __restrict__ bq, const float* __restrict__ bk,
                           const float* __restrict__ bv, const float* __restrict__ bqe,
                           const float* __restrict__ bsk,
                           float* __restrict__ Wall, float* __restrict__ ball) {
  int idx = blockIdx.x * 256 + threadIdx.x;
  if (idx < 128 * 640) {
    int rr = idx / 640, cc = idx % 640;
    int sel = cc >> 7, c = cc & 127;
    const float* s = sel == 0 ? wq : sel == 1 ? wk : sel == 2 ? wv : sel == 3 ? WQE : wsk;
    Wall[idx] = s[rr * 128 + c];
  }
  if (idx < 640) {
    int sel = idx >> 7, c = idx & 127;
    const float* s = sel == 0 ? bq : sel == 1 ? bk : sel == 2 ? bv : sel == 3 ? bqe : bsk;
    ball[idx] = s[c];
  }
}

// up[64x64] f32 -> bf16 fragments, k-mapping (s,g,j): k = s*32 + g*8 + j
__global__ void build_upfrag(const float* __restrict__ up, u16* __restrict__ upfrag) {
  int idx = blockIdx.x * 256 + threadIdx.x;  // 8*64*8 = 4096
  if (idx >= 4096) return;
  int j = idx & 7, lane = (idx >> 3) & 63, st = idx >> 9;
  int s = st >> 2, t = st & 3;
  int k = s * 32 + (lane >> 4) * 8 + j;
  int c = t * 16 + (lane & 15);
  upfrag[idx] = f2b(up[k * 64 + c]);
}

// W2 = up @ re_w [64x128]; bvec = ub @ re_w [128]
__global__ void build_w2(const float* __restrict__ up, const float* __restrict__ ub,
                         const float* __restrict__ re_w, float* __restrict__ W2,
                         float* __restrict__ bvec) {
  int idx = blockIdx.x * 256 + threadIdx.x;
  if (idx < 64 * 128) {
    int k_ = idx >> 7, c = idx & 127;
    float a = 0.f;
    for (int j = 0; j < 64; ++j) a = fmaf(up[k_ * 64 + j], re_w[j * 128 + c], a);
    W2[idx] = a;
  } else if (idx < 64 * 128 + 128) {
    int c = idx - 64 * 128;
    float a = 0.f;
    for (int j = 0; j < 64; ++j) a = fmaf(ub[j], re_w[j * 128 + c], a);
    bvec[c] = a;
  }
}

// ---------------- MFMA edge GEMM: ea = elu(ea @ up + ub), in place ----------------
__global__ __launch_bounds__(256) void edge_gemm(u16* __restrict__ ea,
                                                 const u16* __restrict__ upfrag,
                                                 const float* __restrict__ ub) {
  int lane = threadIdx.x & 63;
  int gwave = (blockIdx.x * 256 + threadIdx.x) >> 6;
  int nwaves = (gridDim.x * 256) >> 6;
  bf16x8 bfrag[2][4];
#pragma unroll
  for (int s = 0; s < 2; ++s)
#pragma unroll
    for (int t = 0; t < 4; ++t)
      bfrag[s][t] = *reinterpret_cast<const bf16x8*>(upfrag + ((size_t)((s * 4 + t) * 64 + lane)) * 8);
  float bias_c[4];
#pragma unroll
  for (int t = 0; t < 4; ++t) bias_c[t] = ub[t * 16 + (lane & 15)];
  const int rif = lane & 15;   // row within fragment
  const int kg = lane >> 4;    // k-group 0..3
  for (int mt = gwave; mt < EE / 16; mt += nwaves) {
    size_t rowbase = (size_t)mt * 16;
    const u16* arow = ea + (rowbase + rif) * 64;
    bf16x8 a0 = *reinterpret_cast<const bf16x8*>(arow + kg * 8);
    bf16x8 a1 = *reinterpret_cast<const bf16x8*>(arow + 32 + kg * 8);
    f32x4 acc[4] = {};
#pragma unroll
    for (int t = 0; t < 4; ++t) {
      acc[t] = __builtin_amdgcn_mfma_f32_16x16x32_bf16(a0, bfrag[0][t], acc[t], 0, 0, 0);
      acc[t] = __builtin_amdgcn_mfma_f32_16x16x32_bf16(a1, bfrag[1][t], acc[t], 0, 0, 0);
    }
    // D layout: col = t*16 + (lane&15), row = (lane>>4)*4 + reg
#pragma unroll
    for (int t = 0; t < 4; ++t)
#pragma unroll
      for (int rg = 0; rg < 4; ++rg) {
        float val = acc[t][rg] + bias_c[t];
        ea[(rowbase + kg * 4 + rg) * 64 + t * 16 + rif] = f2b(elu_f(val));
      }
  }
}

// deterministic per-src-graph sum of current ea rows
__global__ __launch_bounds__(256) void gsum_pre(const u16* __restrict__ ea,
                                                const int* __restrict__ sg_start,
                                                const int* __restrict__ sg_perm,
                                                float* __restrict__ gsum_in) {
  __shared__ float red[8][64];
  int g = blockIdx.x, t = threadIdx.x;
  int c2 = t & 31;
  int rgrp = t >> 5;
  int p0 = sg_start[g], p1 = sg_start[g + 1];
  float slo = 0.f, shi = 0.f;
  for (int i = p0 + rgrp; i < p1; i += 8) {
    int pos = sg_perm[i];
    u32 w = ((const u32*)ea)[(size_t)pos * 32 + c2];
    slo += lo2f(w);
    shi += hi2f(w);
  }
  red[rgrp][c2 * 2] = slo;
  red[rgrp][c2 * 2 + 1] = shi;
  __syncthreads();
  if (t < 64) {
    float a = 0.f;
#pragma unroll
    for (int rr = 0; rr < 8; ++rr) a += red[rr][t];
    gsum_in[(size_t)g * 64 + t] = a;
  }
}

// embE = elu(gsum_in @ W2 + cnt*bvec + re_b)
__global__ void emb_e_kernel(const float* __restrict__ gsum_in, const float* __restrict__ cntf,
                             const float* __restrict__ W2, const float* __restrict__ bvec,
                             const float* __restrict__ re_b, float* __restrict__ embE) {
  int g = blockIdx.x, c = threadIdx.x;
  float a = re_b[c] + cntf[g] * bvec[c];
  for (int k_ = 0; k_ < 64; ++k_) a = fmaf(gsum_in[(size_t)g * 64 + k_], W2[k_ * 128 + c], a);
  embE[(size_t)g * 128 + c] = elu_f(a);
}

// ---------------- fused flash-style attention, one wave per dst node ----------------
__global__ __launch_bounds__(256) void attn_node(const u32* __restrict__ nodebuf,
                                                 const u16* __restrict__ ea,
                                                 const int* __restrict__ row_start,
                                                 const int* __restrict__ csr_src,
                                                 float* __restrict__ hn,
                                                 float* __restrict__ r) {
  int d = (blockIdx.x * blockDim.x + threadIdx.x) >> 6;
  if (d >= NN) return;
  int lane = threadIdx.x & 63;
  int p0 = row_start[d], p1 = row_start[d + 1];
  size_t ob = (size_t)d * 128 + lane * 2;
  if (p0 == p1) {
    r[ob] = 0.f;
    r[ob + 1] = 0.f;
    return;
  }
  size_t dbase = (size_t)d * 256;
  u32 qv = nodebuf[dbase + lane];
  u32 qev = nodebuf[dbase + 192 + lane];
  float m = -3.4e38f, ssum = 0.f, a0 = 0.f, a1 = 0.f, r0 = 0.f, r1 = 0.f;
  for (int pos = p0; pos < p1; ++pos) {
    int s = csr_src[pos];
    u32 kv = nodebuf[(size_t)s * 256 + 64 + lane];
    u32 vv = nodebuf[(size_t)s * 256 + 128 + lane];
    u32 eav = ((const u32*)ea)[(size_t)pos * 32 + (lane & 31)];
    float p = lo2f(qv) * lo2f(kv) + hi2f(qv) * hi2f(kv) +
              lo2f(qev) * lo2f(eav) + hi2f(qev) * hi2f(eav);
#pragma unroll
    for (int mm = 16; mm; mm >>= 1) p += __shfl_xor(p, mm, 64);
    float l = p * 0.125f;
    float mn = fmaxf(m, l);
    float f = __expf(m - mn);
    float w = __expf(l - mn);
    ssum = ssum * f + w;
    a0 = a0 * f + w * lo2f(vv);
    a1 = a1 * f + w * hi2f(vv);
    r0 = r0 * f + w * lo2f(eav);
    r1 = r1 * f + w * hi2f(eav);
    m = mn;
  }
  float inv = 1.f / ssum;
  hn[ob] += a0 * inv;
  hn[ob + 1] += a1 * inv;
  r[ob] = r0 * inv;
  r[ob + 1] = r1 * inv;
}

// ---------------- SAG pooling ----------------
__global__ __launch_bounds__(256) void node_dots(const float* __restrict__ hn,
                                                 const float* __restrict__ wrel,
                                                 const float* __restrict__ wroot,
                                                 float* __restrict__ hrel,
                                                 float* __restrict__ troot) {
  int n = (blockIdx.x * blockDim.x + threadIdx.x) >> 6;
  if (n >= NN) return;
  int lane = threadIdx.x & 63;
  float x0 = hn[(size_t)n * 128 + lane], x1 = hn[(size_t)n * 128 + 64 + lane];
  float tr = wred64(x0 * wrel[lane] + x1 * wrel[64 + lane]);
  float tt = wred64(x0 * wroot[lane] + x1 * wroot[64 + lane]);
  if (lane == 0) { hrel[n] = tr; troot[n] = tt; }
}

__global__ __launch_bounds__(256) void sag_gather(const float* __restrict__ hrel,
                                                  const float* __restrict__ troot,
                                                  const float* __restrict__ brel,
                                                  const int* __restrict__ row_start,
                                                  const int* __restrict__ csr_src,
                                                  const int* __restrict__ batch,
                                                  float* __restrict__ sc, unsigned* __restrict__ gm) {
  int n = blockIdx.x * blockDim.x + threadIdx.x;
  if (n >= NN) return;
  float s = 0.f;
  int p1 = row_start[n + 1];
  for (int pos = row_start[n]; pos < p1; ++pos) s += hrel[csr_src[pos]];
  float v = s + troot[n] + brel[0];
  sc[n] = v;
  atomicMax(&gm[batch[n]], fenc(v));
}

__global__ __launch_bounds__(256) void sag_exp(const float* __restrict__ sc,
                                               const int* __restrict__ batch,
                                               const unsigned* __restrict__ gm,
                                               float* __restrict__ gs, float* __restrict__ scp) {
  int n = blockIdx.x * blockDim.x + threadIdx.x;
  if (n >= NN) return;
  int g = batch[n];
  float p = __expf(sc[n] - fdec(gm[g]));
  scp[n] = p;
  atomicAdd(&gs[g], p);
}

__global__ void emb_block(const float* __restrict__ hn, const float* __restrict__ scp,
                          const float* __restrict__ gs, const int* __restrict__ gstart,
                          const float* __restrict__ embE, float* __restrict__ dstv) {
  __shared__ float part[2];
  int g = blockIdx.x, c = threadIdx.x;
  int n0 = gstart[g], n1 = gstart[g + 1];
  float invg = 1.f / gs[g];
  float acc = 0.f;
  for (int n = n0; n < n1; ++n) acc = fmaf(hn[(size_t)n * 128 + c], scp[n] * invg, acc);
  float val = acc * embE[(size_t)g * 128 + c];
  float sq = val * val;
#pragma unroll
  for (int mm = 32; mm; mm >>= 1) sq += __shfl_xor(sq, mm, 64);
  if ((c & 63) == 0) part[c >> 6] = sq;
  __syncthreads();
  float nrm = sqrtf(part[0] + part[1]);
  dstv[(size_t)g * 128 + c] = elu_f(val / fmaxf(nrm, 1e-12f));
}

__global__ void final_combine(const float* __restrict__ e0, const float* __restrict__ e1,
                              float* __restrict__ out) {
  int idx = blockIdx.x * blockDim.x + threadIdx.x;
  if (idx >= GG * 128) return;
  out[idx] = 0.6f * e0[idx] + 0.4f * e1[idx];
}

// =====================================================================
extern "C" void kernel_launch(void* const* d_in, const int* in_sizes, int n_in,
                              void* d_out, int out_size, void* d_ws, size_t ws_size,
                              hipStream_t stream) {
  const float* x = (const float*)d_in[0];
  const float* edge_attr = (const float*)d_in[1];
  const int* edge_index = (const int*)d_in[2];
  const int* batch = (const int*)d_in[3];
  const float* w0 = (const float*)d_in[4];
  const float* b0 = (const float*)d_in[5];
  const float* we0 = (const float*)d_in[6];
  const float* be0 = (const float*)d_in[7];
  const float* ln0_g = (const float*)d_in[8];
  const float* ln0_b = (const float*)d_in[9];
  const float* qkv_w = (const float*)d_in[10];
  const float* qkv_b = (const float*)d_in[11];
  const float* edge_w = (const float*)d_in[12];
  const float* skip_w = (const float*)d_in[13];
  const float* skip_b = (const float*)d_in[14];
  const float* up_w = (const float*)d_in[15];
  const float* up_b = (const float*)d_in[16];
  const float* ng = (const float*)d_in[17];
  const float* nbeta = (const float*)d_in[18];
  const float* sag_wrel = (const float*)d_in[19];
  const float* sag_brel = (const float*)d_in[20];
  const float* sag_wroot = (const float*)d_in[21];
  const float* re_w = (const float*)d_in[22];
  const float* re_b = (const float*)d_in[23];
  const int* srcp = edge_index;
  const int* dstp = edge_index + EE;
  float* out = (float*)d_out;
  (void)in_sizes; (void)n_in;

  float* ws = (float*)d_ws;
  size_t o = 0;
  auto alloc = [&](size_t n) { n = (n + 3) & ~(size_t)3; float* p = ws + o; o += n; return p; };
  float* h = alloc((size_t)NN * 128);
  float* hn = alloc((size_t)NN * 128);
  float* racc = alloc((size_t)NN * 128);
  u16* nodebuf = (u16*)alloc((size_t)NN * 256);   // NN x 512 bf16 (q|k|v|qe)
  u16* ea = (u16*)alloc((size_t)EE * 32);         // EE x 64 bf16, CSR order
  int* csr_src = (int*)alloc(EE);
  int* deg = (int*)alloc(NN);
  int* row_start = (int*)alloc(NN + 1);
  int* cursor = (int*)alloc(NN);
  int* gstart = (int*)alloc(GG + 1);
  int* sg_perm = (int*)alloc(EE);
  int* scnt = (int*)alloc(GG);
  int* sg_start = (int*)alloc(GG + 1);
  int* sg_cursor = (int*)alloc(GG);
  float* cntf = alloc(GG);
  float* gsum_in = alloc(GG * 64);
  float* W2 = alloc(64 * 128);
  float* bvec = alloc(128);
  u16* upfrag = (u16*)alloc(2048);                // 4096 u16
  unsigned* gm = (unsigned*)alloc(GG);            // zero-block (gm, gs)
  float* gs = alloc(GG);
  float* gmean = alloc(GG);
  float* grstd = alloc(GG);
  float* BD = alloc(128 * 128);
  float* WQE = alloc(128 * 128);
  float* bqe = alloc(128);
  float* Wall = alloc(128 * 640);
  float* ball = alloc(640);
  float* hrel = alloc(NN);
  float* troot = alloc(NN);
  float* sc = alloc(NN);
  float* scp = alloc(NN);
  float* embE = alloc(GG * 128);
  float* embs0 = alloc(GG * 128);
  float* embs1 = alloc(GG * 128);

  const size_t need = o * sizeof(float);
  if (ws_size < need) {
    hipMemsetAsync(d_out, 0, (size_t)out_size * sizeof(float), stream);
    return;
  }

  auto gemm = [&](const float* A, const float* B, const float* bias, float* C, u16* C2,
                  int M, int Nn, int K, int act, int accum, int mode) {
    dim3 g((Nn + 63) / 64, (M + 63) / 64);
    gemm_kernel<<<g, 256, 0, stream>>>(A, B, bias, C, C2, M, Nn, K, act, accum, mode);
  };
  auto graph_ln = [&](const float* in, float* outp, const float* gamma, const float* beta) {
    ln_stats_block<<<GG, 256, 0, stream>>>(in, gstart, gmean, grstd);
    ln_apply<<<NN * 32 / 256, 256, 0, stream>>>(in, outp, batch, gmean, grstd, gamma, beta);
  };
  auto tconv = [&](int il) {
    const float* wq = qkv_w + (size_t)(il * 3 + 0) * 128 * 128;
    const float* wk = qkv_w + (size_t)(il * 3 + 1) * 128 * 128;
    const float* wv = qkv_w + (size_t)(il * 3 + 2) * 128 * 128;
    const float* bq = qkv_b + (il * 3 + 0) * 128;
    const float* bk = qkv_b + (il * 3 + 1) * 128;
    const float* bv = qkv_b + (il * 3 + 2) * 128;
    const float* we = edge_w + (size_t)il * 64 * 128;
    const float* wsk = skip_w + (size_t)il * 128 * 128;
    const float* bsk = skip_b + il * 128;
    build_wqe<<<129, 128, 0, stream>>>(wq, bq, we, WQE, bqe);
    build_wall<<<320, 256, 0, stream>>>(wq, wk, wv, WQE, wsk, bq, bk, bv, bqe, bsk, Wall, ball);
    build_bd<<<64, 256, 0, stream>>>(we, BD);
    gemm(h, Wall, ball, hn, nodebuf, NN, 640, 128, 0, 0, 2);  // q|k|v|qe (bf16) + skip->hn
    attn_node<<<NN / 4, 256, 0, stream>>>((const u32*)nodebuf, ea, row_start, csr_src, hn, racc);
    gemm(racc, BD, nullptr, hn, nullptr, NN, 128, 128, 0, 1, 0);  // hn += r @ BD
  };
  auto ea_mlp = [&](int il) {  // ea = elu(ea @ up_w[il] + up_b[il]) via MFMA
    build_upfrag<<<16, 256, 0, stream>>>(up_w + (size_t)il * 4096, upfrag);
    edge_gemm<<<2048, 256, 0, stream>>>(ea, upfrag, up_b + il * 64);
  };

  // one-time topology structures
  hipMemsetAsync(deg, 0, NN * sizeof(int), stream);
  hipMemsetAsync(scnt, 0, GG * sizeof(int), stream);
  csr_hist<<<(EE + 255) / 256, 256, 0, stream>>>(dstp, deg);
  csr_scan<<<1, 256, 0, stream>>>(deg, row_start, cursor);
  gstart_build<<<(NN + 256) / 256, 256, 0, stream>>>(batch, gstart);
  ea_enc<<<2048, 256, 0, stream>>>(edge_attr, we0, be0, srcp, dstp, cursor, csr_src, ea);
  sg_hist<<<(EE + 255) / 256, 256, 0, stream>>>(csr_src, batch, scnt);
  sg_scan<<<1, 256, 0, stream>>>(scnt, sg_start, sg_cursor, cntf);
  sg_fill<<<(EE + 255) / 256, 256, 0, stream>>>(csr_src, batch, sg_cursor, sg_perm);
  // node encoder + first LN
  gemm(x, w0, b0, hn, nullptr, NN, 128, 64, 0, 0, 0);
  graph_ln(hn, h, ln0_g, ln0_b);

  for (int i = 0; i < 2; ++i) {
    tconv(i * 2 + 0);
    graph_ln(hn, h, ng + (i * 2) * 128, nbeta + (i * 2) * 128);
    ea_mlp(i * 2);
    tconv(i * 2 + 1);
    // SAG pooling on pre-LN conv2 output hn; edge emb via linearity:
    // sum(pre-elu ea2) per src-graph = (sum ea)@up + cnt*ub, folded with re_w.
    hipMemsetAsync(gm, 0, 2 * GG * sizeof(float), stream);  // gm, gs
    gsum_pre<<<GG, 256, 0, stream>>>(ea, sg_start, sg_perm, gsum_in);
    build_w2<<<33, 256, 0, stream>>>(up_w + (size_t)(i * 2 + 1) * 4096,
                                     up_b + (i * 2 + 1) * 64,
                                     re_w + (size_t)i * 64 * 128, W2, bvec);
    ea_mlp(i * 2 + 1);
    node_dots<<<NN / 4, 256, 0, stream>>>(hn, sag_wrel + i * 128, sag_wroot + i * 128, hrel, troot);
    sag_gather<<<(NN + 255) / 256, 256, 0, stream>>>(hrel, troot, sag_brel + i, row_start,
                                                     csr_src, batch, sc, gm);
    sag_exp<<<(NN + 255) / 256, 256, 0, stream>>>(sc, batch, gm, gs, scp);
    emb_e_kernel<<<GG, 128, 0, stream>>>(gsum_in, cntf, W2, bvec, re_b + i * 128, embE);
    emb_block<<<GG, 128, 0, stream>>>(hn, scp, gs, gstart, embE, i == 0 ? embs0 : embs1);
    graph_ln(hn, h, ng + (i * 2 + 1) * 128, nbeta + (i * 2 + 1) * 128);
  }
  final_combine<<<GG * 128 / 256, 256, 0, stream>>>(embs0, embs1, out);
}

// Round 6
// 2727.163 us; speedup vs baseline: 4.3556x; 1.2530x over previous
//
#include <hip/hip_runtime.h>
#include <math.h>

#define NN 50000
#define EE 800000
#define GG 256

typedef unsigned short u16;
typedef unsigned int u32;
typedef __attribute__((ext_vector_type(4))) float f32x4;
typedef __attribute__((ext_vector_type(8))) short bf16x8;

__device__ __forceinline__ float elu_f(float x) { return x > 0.f ? x : expm1f(x); }

__device__ __forceinline__ unsigned fenc(float f) {
  unsigned b = __float_as_uint(f);
  return (b & 0x80000000u) ? ~b : (b | 0x80000000u);
}
__device__ __forceinline__ float fdec(unsigned u) {
  return __uint_as_float((u & 0x80000000u) ? (u ^ 0x80000000u) : ~u);
}
__device__ __forceinline__ u16 f2b(float f) {
  u32 u = __float_as_uint(f);
  u32 r = (u + 0x7fffu + ((u >> 16) & 1u)) >> 16;
  return (u16)r;
}
__device__ __forceinline__ float bf2f(u16 u) { return __uint_as_float(((u32)u) << 16); }
__device__ __forceinline__ float lo2f(u32 p) { return __uint_as_float(p << 16); }
__device__ __forceinline__ float hi2f(u32 p) { return __uint_as_float(p & 0xffff0000u); }

__device__ __forceinline__ float wred64(float v) {
#pragma unroll
  for (int m = 32; m; m >>= 1) v += __shfl_xor(v, m, 64);
  return v;
}

// ---------------- generic tiled f32 GEMM: C = act(A@B + bias (+C)) ----------------
__global__ __launch_bounds__(256) void gemm_kernel(
    const float* __restrict__ A, const float* __restrict__ B,
    const float* __restrict__ bias, float* __restrict__ C,
    int M, int Nn, int K, int act, int accum) {
  __shared__ float As[16][68];
  __shared__ float Bs[16][68];
  const int bm = blockIdx.y * 64;
  const int bn = blockIdx.x * 64;
  const int tid = threadIdx.x;
  const int tx = tid & 15, ty = tid >> 4;
  const int lr = tid >> 2;
  const int lk = (tid & 3) << 2;
  float acc[4][4] = {};
  for (int k0 = 0; k0 < K; k0 += 16) {
    int arow = bm + lr;
    float4 a4 = {0.f, 0.f, 0.f, 0.f};
    if (arow < M) a4 = *reinterpret_cast<const float4*>(A + (size_t)arow * K + k0 + lk);
    As[lk + 0][lr] = a4.x; As[lk + 1][lr] = a4.y;
    As[lk + 2][lr] = a4.z; As[lk + 3][lr] = a4.w;
    float4 b4 = *reinterpret_cast<const float4*>(B + (size_t)(k0 + ty) * Nn + bn + tx * 4);
    *reinterpret_cast<float4*>(&Bs[ty][tx * 4]) = b4;
    __syncthreads();
#pragma unroll
    for (int kk = 0; kk < 16; ++kk) {
      float4 av = *reinterpret_cast<const float4*>(&As[kk][ty * 4]);
      float4 bv = *reinterpret_cast<const float4*>(&Bs[kk][tx * 4]);
      float a_[4] = {av.x, av.y, av.z, av.w};
      float b_[4] = {bv.x, bv.y, bv.z, bv.w};
#pragma unroll
      for (int ii = 0; ii < 4; ++ii)
#pragma unroll
        for (int jj = 0; jj < 4; ++jj)
          acc[ii][jj] = fmaf(a_[ii], b_[jj], acc[ii][jj]);
    }
    __syncthreads();
  }
#pragma unroll
  for (int ii = 0; ii < 4; ++ii) {
    int row = bm + ty * 4 + ii;
    if (row >= M) continue;
#pragma unroll
    for (int jj = 0; jj < 4; ++jj) {
      int col = bn + tx * 4 + jj;
      float val = acc[ii][jj];
      if (bias) val += bias[col];
      if (accum) val += C[(size_t)row * Nn + col];
      if (act) val = elu_f(val);
      C[(size_t)row * Nn + col] = val;
    }
  }
}

// ---------------- CSR build ----------------
__global__ void csr_hist(const int* __restrict__ dst, int* __restrict__ deg) {
  int e = blockIdx.x * blockDim.x + threadIdx.x;
  if (e < EE) atomicAdd(&deg[dst[e]], 1);
}

__global__ void csr_scan(const int* __restrict__ deg, int* __restrict__ row_start,
                         int* __restrict__ cursor) {
  __shared__ int sums[256];
  int t = threadIdx.x;
  const int CH = (NN + 255) / 256;
  int base = t * CH;
  int local = 0;
  for (int i = 0; i < CH; ++i) {
    int idx = base + i;
    if (idx < NN) local += deg[idx];
  }
  sums[t] = local;
  __syncthreads();
  for (int off = 1; off < 256; off <<= 1) {
    int tmp = (t >= off) ? sums[t - off] : 0;
    __syncthreads();
    sums[t] += tmp;
    __syncthreads();
  }
  int run = sums[t] - local;
  for (int i = 0; i < CH; ++i) {
    int idx = base + i;
    if (idx < NN) {
      row_start[idx] = run;
      cursor[idx] = run;
      run += deg[idx];
    }
  }
  if (t == 255) row_start[NN] = run;
}

__global__ void gstart_build(const int* __restrict__ batch, int* __restrict__ gstart) {
  int n = blockIdx.x * blockDim.x + threadIdx.x;
  if (n > NN) return;
  int b = (n < NN) ? batch[n] : GG;
  int pb = (n == 0) ? -1 : batch[n - 1];
  for (int g = pb + 1; g <= b; ++g) gstart[g] = n;
}

// out-CSR (by src node) over dst-CSR positions: low-contention bucketing
__global__ void out_hist(const int* __restrict__ csr_src, int* __restrict__ odeg) {
  int pos = blockIdx.x * blockDim.x + threadIdx.x;
  if (pos < EE) atomicAdd(&odeg[csr_src[pos]], 1);
}

__global__ void out_fill(const int* __restrict__ csr_src, int* __restrict__ ocursor,
                         int* __restrict__ operm) {
  int pos = blockIdx.x * blockDim.x + threadIdx.x;
  if (pos < EE) {
    int slot = atomicAdd(&ocursor[csr_src[pos]], 1);
    operm[slot] = pos;
  }
}

__global__ void sgstart_build(const int* __restrict__ out_start, const int* __restrict__ gstart,
                              int* __restrict__ sg_start) {
  int t = blockIdx.x * blockDim.x + threadIdx.x;
  if (t <= GG) sg_start[t] = out_start[gstart[t]];
}

// edge encoder: elu(edge_attr[e] @ we0 + be0) placed at CSR position
__global__ __launch_bounds__(256) void ea_enc(const float* __restrict__ edge_attr,
                                              const float* __restrict__ we0,
                                              const float* __restrict__ be0,
                                              const int* __restrict__ src,
                                              const int* __restrict__ dst,
                                              int* __restrict__ cursor,
                                              int* __restrict__ csr_src,
                                              u16* __restrict__ ea) {
  int lane = threadIdx.x & 63;
  float wc[16];
#pragma unroll
  for (int j = 0; j < 16; ++j) wc[j] = we0[j * 64 + lane];
  float bl = be0[lane];
  int wg = (blockIdx.x * blockDim.x + threadIdx.x) >> 6;
  int nw = (gridDim.x * blockDim.x) >> 6;
  for (int e = wg; e < EE; e += nw) {
    float xr = edge_attr[(size_t)e * 16 + (lane & 15)];
    int pos = 0;
    if (lane == 0) pos = atomicAdd(&cursor[dst[e]], 1);
    pos = __shfl(pos, 0, 64);
    if (lane == 0) csr_src[pos] = src[e];
    float acc = bl;
#pragma unroll
    for (int j = 0; j < 16; ++j) acc = fmaf(__shfl(xr, j, 64), wc[j], acc);
    ea[(size_t)pos * 64 + lane] = f2b(elu_f(acc));
  }
}

// ---------------- graph LayerNorm ----------------
__global__ __launch_bounds__(256) void ln_stats_block(const float* __restrict__ h,
                                                      const int* __restrict__ gstart,
                                                      float* __restrict__ gmean,
                                                      float* __restrict__ grstd) {
  __shared__ float ls[4], lss[4];
  int g = blockIdx.x, t = threadIdx.x;
  int n0 = gstart[g], n1 = gstart[g + 1];
  int total4 = (n1 - n0) * 32;
  const float4* base = (const float4*)(h + (size_t)n0 * 128);
  float s = 0.f, ss = 0.f;
  for (int i = t; i < total4; i += 256) {
    float4 v = base[i];
    s += v.x + v.y + v.z + v.w;
    ss += v.x * v.x + v.y * v.y + v.z * v.z + v.w * v.w;
  }
  s = wred64(s);
  ss = wred64(ss);
  if ((t & 63) == 0) { ls[t >> 6] = s; lss[t >> 6] = ss; }
  __syncthreads();
  if (t == 0) {
    float S = ls[0] + ls[1] + ls[2] + ls[3];
    float SS = lss[0] + lss[1] + lss[2] + lss[3];
    float cnt = fmaxf((float)(n1 - n0) * 128.f, 1.0f);
    float mean = S / cnt;
    float var = fmaxf(SS / cnt - mean * mean, 0.f);
    gmean[g] = mean;
    grstd[g] = rsqrtf(var + 1e-5f);
  }
}

// LN apply -> split bf16 (hi + lo residual) for accurate MFMA A-operand
__global__ __launch_bounds__(256) void ln_apply(const float* __restrict__ in,
                                                u16* __restrict__ out_hi,
                                                u16* __restrict__ out_lo,
                                                const int* __restrict__ batch,
                                                const float* __restrict__ gmean,
                                                const float* __restrict__ grstd,
                                                const float* __restrict__ gamma,
                                                const float* __restrict__ beta) {
  int idx = blockIdx.x * blockDim.x + threadIdx.x;
  if (idx >= NN * 32) return;
  int n = idx >> 5, c4 = (idx & 31) * 4;
  int g = batch[n];
  float mean = gmean[g], rstd = grstd[g];
  float4 xv = *reinterpret_cast<const float4*>(in + (size_t)n * 128 + c4);
  float4 gv = *reinterpret_cast<const float4*>(gamma + c4);
  float4 bv = *reinterpret_cast<const float4*>(beta + c4);
  float v0 = elu_f((xv.x - mean) * rstd * gv.x + bv.x);
  float v1 = elu_f((xv.y - mean) * rstd * gv.y + bv.y);
  float v2 = elu_f((xv.z - mean) * rstd * gv.z + bv.z);
  float v3 = elu_f((xv.w - mean) * rstd * gv.w + bv.w);
  u16 h0 = f2b(v0), h1 = f2b(v1), h2 = f2b(v2), h3 = f2b(v3);
  uint2 hi = {(u32)h0 | ((u32)h1 << 16), (u32)h2 | ((u32)h3 << 16)};
  uint2 lo = {(u32)f2b(v0 - bf2f(h0)) | ((u32)f2b(v1 - bf2f(h1)) << 16),
              (u32)f2b(v2 - bf2f(h2)) | ((u32)f2b(v3 - bf2f(h3)) << 16)};
  *reinterpret_cast<uint2*>(out_hi + (size_t)n * 128 + c4) = hi;
  *reinterpret_cast<uint2*>(out_lo + (size_t)n * 128 + c4) = lo;
}

// ---------------- per-layer weight transforms ----------------
__global__ void build_bd(const float* __restrict__ we, float* __restrict__ BD) {
  int idx = blockIdx.x * blockDim.x + threadIdx.x;
  if (idx >= 128 * 128) return;
  int rr = idx >> 7, cc = idx & 127;
  BD[idx] = ((rr >> 6) == (cc >> 6)) ? we[(rr & 63) * 128 + cc] : 0.f;
}

__global__ void build_wqe(const float* __restrict__ wq, const float* __restrict__ bq,
                          const float* __restrict__ we, float* __restrict__ WQE,
                          float* __restrict__ bqe) {
  int col = threadIdx.x;
  int row = blockIdx.x;
  int hh = col >> 6, j = col & 63;
  const float* wrow = (row < 128) ? (wq + (size_t)row * 128) : bq;
  float acc = 0.f;
  for (int c = 0; c < 64; ++c) acc += wrow[hh * 64 + c] * we[(size_t)j * 128 + hh * 64 + c];
  if (row < 128) WQE[(size_t)row * 128 + col] = acc;
  else bqe[col] = acc;
}

__global__ void build_wall(const float* __restrict__ wq, const float* __restrict__ wk,
                           const float* __restrict__ wv, const float* __restrict__ WQE,
                           const float* __restrict__ wsk,
                           const float* __restrict__ bq, const float* __restrict__ bk,
                           const float* __restrict__ bv, const float* __restrict__ bqe,
                           const float* __restrict__ bsk,
                           float* __restrict__ Wall, float* __restrict__ ball) {
  int idx = blockIdx.x * 256 + threadIdx.x;
  if (idx < 128 * 640) {
    int rr = idx / 640, cc = idx % 640;
    int sel = cc >> 7, c = cc & 127;
    const float* s = sel == 0 ? wq : sel == 1 ? wk : sel == 2 ? wv : sel == 3 ? WQE : wsk;
    Wall[idx] = s[rr * 128 + c];
  }
  if (idx < 640) {
    int sel = idx >> 7, c = idx & 127;
    const float* s = sel == 0 ? bq : sel == 1 ? bk : sel == 2 ? bv : sel == 3 ? bqe : bsk;
    ball[idx] = s[c];
  }
}

// Wall f32[128][640] -> split bf16 MFMA B-fragments (hi + lo)
__global__ void build_wfrag(const float* __restrict__ Wall, u16* __restrict__ Wfrag_hi,
                            u16* __restrict__ Wfrag_lo) {
  int idx = blockIdx.x * 256 + threadIdx.x;  // 81920 total
  if (idx >= 81920) return;
  int j = idx & 7, lane = (idx >> 3) & 63, rest = idx >> 9;
  int tg = rest % 40, s = rest / 40;
  int k = s * 32 + (lane >> 4) * 8 + j;
  int col = tg * 16 + (lane & 15);
  float w = Wall[(size_t)k * 640 + col];
  u16 hi = f2b(w);
  Wfrag_hi[idx] = hi;
  Wfrag_lo[idx] = f2b(w - bf2f(hi));
}

// up[64x64] f32 -> bf16 fragments, k = s*32 + (lane>>4)*8 + j
__global__ void build_upfrag(const float* __restrict__ up, u16* __restrict__ upfrag) {
  int idx = blockIdx.x * 256 + threadIdx.x;
  if (idx >= 4096) return;
  int j = idx & 7, lane = (idx >> 3) & 63, st = idx >> 9;
  int s = st >> 2, t = st & 3;
  int k = s * 32 + (lane >> 4) * 8 + j;
  int c = t * 16 + (lane & 15);
  upfrag[idx] = f2b(up[k * 64 + c]);
}

// W2 = up @ re_w [64x128]; bvec = ub @ re_w [128]
__global__ void build_w2(const float* __restrict__ up, const float* __restrict__ ub,
                         const float* __restrict__ re_w, float* __restrict__ W2,
                         float* __restrict__ bvec) {
  int idx = blockIdx.x * 256 + threadIdx.x;
  if (idx < 64 * 128) {
    int k_ = idx >> 7, c = idx & 127;
    float a = 0.f;
    for (int j = 0; j < 64; ++j) a = fmaf(up[k_ * 64 + j], re_w[j * 128 + c], a);
    W2[idx] = a;
  } else if (idx < 64 * 128 + 128) {
    int c = idx - 64 * 128;
    float a = 0.f;
    for (int j = 0; j < 64; ++j) a = fmaf(ub[j], re_w[j * 128 + c], a);
    bvec[c] = a;
  }
}

// ---------------- split-precision MFMA node GEMM ----------------
// acc = h_hi@W_hi + h_hi@W_lo + h_lo@W_hi  (~f32 accuracy)
__global__ __launch_bounds__(256) void node_gemm(const u16* __restrict__ h_hi,
                                                 const u16* __restrict__ h_lo,
                                                 const u16* __restrict__ Wfrag_hi,
                                                 const u16* __restrict__ Wfrag_lo,
                                                 const float* __restrict__ ball,
                                                 u16* __restrict__ nodebuf,
                                                 float* __restrict__ hn) {
  int tid = threadIdx.x;
  int lane = tid & 63;
  int wv = tid >> 6;
  int cb = blockIdx.x;                       // 0..9 (64-col block)
  int rbase = blockIdx.y * 64 + wv * 16;     // 16 rows per wave
  int rif = lane & 15, kg = lane >> 4;
  f32x4 acc[4] = {};
  int arow = rbase + rif;
  bool rowok = arow < NN;
  const u16* aph = h_hi + (size_t)arow * 128 + kg * 8;
  const u16* apl = h_lo + (size_t)arow * 128 + kg * 8;
#pragma unroll
  for (int s = 0; s < 4; ++s) {
    bf16x8 ah = {}, al = {};
    if (rowok) {
      ah = *reinterpret_cast<const bf16x8*>(aph + s * 32);
      al = *reinterpret_cast<const bf16x8*>(apl + s * 32);
    }
#pragma unroll
    for (int t = 0; t < 4; ++t) {
      size_t fo = ((size_t)((s * 40 + cb * 4 + t) * 64 + lane)) * 8;
      bf16x8 bh = *reinterpret_cast<const bf16x8*>(Wfrag_hi + fo);
      bf16x8 bl = *reinterpret_cast<const bf16x8*>(Wfrag_lo + fo);
      acc[t] = __builtin_amdgcn_mfma_f32_16x16x32_bf16(ah, bh, acc[t], 0, 0, 0);
      acc[t] = __builtin_amdgcn_mfma_f32_16x16x32_bf16(ah, bl, acc[t], 0, 0, 0);
      acc[t] = __builtin_amdgcn_mfma_f32_16x16x32_bf16(al, bh, acc[t], 0, 0, 0);
    }
  }
  // D: col = (cb*4+t)*16 + rif, row = rbase + kg*4 + reg
#pragma unroll
  for (int t = 0; t < 4; ++t) {
    int col = (cb * 4 + t) * 16 + rif;
    float bia = ball[col];
#pragma unroll
    for (int rg = 0; rg < 4; ++rg) {
      int row = rbase + kg * 4 + rg;
      if (row < NN) {
        float val = acc[t][rg] + bia;
        if (col < 512) nodebuf[(size_t)row * 512 + col] = f2b(val);
        else hn[(size_t)row * 128 + col - 512] = val;
      }
    }
  }
}

// ---------------- MFMA edge GEMM: ea = elu(ea @ up + ub), in place ----------------
__global__ __launch_bounds__(256) void edge_gemm(u16* __restrict__ ea,
                                                 const u16* __restrict__ upfrag,
                                                 const float* __restrict__ ub) {
  int lane = threadIdx.x & 63;
  int gwave = (blockIdx.x * 256 + threadIdx.x) >> 6;
  int nwaves = (gridDim.x * 256) >> 6;
  bf16x8 bfrag[2][4];
#pragma unroll
  for (int s = 0; s < 2; ++s)
#pragma unroll
    for (int t = 0; t < 4; ++t)
      bfrag[s][t] = *reinterpret_cast<const bf16x8*>(upfrag + ((size_t)((s * 4 + t) * 64 + lane)) * 8);
  float bias_c[4];
#pragma unroll
  for (int t = 0; t < 4; ++t) bias_c[t] = ub[t * 16 + (lane & 15)];
  const int rif = lane & 15;
  const int kg = lane >> 4;
  for (int mt = gwave; mt < EE / 16; mt += nwaves) {
    size_t rowbase = (size_t)mt * 16;
    const u16* arow = ea + (rowbase + rif) * 64;
    bf16x8 a0 = *reinterpret_cast<const bf16x8*>(arow + kg * 8);
    bf16x8 a1 = *reinterpret_cast<const bf16x8*>(arow + 32 + kg * 8);
    f32x4 acc[4] = {};
#pragma unroll
    for (int t = 0; t < 4; ++t) {
      acc[t] = __builtin_amdgcn_mfma_f32_16x16x32_bf16(a0, bfrag[0][t], acc[t], 0, 0, 0);
      acc[t] = __builtin_amdgcn_mfma_f32_16x16x32_bf16(a1, bfrag[1][t], acc[t], 0, 0, 0);
    }
#pragma unroll
    for (int t = 0; t < 4; ++t)
#pragma unroll
      for (int rg = 0; rg < 4; ++rg) {
        float val = acc[t][rg] + bias_c[t];
        ea[(rowbase + kg * 4 + rg) * 64 + t * 16 + rif] = f2b(elu_f(val));
      }
  }
}

// per-src-graph sum of current ea rows (contiguous perm range per graph)
__global__ __launch_bounds__(256) void gsum_pre(const u16* __restrict__ ea,
                                                const int* __restrict__ sg_start,
                                                const int* __restrict__ sg_perm,
                                                float* __restrict__ gsum_in) {
  __shared__ float red[8][64];
  int g = blockIdx.x, t = threadIdx.x;
  int c2 = t & 31;
  int rgrp = t >> 5;
  int p0 = sg_start[g], p1 = sg_start[g + 1];
  float slo = 0.f, shi = 0.f;
  for (int i = p0 + rgrp; i < p1; i += 8) {
    int pos = sg_perm[i];
    u32 w = ((const u32*)ea)[(size_t)pos * 32 + c2];
    slo += lo2f(w);
    shi += hi2f(w);
  }
  red[rgrp][c2 * 2] = slo;
  red[rgrp][c2 * 2 + 1] = shi;
  __syncthreads();
  if (t < 64) {
    float a = 0.f;
#pragma unroll
    for (int rr = 0; rr < 8; ++rr) a += red[rr][t];
    gsum_in[(size_t)g * 64 + t] = a;
  }
}

// embE = elu(gsum_in @ W2 + cnt*bvec + re_b)
__global__ void emb_e_kernel(const float* __restrict__ gsum_in, const int* __restrict__ sg_start,
                             const float* __restrict__ W2, const float* __restrict__ bvec,
                             const float* __restrict__ re_b, float* __restrict__ embE) {
  int g = blockIdx.x, c = threadIdx.x;
  float cnt = (float)(sg_start[g + 1] - sg_start[g]);
  float a = re_b[c] + cnt * bvec[c];
  for (int k_ = 0; k_ < 64; ++k_) a = fmaf(gsum_in[(size_t)g * 64 + k_], W2[k_ * 128 + c], a);
  embE[(size_t)g * 128 + c] = elu_f(a);
}

// ---------------- fused flash-style attention, one wave per dst node ----------------
__global__ __launch_bounds__(256) void attn_node(const u32* __restrict__ nodebuf,
                                                 const u16* __restrict__ ea,
                                                 const int* __restrict__ row_start,
                                                 const int* __restrict__ csr_src,
                                                 float* __restrict__ hn,
                                                 float* __restrict__ r) {
  int d = (blockIdx.x * blockDim.x + threadIdx.x) >> 6;
  if (d >= NN) return;
  int lane = threadIdx.x & 63;
  int p0 = row_start[d], p1 = row_start[d + 1];
  size_t ob = (size_t)d * 128 + lane * 2;
  if (p0 == p1) {
    r[ob] = 0.f;
    r[ob + 1] = 0.f;
    return;
  }
  size_t dbase = (size_t)d * 256;
  u32 qv = nodebuf[dbase + lane];
  u32 qev = nodebuf[dbase + 192 + lane];
  float m = -3.4e38f, ssum = 0.f, a0 = 0.f, a1 = 0.f, r0 = 0.f, r1 = 0.f;
  for (int pos = p0; pos < p1; ++pos) {
    int s = csr_src[pos];
    u32 kv = nodebuf[(size_t)s * 256 + 64 + lane];
    u32 vv = nodebuf[(size_t)s * 256 + 128 + lane];
    u32 eav = ((const u32*)ea)[(size_t)pos * 32 + (lane & 31)];
    float p = lo2f(qv) * lo2f(kv) + hi2f(qv) * hi2f(kv) +
              lo2f(qev) * lo2f(eav) + hi2f(qev) * hi2f(eav);
#pragma unroll
    for (int mm = 16; mm; mm >>= 1) p += __shfl_xor(p, mm, 64);
    float l = p * 0.125f;
    float mn = fmaxf(m, l);
    float f = __expf(m - mn);
    float w = __expf(l - mn);
    ssum = ssum * f + w;
    a0 = a0 * f + w * lo2f(vv);
    a1 = a1 * f + w * hi2f(vv);
    r0 = r0 * f + w * lo2f(eav);
    r1 = r1 * f + w * hi2f(eav);
    m = mn;
  }
  float inv = 1.f / ssum;
  hn[ob] += a0 * inv;
  hn[ob + 1] += a1 * inv;
  r[ob] = r0 * inv;
  r[ob + 1] = r1 * inv;
}

// ---------------- SAG pooling ----------------
__global__ __launch_bounds__(256) void node_dots(const float* __restrict__ hn,
                                                 const float* __restrict__ wrel,
                                                 const float* __restrict__ wroot,
                                                 float* __restrict__ hrel,
                                                 float* __restrict__ troot) {
  int n = (blockIdx.x * blockDim.x + threadIdx.x) >> 6;
  if (n >= NN) return;
  int lane = threadIdx.x & 63;
  float x0 = hn[(size_t)n * 128 + lane], x1 = hn[(size_t)n * 128 + 64 + lane];
  float tr = wred64(x0 * wrel[lane] + x1 * wrel[64 + lane]);
  float tt = wred64(x0 * wroot[lane] + x1 * wroot[64 + lane]);
  if (lane == 0) { hrel[n] = tr; troot[n] = tt; }
}

__global__ __launch_bounds__(256) void sag_gather(const float* __restrict__ hrel,
                                                  const float* __restrict__ troot,
                                                  const float* __restrict__ brel,
                                                  const int* __restrict__ row_start,
                                                  const int* __restrict__ csr_src,
                                                  const int* __restrict__ batch,
                                                  float* __restrict__ sc, unsigned* __restrict__ gm) {
  int n = blockIdx.x * blockDim.x + threadIdx.x;
  if (n >= NN) return;
  float s = 0.f;
  int p1 = row_start[n + 1];
  for (int pos = row_start[n]; pos < p1; ++pos) s += hrel[csr_src[pos]];
  float v = s + troot[n] + brel[0];
  sc[n] = v;
  atomicMax(&gm[batch[n]], fenc(v));
}

__global__ __launch_bounds__(256) void sag_exp(const float* __restrict__ sc,
                                               const int* __restrict__ batch,
                                               const unsigned* __restrict__ gm,
                                               float* __restrict__ gs, float* __restrict__ scp) {
  int n = blockIdx.x * blockDim.x + threadIdx.x;
  if (n >= NN) return;
  int g = batch[n];
  float p = __expf(sc[n] - fdec(gm[g]));
  scp[n] = p;
  atomicAdd(&gs[g], p);
}

__global__ void emb_block(const float* __restrict__ hn, const float* __restrict__ scp,
                          const float* __restrict__ gs, const int* __restrict__ gstart,
                          const float* __restrict__ embE, float* __restrict__ dstv) {
  __shared__ float part[2];
  int g = blockIdx.x, c = threadIdx.x;
  int n0 = gstart[g], n1 = gstart[g + 1];
  float invg = 1.f / gs[g];
  float acc = 0.f;
  for (int n = n0; n < n1; ++n) acc = fmaf(hn[(size_t)n * 128 + c], scp[n] * invg, acc);
  float val = acc * embE[(size_t)g * 128 + c];
  float sq = val * val;
#pragma unroll
  for (int mm = 32; mm; mm >>= 1) sq += __shfl_xor(sq, mm, 64);
  if ((c & 63) == 0) part[c >> 6] = sq;
  __syncthreads();
  float nrm = sqrtf(part[0] + part[1]);
  dstv[(size_t)g * 128 + c] = elu_f(val / fmaxf(nrm, 1e-12f));
}

__global__ void final_combine(const float* __restrict__ e0, const float* __restrict__ e1,
                              float* __restrict__ out) {
  int idx = blockIdx.x * blockDim.x + threadIdx.x;
  if (idx >= GG * 128) return;
  out[idx] = 0.6f * e0[idx] + 0.4f * e1[idx];
}

// =====================================================================
extern "C" void kernel_launch(void* const* d_in, const int* in_sizes, int n_in,
                              void* d_out, int out_size, void* d_ws, size_t ws_size,
                              hipStream_t stream) {
  const float* x = (const float*)d_in[0];
  const float* edge_attr = (const float*)d_in[1];
  const int* edge_index = (const int*)d_in[2];
  const int* batch = (const int*)d_in[3];
  const float* w0 = (const float*)d_in[4];
  const float* b0 = (const float*)d_in[5];
  const float* we0 = (const float*)d_in[6];
  const float* be0 = (const float*)d_in[7];
  const float* ln0_g = (const float*)d_in[8];
  const float* ln0_b = (const float*)d_in[9];
  const float* qkv_w = (const float*)d_in[10];
  const float* qkv_b = (const float*)d_in[11];
  const float* edge_w = (const float*)d_in[12];
  const float* skip_w = (const float*)d_in[13];
  const float* skip_b = (const float*)d_in[14];
  const float* up_w = (const float*)d_in[15];
  const float* up_b = (const float*)d_in[16];
  const float* ng = (const float*)d_in[17];
  const float* nbeta = (const float*)d_in[18];
  const float* sag_wrel = (const float*)d_in[19];
  const float* sag_brel = (const float*)d_in[20];
  const float* sag_wroot = (const float*)d_in[21];
  const float* re_w = (const float*)d_in[22];
  const float* re_b = (const float*)d_in[23];
  const int* srcp = edge_index;
  const int* dstp = edge_index + EE;
  float* out = (float*)d_out;
  (void)in_sizes; (void)n_in;

  float* ws = (float*)d_ws;
  size_t o = 0;
  auto alloc = [&](size_t n) { n = (n + 3) & ~(size_t)3; float* p = ws + o; o += n; return p; };
  u16* h_hi = (u16*)alloc((size_t)NN * 64);       // NN x 128 bf16
  u16* h_lo = (u16*)alloc((size_t)NN * 64);       // NN x 128 bf16 residual
  float* hn = alloc((size_t)NN * 128);
  float* racc = alloc((size_t)NN * 128);
  u16* nodebuf = (u16*)alloc((size_t)NN * 256);   // NN x 512 bf16 (q|k|v|qe)
  u16* ea = (u16*)alloc((size_t)EE * 32);         // EE x 64 bf16, dst-CSR order
  int* csr_src = (int*)alloc(EE);
  int* deg = (int*)alloc(NN);
  int* row_start = (int*)alloc(NN + 1);
  int* cursor = (int*)alloc(NN);
  int* out_start = (int*)alloc(NN + 1);
  int* gstart = (int*)alloc(GG + 1);
  int* sg_perm = (int*)alloc(EE);
  int* sg_start = (int*)alloc(GG + 1);
  float* gsum_in = alloc(GG * 64);
  float* W2 = alloc(64 * 128);
  float* bvec = alloc(128);
  u16* upfrag = (u16*)alloc(2048);                // 4096 u16
  u16* Wfrag_hi = (u16*)alloc(40960);             // 81920 u16
  u16* Wfrag_lo = (u16*)alloc(40960);
  unsigned* gm = (unsigned*)alloc(GG);            // zero-block (gm, gs)
  float* gs = alloc(GG);
  float* gmean = alloc(GG);
  float* grstd = alloc(GG);
  float* BD = alloc(128 * 128);
  float* WQE = alloc(128 * 128);
  float* bqe = alloc(128);
  float* Wall = alloc(128 * 640);
  float* ball = alloc(640);
  float* hrel = alloc(NN);
  float* troot = alloc(NN);
  float* sc = alloc(NN);
  float* scp = alloc(NN);
  float* embE = alloc(GG * 128);
  float* embs0 = alloc(GG * 128);
  float* embs1 = alloc(GG * 128);

  const size_t need = o * sizeof(float);
  if (ws_size < need) {
    hipMemsetAsync(d_out, 0, (size_t)out_size * sizeof(float), stream);
    return;
  }

  auto gemm = [&](const float* A, const float* B, const float* bias, float* C,
                  int M, int Nn, int K, int act, int accum) {
    dim3 g((Nn + 63) / 64, (M + 63) / 64);
    gemm_kernel<<<g, 256, 0, stream>>>(A, B, bias, C, M, Nn, K, act, accum);
  };
  auto graph_ln = [&](const float* in, const float* gamma, const float* beta) {
    ln_stats_block<<<GG, 256, 0, stream>>>(in, gstart, gmean, grstd);
    ln_apply<<<NN * 32 / 256, 256, 0, stream>>>(in, h_hi, h_lo, batch, gmean, grstd, gamma, beta);
  };
  auto tconv = [&](int il) {
    const float* wq = qkv_w + (size_t)(il * 3 + 0) * 128 * 128;
    const float* wk = qkv_w + (size_t)(il * 3 + 1) * 128 * 128;
    const float* wv = qkv_w + (size_t)(il * 3 + 2) * 128 * 128;
    const float* bq = qkv_b + (il * 3 + 0) * 128;
    const float* bk = qkv_b + (il * 3 + 1) * 128;
    const float* bv = qkv_b + (il * 3 + 2) * 128;
    const float* we = edge_w + (size_t)il * 64 * 128;
    const float* wsk = skip_w + (size_t)il * 128 * 128;
    const float* bsk = skip_b + il * 128;
    build_wqe<<<129, 128, 0, stream>>>(wq, bq, we, WQE, bqe);
    build_wall<<<320, 256, 0, stream>>>(wq, wk, wv, WQE, wsk, bq, bk, bv, bqe, bsk, Wall, ball);
    build_wfrag<<<320, 256, 0, stream>>>(Wall, Wfrag_hi, Wfrag_lo);
    build_bd<<<64, 256, 0, stream>>>(we, BD);
    dim3 ng2(10, (NN + 63) / 64);
    node_gemm<<<ng2, 256, 0, stream>>>(h_hi, h_lo, Wfrag_hi, Wfrag_lo, ball, nodebuf, hn);
    attn_node<<<NN / 4, 256, 0, stream>>>((const u32*)nodebuf, ea, row_start, csr_src, hn, racc);
    gemm(racc, BD, nullptr, hn, NN, 128, 128, 0, 1);  // hn += r @ BD
  };
  auto ea_mlp = [&](int il) {
    build_upfrag<<<16, 256, 0, stream>>>(up_w + (size_t)il * 4096, upfrag);
    edge_gemm<<<2048, 256, 0, stream>>>(ea, upfrag, up_b + il * 64);
  };

  // one-time topology structures
  hipMemsetAsync(deg, 0, NN * sizeof(int), stream);
  csr_hist<<<(EE + 255) / 256, 256, 0, stream>>>(dstp, deg);
  csr_scan<<<1, 256, 0, stream>>>(deg, row_start, cursor);
  gstart_build<<<(NN + 256) / 256, 256, 0, stream>>>(batch, gstart);
  ea_enc<<<2048, 256, 0, stream>>>(edge_attr, we0, be0, srcp, dstp, cursor, csr_src, ea);
  // out-CSR (by src node) -> per-src-graph contiguous position ranges
  hipMemsetAsync(deg, 0, NN * sizeof(int), stream);
  out_hist<<<(EE + 255) / 256, 256, 0, stream>>>(csr_src, deg);
  csr_scan<<<1, 256, 0, stream>>>(deg, out_start, cursor);
  out_fill<<<(EE + 255) / 256, 256, 0, stream>>>(csr_src, cursor, sg_perm);
  sgstart_build<<<2, 256, 0, stream>>>(out_start, gstart, sg_start);
  // node encoder + first LN
  gemm(x, w0, b0, hn, NN, 128, 64, 0, 0);
  graph_ln(hn, ln0_g, ln0_b);

  for (int i = 0; i < 2; ++i) {
    tconv(i * 2 + 0);
    graph_ln(hn, ng + (i * 2) * 128, nbeta + (i * 2) * 128);
    ea_mlp(i * 2);
    tconv(i * 2 + 1);
    // SAG pooling on pre-LN conv2 output hn; edge emb via linearity:
    // sum(pre-elu ea2) per src-graph = (sum ea)@up + cnt*ub, folded with re_w.
    hipMemsetAsync(gm, 0, 2 * GG * sizeof(float), stream);  // gm, gs
    gsum_pre<<<GG, 256, 0, stream>>>(ea, sg_start, sg_perm, gsum_in);
    build_w2<<<33, 256, 0, stream>>>(up_w + (size_t)(i * 2 + 1) * 4096,
                                     up_b + (i * 2 + 1) * 64,
                                     re_w + (size_t)i * 64 * 128, W2, bvec);
    ea_mlp(i * 2 + 1);
    node_dots<<<NN / 4, 256, 0, stream>>>(hn, sag_wrel + i * 128, sag_wroot + i * 128, hrel, troot);
    sag_gather<<<(NN + 255) / 256, 256, 0, stream>>>(hrel, troot, sag_brel + i, row_start,
                                                     csr_src, batch, sc, gm);
    sag_exp<<<(NN + 255) / 256, 256, 0, stream>>>(sc, batch, gm, gs, scp);
    emb_e_kernel<<<GG, 128, 0, stream>>>(gsum_in, sg_start, W2, bvec, re_b + i * 128, embE);
    emb_block<<<GG, 128, 0, stream>>>(hn, scp, gs, gstart, embE, i == 0 ? embs0 : embs1);
    graph_ln(hn, ng + (i * 2 + 1) * 128, nbeta + (i * 2 + 1) * 128);
  }
  final_combine<<<GG * 128 / 256, 256, 0, stream>>>(embs0, embs1, out);
}

// Round 7
// 2325.486 us; speedup vs baseline: 5.1079x; 1.1727x over previous
//
#include <hip/hip_runtime.h>
#include <math.h>

#define NN 50000
#define EE 800000
#define GG 256

typedef unsigned short u16;
typedef unsigned int u32;
typedef __attribute__((ext_vector_type(4))) float f32x4;
typedef __attribute__((ext_vector_type(8))) short bf16x8;

__device__ __forceinline__ float elu_f(float x) { return x > 0.f ? x : expm1f(x); }

__device__ __forceinline__ unsigned fenc(float f) {
  unsigned b = __float_as_uint(f);
  return (b & 0x80000000u) ? ~b : (b | 0x80000000u);
}
__device__ __forceinline__ float fdec(unsigned u) {
  return __uint_as_float((u & 0x80000000u) ? (u ^ 0x80000000u) : ~u);
}
__device__ __forceinline__ u16 f2b(float f) {
  u32 u = __float_as_uint(f);
  u32 r = (u + 0x7fffu + ((u >> 16) & 1u)) >> 16;
  return (u16)r;
}
__device__ __forceinline__ float bf2f(u16 u) { return __uint_as_float(((u32)u) << 16); }
__device__ __forceinline__ float lo2f(u32 p) { return __uint_as_float(p << 16); }
__device__ __forceinline__ float hi2f(u32 p) { return __uint_as_float(p & 0xffff0000u); }

__device__ __forceinline__ float wred64(float v) {
#pragma unroll
  for (int m = 32; m; m >>= 1) v += __shfl_xor(v, m, 64);
  return v;
}

// ---------------- generic tiled f32 GEMM: C = act(A@B + bias (+C)) ----------------
__global__ __launch_bounds__(256) void gemm_kernel(
    const float* __restrict__ A, const float* __restrict__ B,
    const float* __restrict__ bias, float* __restrict__ C,
    int M, int Nn, int K, int act, int accum) {
  __shared__ float As[16][68];
  __shared__ float Bs[16][68];
  const int bm = blockIdx.y * 64;
  const int bn = blockIdx.x * 64;
  const int tid = threadIdx.x;
  const int tx = tid & 15, ty = tid >> 4;
  const int lr = tid >> 2;
  const int lk = (tid & 3) << 2;
  float acc[4][4] = {};
  for (int k0 = 0; k0 < K; k0 += 16) {
    int arow = bm + lr;
    float4 a4 = {0.f, 0.f, 0.f, 0.f};
    if (arow < M) a4 = *reinterpret_cast<const float4*>(A + (size_t)arow * K + k0 + lk);
    As[lk + 0][lr] = a4.x; As[lk + 1][lr] = a4.y;
    As[lk + 2][lr] = a4.z; As[lk + 3][lr] = a4.w;
    float4 b4 = *reinterpret_cast<const float4*>(B + (size_t)(k0 + ty) * Nn + bn + tx * 4);
    *reinterpret_cast<float4*>(&Bs[ty][tx * 4]) = b4;
    __syncthreads();
#pragma unroll
    for (int kk = 0; kk < 16; ++kk) {
      float4 av = *reinterpret_cast<const float4*>(&As[kk][ty * 4]);
      float4 bv = *reinterpret_cast<const float4*>(&Bs[kk][tx * 4]);
      float a_[4] = {av.x, av.y, av.z, av.w};
      float b_[4] = {bv.x, bv.y, bv.z, bv.w};
#pragma unroll
      for (int ii = 0; ii < 4; ++ii)
#pragma unroll
        for (int jj = 0; jj < 4; ++jj)
          acc[ii][jj] = fmaf(a_[ii], b_[jj], acc[ii][jj]);
    }
    __syncthreads();
  }
#pragma unroll
  for (int ii = 0; ii < 4; ++ii) {
    int row = bm + ty * 4 + ii;
    if (row >= M) continue;
#pragma unroll
    for (int jj = 0; jj < 4; ++jj) {
      int col = bn + tx * 4 + jj;
      float val = acc[ii][jj];
      if (bias) val += bias[col];
      if (accum) val += C[(size_t)row * Nn + col];
      if (act) val = elu_f(val);
      C[(size_t)row * Nn + col] = val;
    }
  }
}

// ---------------- CSR build ----------------
__global__ void csr_hist(const int* __restrict__ dst, int* __restrict__ deg) {
  int e = blockIdx.x * blockDim.x + threadIdx.x;
  if (e < EE) atomicAdd(&deg[dst[e]], 1);
}

__global__ void csr_scan(const int* __restrict__ deg, int* __restrict__ row_start,
                         int* __restrict__ cursor) {
  __shared__ int sums[256];
  int t = threadIdx.x;
  const int CH = (NN + 255) / 256;
  int base = t * CH;
  int local = 0;
  for (int i = 0; i < CH; ++i) {
    int idx = base + i;
    if (idx < NN) local += deg[idx];
  }
  sums[t] = local;
  __syncthreads();
  for (int off = 1; off < 256; off <<= 1) {
    int tmp = (t >= off) ? sums[t - off] : 0;
    __syncthreads();
    sums[t] += tmp;
    __syncthreads();
  }
  int run = sums[t] - local;
  for (int i = 0; i < CH; ++i) {
    int idx = base + i;
    if (idx < NN) {
      row_start[idx] = run;
      cursor[idx] = run;
      run += deg[idx];
    }
  }
  if (t == 255) row_start[NN] = run;
}

__global__ void gstart_build(const int* __restrict__ batch, int* __restrict__ gstart) {
  int n = blockIdx.x * blockDim.x + threadIdx.x;
  if (n > NN) return;
  int b = (n < NN) ? batch[n] : GG;
  int pb = (n == 0) ? -1 : batch[n - 1];
  for (int g = pb + 1; g <= b; ++g) gstart[g] = n;
}

__global__ void out_hist(const int* __restrict__ csr_src, int* __restrict__ odeg) {
  int pos = blockIdx.x * blockDim.x + threadIdx.x;
  if (pos < EE) atomicAdd(&odeg[csr_src[pos]], 1);
}

__global__ void out_fill(const int* __restrict__ csr_src, int* __restrict__ ocursor,
                         int* __restrict__ operm) {
  int pos = blockIdx.x * blockDim.x + threadIdx.x;
  if (pos < EE) {
    int slot = atomicAdd(&ocursor[csr_src[pos]], 1);
    operm[slot] = pos;
  }
}

__global__ void sgstart_build(const int* __restrict__ out_start, const int* __restrict__ gstart,
                              int* __restrict__ sg_start) {
  int t = blockIdx.x * blockDim.x + threadIdx.x;
  if (t <= GG) sg_start[t] = out_start[gstart[t]];
}

// edge encoder: elu(edge_attr[e] @ we0 + be0) placed at CSR position
__global__ __launch_bounds__(256) void ea_enc(const float* __restrict__ edge_attr,
                                              const float* __restrict__ we0,
                                              const float* __restrict__ be0,
                                              const int* __restrict__ src,
                                              const int* __restrict__ dst,
                                              int* __restrict__ cursor,
                                              int* __restrict__ csr_src,
                                              u16* __restrict__ ea) {
  int lane = threadIdx.x & 63;
  float wc[16];
#pragma unroll
  for (int j = 0; j < 16; ++j) wc[j] = we0[j * 64 + lane];
  float bl = be0[lane];
  int wg = (blockIdx.x * blockDim.x + threadIdx.x) >> 6;
  int nw = (gridDim.x * blockDim.x) >> 6;
  for (int e = wg; e < EE; e += nw) {
    float xr = edge_attr[(size_t)e * 16 + (lane & 15)];
    int pos = 0;
    if (lane == 0) pos = atomicAdd(&cursor[dst[e]], 1);
    pos = __shfl(pos, 0, 64);
    if (lane == 0) csr_src[pos] = src[e];
    float acc = bl;
#pragma unroll
    for (int j = 0; j < 16; ++j) acc = fmaf(__shfl(xr, j, 64), wc[j], acc);
    ea[(size_t)pos * 64 + lane] = f2b(elu_f(acc));
  }
}

// ---------------- graph LayerNorm ----------------
__global__ __launch_bounds__(256) void ln_stats_block(const float* __restrict__ h,
                                                      const int* __restrict__ gstart,
                                                      float* __restrict__ gmean,
                                                      float* __restrict__ grstd) {
  __shared__ float ls[4], lss[4];
  int g = blockIdx.x, t = threadIdx.x;
  int n0 = gstart[g], n1 = gstart[g + 1];
  int total4 = (n1 - n0) * 32;
  const float4* base = (const float4*)(h + (size_t)n0 * 128);
  float s = 0.f, ss = 0.f;
  for (int i = t; i < total4; i += 256) {
    float4 v = base[i];
    s += v.x + v.y + v.z + v.w;
    ss += v.x * v.x + v.y * v.y + v.z * v.z + v.w * v.w;
  }
  s = wred64(s);
  ss = wred64(ss);
  if ((t & 63) == 0) { ls[t >> 6] = s; lss[t >> 6] = ss; }
  __syncthreads();
  if (t == 0) {
    float S = ls[0] + ls[1] + ls[2] + ls[3];
    float SS = lss[0] + lss[1] + lss[2] + lss[3];
    float cnt = fmaxf((float)(n1 - n0) * 128.f, 1.0f);
    float mean = S / cnt;
    float var = fmaxf(SS / cnt - mean * mean, 0.f);
    gmean[g] = mean;
    grstd[g] = rsqrtf(var + 1e-5f);
  }
}

// LN apply -> split bf16 (hi + lo residual)
__global__ __launch_bounds__(256) void ln_apply(const float* __restrict__ in,
                                                u16* __restrict__ out_hi,
                                                u16* __restrict__ out_lo,
                                                const int* __restrict__ batch,
                                                const float* __restrict__ gmean,
                                                const float* __restrict__ grstd,
                                                const float* __restrict__ gamma,
                                                const float* __restrict__ beta) {
  int idx = blockIdx.x * blockDim.x + threadIdx.x;
  if (idx >= NN * 32) return;
  int n = idx >> 5, c4 = (idx & 31) * 4;
  int g = batch[n];
  float mean = gmean[g], rstd = grstd[g];
  float4 xv = *reinterpret_cast<const float4*>(in + (size_t)n * 128 + c4);
  float4 gv = *reinterpret_cast<const float4*>(gamma + c4);
  float4 bv = *reinterpret_cast<const float4*>(beta + c4);
  float v0 = elu_f((xv.x - mean) * rstd * gv.x + bv.x);
  float v1 = elu_f((xv.y - mean) * rstd * gv.y + bv.y);
  float v2 = elu_f((xv.z - mean) * rstd * gv.z + bv.z);
  float v3 = elu_f((xv.w - mean) * rstd * gv.w + bv.w);
  u16 h0 = f2b(v0), h1 = f2b(v1), h2 = f2b(v2), h3 = f2b(v3);
  uint2 hi = {(u32)h0 | ((u32)h1 << 16), (u32)h2 | ((u32)h3 << 16)};
  uint2 lo = {(u32)f2b(v0 - bf2f(h0)) | ((u32)f2b(v1 - bf2f(h1)) << 16),
              (u32)f2b(v2 - bf2f(h2)) | ((u32)f2b(v3 - bf2f(h3)) << 16)};
  *reinterpret_cast<uint2*>(out_hi + (size_t)n * 128 + c4) = hi;
  *reinterpret_cast<uint2*>(out_lo + (size_t)n * 128 + c4) = lo;
}

// ---------------- per-layer weight transforms ----------------
__global__ void build_wqe(const float* __restrict__ wq, const float* __restrict__ bq,
                          const float* __restrict__ we, float* __restrict__ WQE,
                          float* __restrict__ bqe) {
  int col = threadIdx.x;
  int row = blockIdx.x;
  int hh = col >> 6, j = col & 63;
  const float* wrow = (row < 128) ? (wq + (size_t)row * 128) : bq;
  float acc = 0.f;
  for (int c = 0; c < 64; ++c) acc += wrow[hh * 64 + c] * we[(size_t)j * 128 + hh * 64 + c];
  if (row < 128) WQE[(size_t)row * 128 + col] = acc;
  else bqe[col] = acc;
}

__global__ void build_wall(const float* __restrict__ wq, const float* __restrict__ wk,
                           const float* __restrict__ wv, const float* __restrict__ WQE,
                           const float* __restrict__ wsk,
                           const float* __restrict__ bq, const float* __restrict__ bk,
                           const float* __restrict__ bv, const float* __restrict__ bqe,
                           const float* __restrict__ bsk,
                           float* __restrict__ Wall, float* __restrict__ ball) {
  int idx = blockIdx.x * 256 + threadIdx.x;
  if (idx < 128 * 640) {
    int rr = idx / 640, cc = idx % 640;
    int sel = cc >> 7, c = cc & 127;
    const float* s = sel == 0 ? wq : sel == 1 ? wk : sel == 2 ? wv : sel == 3 ? WQE : wsk;
    Wall[idx] = s[rr * 128 + c];
  }
  if (idx < 640) {
    int sel = idx >> 7, c = idx & 127;
    const float* s = sel == 0 ? bq : sel == 1 ? bk : sel == 2 ? bv : sel == 3 ? bqe : bsk;
    ball[idx] = s[c];
  }
}

// Wall f32[128][640] -> split bf16 MFMA B-fragments (hi + lo)
__global__ void build_wfrag(const float* __restrict__ Wall, u16* __restrict__ Wfrag_hi,
                            u16* __restrict__ Wfrag_lo) {
  int idx = blockIdx.x * 256 + threadIdx.x;  // 81920 total
  if (idx >= 81920) return;
  int j = idx & 7, lane = (idx >> 3) & 63, rest = idx >> 9;
  int tg = rest % 40, s = rest / 40;
  int k = s * 32 + (lane >> 4) * 8 + j;
  int col = tg * 16 + (lane & 15);
  float w = Wall[(size_t)k * 640 + col];
  u16 hi = f2b(w);
  Wfrag_hi[idx] = hi;
  Wfrag_lo[idx] = f2b(w - bf2f(hi));
}

// we[64x128] -> split bf16 fragments for bd_gemm: [s][h][t][lane][j]
__global__ void build_wefrag(const float* __restrict__ we, u16* __restrict__ wef_hi,
                             u16* __restrict__ wef_lo) {
  int idx = blockIdx.x * 256 + threadIdx.x;  // 8192
  if (idx >= 8192) return;
  int j = idx & 7, lane = (idx >> 3) & 63, rest = idx >> 9;  // 0..15
  int t = rest & 3, hh = (rest >> 2) & 1, s = rest >> 3;
  int k = s * 32 + (lane >> 4) * 8 + j;               // 0..63
  int col = hh * 64 + t * 16 + (lane & 15);           // 0..127
  float w = we[(size_t)k * 128 + col];
  u16 hi = f2b(w);
  wef_hi[idx] = hi;
  wef_lo[idx] = f2b(w - bf2f(hi));
}

// up[64x64] f32 -> bf16 fragments
__global__ void build_upfrag(const float* __restrict__ up, u16* __restrict__ upfrag) {
  int idx = blockIdx.x * 256 + threadIdx.x;
  if (idx >= 4096) return;
  int j = idx & 7, lane = (idx >> 3) & 63, st = idx >> 9;
  int s = st >> 2, t = st & 3;
  int k = s * 32 + (lane >> 4) * 8 + j;
  int c = t * 16 + (lane & 15);
  upfrag[idx] = f2b(up[k * 64 + c]);
}

// W2 = up @ re_w [64x128]; bvec = ub @ re_w [128]
__global__ void build_w2(const float* __restrict__ up, const float* __restrict__ ub,
                         const float* __restrict__ re_w, float* __restrict__ W2,
                         float* __restrict__ bvec) {
  int idx = blockIdx.x * 256 + threadIdx.x;
  if (idx < 64 * 128) {
    int k_ = idx >> 7, c = idx & 127;
    float a = 0.f;
    for (int j = 0; j < 64; ++j) a = fmaf(up[k_ * 64 + j], re_w[j * 128 + c], a);
    W2[idx] = a;
  } else if (idx < 64 * 128 + 128) {
    int c = idx - 64 * 128;
    float a = 0.f;
    for (int j = 0; j < 64; ++j) a = fmaf(ub[j], re_w[j * 128 + c], a);
    bvec[c] = a;
  }
}

// ---------------- split-precision MFMA node GEMM ----------------
// nodebuf row layout (u16 idx): q[0..127] | qe[128..255] | kv interleaved [256..511]
__global__ __launch_bounds__(256) void node_gemm(const u16* __restrict__ h_hi,
                                                 const u16* __restrict__ h_lo,
                                                 const u16* __restrict__ Wfrag_hi,
                                                 const u16* __restrict__ Wfrag_lo,
                                                 const float* __restrict__ ball,
                                                 u16* __restrict__ nodebuf,
                                                 float* __restrict__ hn) {
  int tid = threadIdx.x;
  int lane = tid & 63;
  int wv = tid >> 6;
  int cb = blockIdx.x;
  int rbase = blockIdx.y * 64 + wv * 16;
  int rif = lane & 15, kg = lane >> 4;
  f32x4 acc[4] = {};
  int arow = rbase + rif;
  bool rowok = arow < NN;
  const u16* aph = h_hi + (size_t)arow * 128 + kg * 8;
  const u16* apl = h_lo + (size_t)arow * 128 + kg * 8;
#pragma unroll
  for (int s = 0; s < 4; ++s) {
    bf16x8 ah = {}, al = {};
    if (rowok) {
      ah = *reinterpret_cast<const bf16x8*>(aph + s * 32);
      al = *reinterpret_cast<const bf16x8*>(apl + s * 32);
    }
#pragma unroll
    for (int t = 0; t < 4; ++t) {
      size_t fo = ((size_t)((s * 40 + cb * 4 + t) * 64 + lane)) * 8;
      bf16x8 bh = *reinterpret_cast<const bf16x8*>(Wfrag_hi + fo);
      bf16x8 bl = *reinterpret_cast<const bf16x8*>(Wfrag_lo + fo);
      acc[t] = __builtin_amdgcn_mfma_f32_16x16x32_bf16(ah, bh, acc[t], 0, 0, 0);
      acc[t] = __builtin_amdgcn_mfma_f32_16x16x32_bf16(ah, bl, acc[t], 0, 0, 0);
      acc[t] = __builtin_amdgcn_mfma_f32_16x16x32_bf16(al, bh, acc[t], 0, 0, 0);
    }
  }
#pragma unroll
  for (int t = 0; t < 4; ++t) {
    int col = (cb * 4 + t) * 16 + rif;
    float bia = ball[col];
#pragma unroll
    for (int rg = 0; rg < 4; ++rg) {
      int row = rbase + kg * 4 + rg;
      if (row < NN) {
        float val = acc[t][rg] + bia;
        if (col < 512) {
          int idx;
          if (col < 128) idx = col;                                        // q
          else if (col < 256) { int c1 = col - 128; idx = 256 + ((c1 >> 1) << 2) + (c1 & 1); }  // k
          else if (col < 384) { int c2 = col - 256; idx = 256 + ((c2 >> 1) << 2) + 2 + (c2 & 1); }  // v
          else idx = 128 + (col - 384);                                    // qe
          nodebuf[(size_t)row * 512 + idx] = f2b(val);
        } else {
          hn[(size_t)row * 128 + col - 512] = val;
        }
      }
    }
  }
}

// ---------------- MFMA edge GEMM: ea = elu(ea @ up + ub), in place ----------------
__global__ __launch_bounds__(256) void edge_gemm(u16* __restrict__ ea,
                                                 const u16* __restrict__ upfrag,
                                                 const float* __restrict__ ub) {
  int lane = threadIdx.x & 63;
  int gwave = (blockIdx.x * 256 + threadIdx.x) >> 6;
  int nwaves = (gridDim.x * 256) >> 6;
  bf16x8 bfrag[2][4];
#pragma unroll
  for (int s = 0; s < 2; ++s)
#pragma unroll
    for (int t = 0; t < 4; ++t)
      bfrag[s][t] = *reinterpret_cast<const bf16x8*>(upfrag + ((size_t)((s * 4 + t) * 64 + lane)) * 8);
  float bias_c[4];
#pragma unroll
  for (int t = 0; t < 4; ++t) bias_c[t] = ub[t * 16 + (lane & 15)];
  const int rif = lane & 15;
  const int kg = lane >> 4;
  for (int mt = gwave; mt < EE / 16; mt += nwaves) {
    size_t rowbase = (size_t)mt * 16;
    const u16* arow = ea + (rowbase + rif) * 64;
    bf16x8 a0 = *reinterpret_cast<const bf16x8*>(arow + kg * 8);
    bf16x8 a1 = *reinterpret_cast<const bf16x8*>(arow + 32 + kg * 8);
    f32x4 acc[4] = {};
#pragma unroll
    for (int t = 0; t < 4; ++t) {
      acc[t] = __builtin_amdgcn_mfma_f32_16x16x32_bf16(a0, bfrag[0][t], acc[t], 0, 0, 0);
      acc[t] = __builtin_amdgcn_mfma_f32_16x16x32_bf16(a1, bfrag[1][t], acc[t], 0, 0, 0);
    }
#pragma unroll
    for (int t = 0; t < 4; ++t)
#pragma unroll
      for (int rg = 0; rg < 4; ++rg) {
        float val = acc[t][rg] + bias_c[t];
        ea[(rowbase + kg * 4 + rg) * 64 + t * 16 + rif] = f2b(elu_f(val));
      }
  }
}

// ---------------- split-precision MFMA BD GEMM: hn += r @ BD (per-head we) ----------------
__global__ __launch_bounds__(256) void bd_gemm(const u16* __restrict__ r_hi,
                                               const u16* __restrict__ r_lo,
                                               const u16* __restrict__ wef_hi,
                                               const u16* __restrict__ wef_lo,
                                               float* __restrict__ hn) {
  int tid = threadIdx.x;
  int lane = tid & 63;
  int w = blockIdx.x * 4 + (tid >> 6);
  if (w >= NN / 16) return;
  int rif = lane & 15, kg = lane >> 4;
  size_t rowbase = (size_t)w * 16;
  const u16* ahb = r_hi + (rowbase + rif) * 128;
  const u16* alb = r_lo + (rowbase + rif) * 128;
  f32x4 acc[2][4] = {};
#pragma unroll
  for (int hh = 0; hh < 2; ++hh)
#pragma unroll
    for (int s = 0; s < 2; ++s) {
      int ko = hh * 64 + s * 32 + kg * 8;
      bf16x8 ah = *reinterpret_cast<const bf16x8*>(ahb + ko);
      bf16x8 al = *reinterpret_cast<const bf16x8*>(alb + ko);
#pragma unroll
      for (int t = 0; t < 4; ++t) {
        size_t fo = ((size_t)((((s * 2 + hh) * 4 + t)) * 64 + lane)) * 8;
        bf16x8 bh = *reinterpret_cast<const bf16x8*>(wef_hi + fo);
        bf16x8 bl = *reinterpret_cast<const bf16x8*>(wef_lo + fo);
        acc[hh][t] = __builtin_amdgcn_mfma_f32_16x16x32_bf16(ah, bh, acc[hh][t], 0, 0, 0);
        acc[hh][t] = __builtin_amdgcn_mfma_f32_16x16x32_bf16(ah, bl, acc[hh][t], 0, 0, 0);
        acc[hh][t] = __builtin_amdgcn_mfma_f32_16x16x32_bf16(al, bh, acc[hh][t], 0, 0, 0);
      }
    }
#pragma unroll
  for (int hh = 0; hh < 2; ++hh)
#pragma unroll
    for (int t = 0; t < 4; ++t)
#pragma unroll
      for (int rg = 0; rg < 4; ++rg) {
        size_t row = rowbase + kg * 4 + rg;
        int col = hh * 64 + t * 16 + rif;
        hn[row * 128 + col] += acc[hh][t][rg];
      }
}

// per-src-graph sum of current ea rows, 16 chunks per graph + atomic merge
__global__ __launch_bounds__(256) void gsum_pre(const u16* __restrict__ ea,
                                                const int* __restrict__ sg_start,
                                                const int* __restrict__ sg_perm,
                                                float* __restrict__ gsum_in) {
  __shared__ float red[8][64];
  int g = blockIdx.x, t = threadIdx.x;
  int c2 = t & 31;
  int rgrp = t >> 5;
  int gr = blockIdx.y * 8 + rgrp;  // 0..127
  int p0 = sg_start[g], p1 = sg_start[g + 1];
  float slo = 0.f, shi = 0.f;
  for (int i = p0 + gr; i < p1; i += 128) {
    int pos = sg_perm[i];
    u32 w = ((const u32*)ea)[(size_t)pos * 32 + c2];
    slo += lo2f(w);
    shi += hi2f(w);
  }
  red[rgrp][c2 * 2] = slo;
  red[rgrp][c2 * 2 + 1] = shi;
  __syncthreads();
  if (t < 64) {
    float a = 0.f;
#pragma unroll
    for (int rr = 0; rr < 8; ++rr) a += red[rr][t];
    atomicAdd(&gsum_in[(size_t)g * 64 + t], a);
  }
}

// embE = elu(gsum_in @ W2 + cnt*bvec + re_b)
__global__ void emb_e_kernel(const float* __restrict__ gsum_in, const int* __restrict__ sg_start,
                             const float* __restrict__ W2, const float* __restrict__ bvec,
                             const float* __restrict__ re_b, float* __restrict__ embE) {
  int g = blockIdx.x, c = threadIdx.x;
  float cnt = (float)(sg_start[g + 1] - sg_start[g]);
  float a = re_b[c] + cnt * bvec[c];
  for (int k_ = 0; k_ < 64; ++k_) a = fmaf(gsum_in[(size_t)g * 64 + k_], W2[k_ * 128 + c], a);
  embE[(size_t)g * 128 + c] = elu_f(a);
}

// ---------------- fused flash-style attention, one wave per dst node ----------------
__global__ __launch_bounds__(256) void attn_node(const u32* __restrict__ nodebuf,
                                                 const u16* __restrict__ ea,
                                                 const int* __restrict__ row_start,
                                                 const int* __restrict__ csr_src,
                                                 float* __restrict__ hn,
                                                 u32* __restrict__ r_hi,
                                                 u32* __restrict__ r_lo) {
  int d = (blockIdx.x * blockDim.x + threadIdx.x) >> 6;
  if (d >= NN) return;
  int lane = threadIdx.x & 63;
  int p0 = row_start[d], p1 = row_start[d + 1];
  if (p0 == p1) {
    r_hi[(size_t)d * 64 + lane] = 0u;
    r_lo[(size_t)d * 64 + lane] = 0u;
    return;
  }
  size_t dbase = (size_t)d * 256;
  u32 qv = nodebuf[dbase + lane];
  u32 qev = nodebuf[dbase + 64 + lane];
  float m = -3.4e38f, ssum = 0.f, a0 = 0.f, a1 = 0.f, r0 = 0.f, r1 = 0.f;
  // 1-deep prefetch
  int sN = csr_src[p0];
  uint2 kvN = *((const uint2*)(nodebuf + (size_t)sN * 256 + 128) + lane);
  u32 eaN = ((const u32*)ea)[(size_t)p0 * 32 + (lane & 31)];
  for (int pos = p0; pos < p1; ++pos) {
    uint2 kv = kvN;
    u32 eav = eaN;
    int nxt = (pos + 1 < p1) ? pos + 1 : pos;
    sN = csr_src[nxt];
    kvN = *((const uint2*)(nodebuf + (size_t)sN * 256 + 128) + lane);
    eaN = ((const u32*)ea)[(size_t)nxt * 32 + (lane & 31)];
    float p = lo2f(qv) * lo2f(kv.x) + hi2f(qv) * hi2f(kv.x) +
              lo2f(qev) * lo2f(eav) + hi2f(qev) * hi2f(eav);
#pragma unroll
    for (int mm = 16; mm; mm >>= 1) p += __shfl_xor(p, mm, 64);
    float l = p * 0.125f;
    float mn = fmaxf(m, l);
    float f = __expf(m - mn);
    float w = __expf(l - mn);
    ssum = ssum * f + w;
    a0 = a0 * f + w * lo2f(kv.y);
    a1 = a1 * f + w * hi2f(kv.y);
    r0 = r0 * f + w * lo2f(eav);
    r1 = r1 * f + w * hi2f(eav);
    m = mn;
  }
  float inv = 1.f / ssum;
  size_t ob = (size_t)d * 128 + lane * 2;
  hn[ob] += a0 * inv;
  hn[ob + 1] += a1 * inv;
  float rv0 = r0 * inv, rv1 = r1 * inv;
  u16 h0 = f2b(rv0), h1 = f2b(rv1);
  r_hi[(size_t)d * 64 + lane] = (u32)h0 | ((u32)h1 << 16);
  r_lo[(size_t)d * 64 + lane] = (u32)f2b(rv0 - bf2f(h0)) | ((u32)f2b(rv1 - bf2f(h1)) << 16);
}

// ---------------- SAG pooling ----------------
__global__ __launch_bounds__(256) void node_dots(const float* __restrict__ hn,
                                                 const float* __restrict__ wrel,
                                                 const float* __restrict__ wroot,
                                                 float* __restrict__ hrel,
                                                 float* __restrict__ troot) {
  int n = (blockIdx.x * blockDim.x + threadIdx.x) >> 6;
  if (n >= NN) return;
  int lane = threadIdx.x & 63;
  float x0 = hn[(size_t)n * 128 + lane], x1 = hn[(size_t)n * 128 + 64 + lane];
  float tr = wred64(x0 * wrel[lane] + x1 * wrel[64 + lane]);
  float tt = wred64(x0 * wroot[lane] + x1 * wroot[64 + lane]);
  if (lane == 0) { hrel[n] = tr; troot[n] = tt; }
}

__global__ __launch_bounds__(256) void sag_gather(const float* __restrict__ hrel,
                                                  const float* __restrict__ troot,
                                                  const float* __restrict__ brel,
                                                  const int* __restrict__ row_start,
                                                  const int* __restrict__ csr_src,
                                                  const int* __restrict__ batch,
                                                  float* __restrict__ sc, unsigned* __restrict__ gm) {
  int n = blockIdx.x * blockDim.x + threadIdx.x;
  if (n >= NN) return;
  float s = 0.f;
  int p1 = row_start[n + 1];
  for (int pos = row_start[n]; pos < p1; ++pos) s += hrel[csr_src[pos]];
  float v = s + troot[n] + brel[0];
  sc[n] = v;
  atomicMax(&gm[batch[n]], fenc(v));
}

__global__ __launch_bounds__(256) void sag_exp(const float* __restrict__ sc,
                                               const int* __restrict__ batch,
                                               const unsigned* __restrict__ gm,
                                               float* __restrict__ gs, float* __restrict__ scp) {
  int n = blockIdx.x * blockDim.x + threadIdx.x;
  if (n >= NN) return;
  int g = batch[n];
  float p = __expf(sc[n] - fdec(gm[g]));
  scp[n] = p;
  atomicAdd(&gs[g], p);
}

__global__ void emb_block(const float* __restrict__ hn, const float* __restrict__ scp,
                          const float* __restrict__ gs, const int* __restrict__ gstart,
                          const float* __restrict__ embE, float* __restrict__ dstv) {
  __shared__ float part[2];
  int g = blockIdx.x, c = threadIdx.x;
  int n0 = gstart[g], n1 = gstart[g + 1];
  float invg = 1.f / gs[g];
  float acc = 0.f;
  for (int n = n0; n < n1; ++n) acc = fmaf(hn[(size_t)n * 128 + c], scp[n] * invg, acc);
  float val = acc * embE[(size_t)g * 128 + c];
  float sq = val * val;
#pragma unroll
  for (int mm = 32; mm; mm >>= 1) sq += __shfl_xor(sq, mm, 64);
  if ((c & 63) == 0) part[c >> 6] = sq;
  __syncthreads();
  float nrm = sqrtf(part[0] + part[1]);
  dstv[(size_t)g * 128 + c] = elu_f(val / fmaxf(nrm, 1e-12f));
}

__global__ void final_combine(const float* __restrict__ e0, const float* __restrict__ e1,
                              float* __restrict__ out) {
  int idx = blockIdx.x * blockDim.x + threadIdx.x;
  if (idx >= GG * 128) return;
  out[idx] = 0.6f * e0[idx] + 0.4f * e1[idx];
}

// =====================================================================
extern "C" void kernel_launch(void* const* d_in, const int* in_sizes, int n_in,
                              void* d_out, int out_size, void* d_ws, size_t ws_size,
                              hipStream_t stream) {
  const float* x = (const float*)d_in[0];
  const float* edge_attr = (const float*)d_in[1];
  const int* edge_index = (const int*)d_in[2];
  const int* batch = (const int*)d_in[3];
  const float* w0 = (const float*)d_in[4];
  const float* b0 = (const float*)d_in[5];
  const float* we0 = (const float*)d_in[6];
  const float* be0 = (const float*)d_in[7];
  const float* ln0_g = (const float*)d_in[8];
  const float* ln0_b = (const float*)d_in[9];
  const float* qkv_w = (const float*)d_in[10];
  const float* qkv_b = (const float*)d_in[11];
  const float* edge_w = (const float*)d_in[12];
  const float* skip_w = (const float*)d_in[13];
  const float* skip_b = (const float*)d_in[14];
  const float* up_w = (const float*)d_in[15];
  const float* up_b = (const float*)d_in[16];
  const float* ng = (const float*)d_in[17];
  const float* nbeta = (const float*)d_in[18];
  const float* sag_wrel = (const float*)d_in[19];
  const float* sag_brel = (const float*)d_in[20];
  const float* sag_wroot = (const float*)d_in[21];
  const float* re_w = (const float*)d_in[22];
  const float* re_b = (const float*)d_in[23];
  const int* srcp = edge_index;
  const int* dstp = edge_index + EE;
  float* out = (float*)d_out;
  (void)in_sizes; (void)n_in;

  float* ws = (float*)d_ws;
  size_t o = 0;
  auto alloc = [&](size_t n) { n = (n + 3) & ~(size_t)3; float* p = ws + o; o += n; return p; };
  u16* h_hi = (u16*)alloc((size_t)NN * 64);
  u16* h_lo = (u16*)alloc((size_t)NN * 64);
  float* hn = alloc((size_t)NN * 128);
  u32* r_hi = (u32*)alloc((size_t)NN * 64);
  u32* r_lo = (u32*)alloc((size_t)NN * 64);
  u16* nodebuf = (u16*)alloc((size_t)NN * 256);   // NN x 512 bf16 (q|qe|kv)
  u16* ea = (u16*)alloc((size_t)EE * 32);         // EE x 64 bf16, dst-CSR order
  int* csr_src = (int*)alloc(EE);
  int* deg = (int*)alloc(NN);
  int* row_start = (int*)alloc(NN + 1);
  int* cursor = (int*)alloc(NN);
  int* out_start = (int*)alloc(NN + 1);
  int* gstart = (int*)alloc(GG + 1);
  int* sg_perm = (int*)alloc(EE);
  int* sg_start = (int*)alloc(GG + 1);
  float* gsum_in = alloc(GG * 64);
  float* W2 = alloc(64 * 128);
  float* bvec = alloc(128);
  u16* upfrag = (u16*)alloc(2048);
  u16* Wfrag_hi = (u16*)alloc(40960);
  u16* Wfrag_lo = (u16*)alloc(40960);
  u16* wef_hi = (u16*)alloc(4096);                // 8192 u16
  u16* wef_lo = (u16*)alloc(4096);
  unsigned* gm = (unsigned*)alloc(GG);            // zero-block (gm, gs)
  float* gs = alloc(GG);
  float* gmean = alloc(GG);
  float* grstd = alloc(GG);
  float* WQE = alloc(128 * 128);
  float* bqe = alloc(128);
  float* Wall = alloc(128 * 640);
  float* ball = alloc(640);
  float* hrel = alloc(NN);
  float* troot = alloc(NN);
  float* sc = alloc(NN);
  float* scp = alloc(NN);
  float* embE = alloc(GG * 128);
  float* embs0 = alloc(GG * 128);
  float* embs1 = alloc(GG * 128);

  const size_t need = o * sizeof(float);
  if (ws_size < need) {
    hipMemsetAsync(d_out, 0, (size_t)out_size * sizeof(float), stream);
    return;
  }

  auto gemm = [&](const float* A, const float* B, const float* bias, float* C,
                  int M, int Nn, int K, int act, int accum) {
    dim3 g((Nn + 63) / 64, (M + 63) / 64);
    gemm_kernel<<<g, 256, 0, stream>>>(A, B, bias, C, M, Nn, K, act, accum);
  };
  auto graph_ln = [&](const float* in, const float* gamma, const float* beta) {
    ln_stats_block<<<GG, 256, 0, stream>>>(in, gstart, gmean, grstd);
    ln_apply<<<NN * 32 / 256, 256, 0, stream>>>(in, h_hi, h_lo, batch, gmean, grstd, gamma, beta);
  };
  auto tconv = [&](int il) {
    const float* wq = qkv_w + (size_t)(il * 3 + 0) * 128 * 128;
    const float* wk = qkv_w + (size_t)(il * 3 + 1) * 128 * 128;
    const float* wv = qkv_w + (size_t)(il * 3 + 2) * 128 * 128;
    const float* bq = qkv_b + (il * 3 + 0) * 128;
    const float* bk = qkv_b + (il * 3 + 1) * 128;
    const float* bv = qkv_b + (il * 3 + 2) * 128;
    const float* we = edge_w + (size_t)il * 64 * 128;
    const float* wsk = skip_w + (size_t)il * 128 * 128;
    const float* bsk = skip_b + il * 128;
    build_wqe<<<129, 128, 0, stream>>>(wq, bq, we, WQE, bqe);
    build_wall<<<320, 256, 0, stream>>>(wq, wk, wv, WQE, wsk, bq, bk, bv, bqe, bsk, Wall, ball);
    build_wfrag<<<320, 256, 0, stream>>>(Wall, Wfrag_hi, Wfrag_lo);
    build_wefrag<<<32, 256, 0, stream>>>(we, wef_hi, wef_lo);
    dim3 ng2(10, (NN + 63) / 64);
    node_gemm<<<ng2, 256, 0, stream>>>(h_hi, h_lo, Wfrag_hi, Wfrag_lo, ball, nodebuf, hn);
    attn_node<<<NN / 4, 256, 0, stream>>>((const u32*)nodebuf, ea, row_start, csr_src, hn,
                                          r_hi, r_lo);
    bd_gemm<<<(NN / 16 + 3) / 4, 256, 0, stream>>>((const u16*)r_hi, (const u16*)r_lo,
                                                   wef_hi, wef_lo, hn);
  };
  auto ea_mlp = [&](int il) {
    build_upfrag<<<16, 256, 0, stream>>>(up_w + (size_t)il * 4096, upfrag);
    edge_gemm<<<2048, 256, 0, stream>>>(ea, upfrag, up_b + il * 64);
  };

  // one-time topology structures
  hipMemsetAsync(deg, 0, NN * sizeof(int), stream);
  csr_hist<<<(EE + 255) / 256, 256, 0, stream>>>(dstp, deg);
  csr_scan<<<1, 256, 0, stream>>>(deg, row_start, cursor);
  gstart_build<<<(NN + 256) / 256, 256, 0, stream>>>(batch, gstart);
  ea_enc<<<2048, 256, 0, stream>>>(edge_attr, we0, be0, srcp, dstp, cursor, csr_src, ea);
  hipMemsetAsync(deg, 0, NN * sizeof(int), stream);
  out_hist<<<(EE + 255) / 256, 256, 0, stream>>>(csr_src, deg);
  csr_scan<<<1, 256, 0, stream>>>(deg, out_start, cursor);
  out_fill<<<(EE + 255) / 256, 256, 0, stream>>>(csr_src, cursor, sg_perm);
  sgstart_build<<<2, 256, 0, stream>>>(out_start, gstart, sg_start);
  // node encoder + first LN
  gemm(x, w0, b0, hn, NN, 128, 64, 0, 0);
  graph_ln(hn, ln0_g, ln0_b);

  for (int i = 0; i < 2; ++i) {
    tconv(i * 2 + 0);
    graph_ln(hn, ng + (i * 2) * 128, nbeta + (i * 2) * 128);
    ea_mlp(i * 2);
    tconv(i * 2 + 1);
    // SAG pooling on pre-LN conv2 output hn; edge emb via linearity:
    hipMemsetAsync(gm, 0, 2 * GG * sizeof(float), stream);       // gm, gs
    hipMemsetAsync(gsum_in, 0, GG * 64 * sizeof(float), stream);
    dim3 gsg(GG, 16);
    gsum_pre<<<gsg, 256, 0, stream>>>(ea, sg_start, sg_perm, gsum_in);
    build_w2<<<33, 256, 0, stream>>>(up_w + (size_t)(i * 2 + 1) * 4096,
                                     up_b + (i * 2 + 1) * 64,
                                     re_w + (size_t)i * 64 * 128, W2, bvec);
    ea_mlp(i * 2 + 1);
    node_dots<<<NN / 4, 256, 0, stream>>>(hn, sag_wrel + i * 128, sag_wroot + i * 128, hrel, troot);
    sag_gather<<<(NN + 255) / 256, 256, 0, stream>>>(hrel, troot, sag_brel + i, row_start,
                                                     csr_src, batch, sc, gm);
    sag_exp<<<(NN + 255) / 256, 256, 0, stream>>>(sc, batch, gm, gs, scp);
    emb_e_kernel<<<GG, 128, 0, stream>>>(gsum_in, sg_start, W2, bvec, re_b + i * 128, embE);
    emb_block<<<GG, 128, 0, stream>>>(hn, scp, gs, gstart, embE, i == 0 ? embs0 : embs1);
    graph_ln(hn, ng + (i * 2 + 1) * 128, nbeta + (i * 2 + 1) * 128);
  }
  final_combine<<<GG * 128 / 256, 256, 0, stream>>>(embs0, embs1, out);
}

// Round 8
// 2087.462 us; speedup vs baseline: 5.6903x; 1.1140x over previous
//
#include <hip/hip_runtime.h>
#include <math.h>

#define NN 50000
#define EE 800000
#define GG 256

typedef unsigned short u16;
typedef unsigned int u32;
typedef __attribute__((ext_vector_type(4))) float f32x4;
typedef __attribute__((ext_vector_type(8))) short bf16x8;

__device__ __forceinline__ float elu_f(float x) { return x > 0.f ? x : expm1f(x); }

__device__ __forceinline__ unsigned fenc(float f) {
  unsigned b = __float_as_uint(f);
  return (b & 0x80000000u) ? ~b : (b | 0x80000000u);
}
__device__ __forceinline__ float fdec(unsigned u) {
  return __uint_as_float((u & 0x80000000u) ? (u ^ 0x80000000u) : ~u);
}
__device__ __forceinline__ u16 f2b(float f) {
  u32 u = __float_as_uint(f);
  u32 r = (u + 0x7fffu + ((u >> 16) & 1u)) >> 16;
  return (u16)r;
}
__device__ __forceinline__ float bf2f(u16 u) { return __uint_as_float(((u32)u) << 16); }
__device__ __forceinline__ float lo2f(u32 p) { return __uint_as_float(p << 16); }
__device__ __forceinline__ float hi2f(u32 p) { return __uint_as_float(p & 0xffff0000u); }

__device__ __forceinline__ float wred64(float v) {
#pragma unroll
  for (int m = 32; m; m >>= 1) v += __shfl_xor(v, m, 64);
  return v;
}

// ---------------- generic tiled f32 GEMM: C = act(A@B + bias (+C)) ----------------
__global__ __launch_bounds__(256) void gemm_kernel(
    const float* __restrict__ A, const float* __restrict__ B,
    const float* __restrict__ bias, float* __restrict__ C,
    int M, int Nn, int K, int act, int accum) {
  __shared__ float As[16][68];
  __shared__ float Bs[16][68];
  const int bm = blockIdx.y * 64;
  const int bn = blockIdx.x * 64;
  const int tid = threadIdx.x;
  const int tx = tid & 15, ty = tid >> 4;
  const int lr = tid >> 2;
  const int lk = (tid & 3) << 2;
  float acc[4][4] = {};
  for (int k0 = 0; k0 < K; k0 += 16) {
    int arow = bm + lr;
    float4 a4 = {0.f, 0.f, 0.f, 0.f};
    if (arow < M) a4 = *reinterpret_cast<const float4*>(A + (size_t)arow * K + k0 + lk);
    As[lk + 0][lr] = a4.x; As[lk + 1][lr] = a4.y;
    As[lk + 2][lr] = a4.z; As[lk + 3][lr] = a4.w;
    float4 b4 = *reinterpret_cast<const float4*>(B + (size_t)(k0 + ty) * Nn + bn + tx * 4);
    *reinterpret_cast<float4*>(&Bs[ty][tx * 4]) = b4;
    __syncthreads();
#pragma unroll
    for (int kk = 0; kk < 16; ++kk) {
      float4 av = *reinterpret_cast<const float4*>(&As[kk][ty * 4]);
      float4 bv = *reinterpret_cast<const float4*>(&Bs[kk][tx * 4]);
      float a_[4] = {av.x, av.y, av.z, av.w};
      float b_[4] = {bv.x, bv.y, bv.z, bv.w};
#pragma unroll
      for (int ii = 0; ii < 4; ++ii)
#pragma unroll
        for (int jj = 0; jj < 4; ++jj)
          acc[ii][jj] = fmaf(a_[ii], b_[jj], acc[ii][jj]);
    }
    __syncthreads();
  }
#pragma unroll
  for (int ii = 0; ii < 4; ++ii) {
    int row = bm + ty * 4 + ii;
    if (row >= M) continue;
#pragma unroll
    for (int jj = 0; jj < 4; ++jj) {
      int col = bn + tx * 4 + jj;
      float val = acc[ii][jj];
      if (bias) val += bias[col];
      if (accum) val += C[(size_t)row * Nn + col];
      if (act) val = elu_f(val);
      C[(size_t)row * Nn + col] = val;
    }
  }
}

// ---------------- CSR build ----------------
__global__ void csr_hist(const int* __restrict__ dst, int* __restrict__ deg) {
  int e = blockIdx.x * blockDim.x + threadIdx.x;
  if (e < EE) atomicAdd(&deg[dst[e]], 1);
}

__global__ void csr_scan(const int* __restrict__ deg, int* __restrict__ row_start,
                         int* __restrict__ cursor) {
  __shared__ int sums[256];
  int t = threadIdx.x;
  const int CH = (NN + 255) / 256;
  int base = t * CH;
  int local = 0;
  for (int i = 0; i < CH; ++i) {
    int idx = base + i;
    if (idx < NN) local += deg[idx];
  }
  sums[t] = local;
  __syncthreads();
  for (int off = 1; off < 256; off <<= 1) {
    int tmp = (t >= off) ? sums[t - off] : 0;
    __syncthreads();
    sums[t] += tmp;
    __syncthreads();
  }
  int run = sums[t] - local;
  for (int i = 0; i < CH; ++i) {
    int idx = base + i;
    if (idx < NN) {
      row_start[idx] = run;
      cursor[idx] = run;
      run += deg[idx];
    }
  }
  if (t == 255) row_start[NN] = run;
}

__global__ void gstart_build(const int* __restrict__ batch, int* __restrict__ gstart) {
  int n = blockIdx.x * blockDim.x + threadIdx.x;
  if (n > NN) return;
  int b = (n < NN) ? batch[n] : GG;
  int pb = (n == 0) ? -1 : batch[n - 1];
  for (int g = pb + 1; g <= b; ++g) gstart[g] = n;
}

// per-edge CSR position + record
__global__ void csr_pos(const int* __restrict__ src, const int* __restrict__ dst,
                        int* __restrict__ cursor, int* __restrict__ csr_src,
                        int* __restrict__ epos) {
  int e = blockIdx.x * blockDim.x + threadIdx.x;
  if (e >= EE) return;
  int pos = atomicAdd(&cursor[dst[e]], 1);
  csr_src[pos] = src[e];
  epos[e] = pos;
}

__global__ void out_hist(const int* __restrict__ csr_src, int* __restrict__ odeg) {
  int pos = blockIdx.x * blockDim.x + threadIdx.x;
  if (pos < EE) atomicAdd(&odeg[csr_src[pos]], 1);
}

__global__ void out_fill(const int* __restrict__ csr_src, int* __restrict__ ocursor,
                         int* __restrict__ operm) {
  int pos = blockIdx.x * blockDim.x + threadIdx.x;
  if (pos < EE) {
    int slot = atomicAdd(&ocursor[csr_src[pos]], 1);
    operm[slot] = pos;
  }
}

__global__ void sgstart_build(const int* __restrict__ out_start, const int* __restrict__ gstart,
                              int* __restrict__ sg_start) {
  int t = blockIdx.x * blockDim.x + threadIdx.x;
  if (t <= GG) sg_start[t] = out_start[gstart[t]];
}

// we0[16x64] -> split bf16 fragments, K padded to 32 (k>=16 -> 0)
__global__ void build_we0frag(const float* __restrict__ we0, u16* __restrict__ wf_hi,
                              u16* __restrict__ wf_lo) {
  int idx = blockIdx.x * 256 + threadIdx.x;  // 2048
  if (idx >= 2048) return;
  int j = idx & 7, lane = (idx >> 3) & 63, t = idx >> 9;
  int k = (lane >> 4) * 8 + j;
  int c = t * 16 + (lane & 15);
  float w = (k < 16) ? we0[(size_t)k * 64 + c] : 0.f;
  u16 hi = f2b(w);
  wf_hi[idx] = hi;
  wf_lo[idx] = f2b(w - bf2f(hi));
}

// MFMA edge encoder: ea[epos[e]] = elu(edge_attr[e] @ we0 + be0), 16 edges/wave
__global__ __launch_bounds__(256) void ea_enc_mfma(const float* __restrict__ edge_attr,
                                                   const u16* __restrict__ wf_hi,
                                                   const u16* __restrict__ wf_lo,
                                                   const float* __restrict__ be0,
                                                   const int* __restrict__ epos,
                                                   u16* __restrict__ ea) {
  int lane = threadIdx.x & 63;
  int gwave = (blockIdx.x * 256 + threadIdx.x) >> 6;
  int nwaves = (gridDim.x * 256) >> 6;
  bf16x8 bh[4], bl[4];
#pragma unroll
  for (int t = 0; t < 4; ++t) {
    bh[t] = *reinterpret_cast<const bf16x8*>(wf_hi + ((size_t)(t * 64 + lane)) * 8);
    bl[t] = *reinterpret_cast<const bf16x8*>(wf_lo + ((size_t)(t * 64 + lane)) * 8);
  }
  float bias_c[4];
#pragma unroll
  for (int t = 0; t < 4; ++t) bias_c[t] = be0[t * 16 + (lane & 15)];
  const int rif = lane & 15;
  const int kg = lane >> 4;
  for (int mt = gwave; mt < EE / 16; mt += nwaves) {
    int base = mt * 16;
    bf16x8 ah = {}, al = {};
    if (kg < 2) {
      const float* ap = edge_attr + (size_t)(base + rif) * 16 + kg * 8;
      float4 f0 = *reinterpret_cast<const float4*>(ap);
      float4 f1 = *reinterpret_cast<const float4*>(ap + 4);
      float fv[8] = {f0.x, f0.y, f0.z, f0.w, f1.x, f1.y, f1.z, f1.w};
#pragma unroll
      for (int jj = 0; jj < 8; ++jj) {
        u16 hi = f2b(fv[jj]);
        ah[jj] = (short)hi;
        al[jj] = (short)f2b(fv[jj] - bf2f(hi));
      }
    }
    f32x4 acc[4] = {};
#pragma unroll
    for (int t = 0; t < 4; ++t) {
      acc[t] = __builtin_amdgcn_mfma_f32_16x16x32_bf16(ah, bh[t], acc[t], 0, 0, 0);
      acc[t] = __builtin_amdgcn_mfma_f32_16x16x32_bf16(ah, bl[t], acc[t], 0, 0, 0);
      acc[t] = __builtin_amdgcn_mfma_f32_16x16x32_bf16(al, bh[t], acc[t], 0, 0, 0);
    }
#pragma unroll
    for (int rg = 0; rg < 4; ++rg) {
      int pr = epos[base + kg * 4 + rg];
#pragma unroll
      for (int t = 0; t < 4; ++t)
        ea[(size_t)pr * 64 + t * 16 + rif] = f2b(elu_f(acc[t][rg] + bias_c[t]));
    }
  }
}

// ---------------- graph LayerNorm ----------------
__global__ __launch_bounds__(256) void ln_stats_block(const float* __restrict__ h,
                                                      const int* __restrict__ gstart,
                                                      float* __restrict__ gmean,
                                                      float* __restrict__ grstd) {
  __shared__ float ls[4], lss[4];
  int g = blockIdx.x, t = threadIdx.x;
  int n0 = gstart[g], n1 = gstart[g + 1];
  int total4 = (n1 - n0) * 32;
  const float4* base = (const float4*)(h + (size_t)n0 * 128);
  float s = 0.f, ss = 0.f;
  for (int i = t; i < total4; i += 256) {
    float4 v = base[i];
    s += v.x + v.y + v.z + v.w;
    ss += v.x * v.x + v.y * v.y + v.z * v.z + v.w * v.w;
  }
  s = wred64(s);
  ss = wred64(ss);
  if ((t & 63) == 0) { ls[t >> 6] = s; lss[t >> 6] = ss; }
  __syncthreads();
  if (t == 0) {
    float S = ls[0] + ls[1] + ls[2] + ls[3];
    float SS = lss[0] + lss[1] + lss[2] + lss[3];
    float cnt = fmaxf((float)(n1 - n0) * 128.f, 1.0f);
    float mean = S / cnt;
    float var = fmaxf(SS / cnt - mean * mean, 0.f);
    gmean[g] = mean;
    grstd[g] = rsqrtf(var + 1e-5f);
  }
}

// LN apply -> split bf16 (hi + lo residual)
__global__ __launch_bounds__(256) void ln_apply(const float* __restrict__ in,
                                                u16* __restrict__ out_hi,
                                                u16* __restrict__ out_lo,
                                                const int* __restrict__ batch,
                                                const float* __restrict__ gmean,
                                                const float* __restrict__ grstd,
                                                const float* __restrict__ gamma,
                                                const float* __restrict__ beta) {
  int idx = blockIdx.x * blockDim.x + threadIdx.x;
  if (idx >= NN * 32) return;
  int n = idx >> 5, c4 = (idx & 31) * 4;
  int g = batch[n];
  float mean = gmean[g], rstd = grstd[g];
  float4 xv = *reinterpret_cast<const float4*>(in + (size_t)n * 128 + c4);
  float4 gv = *reinterpret_cast<const float4*>(gamma + c4);
  float4 bv = *reinterpret_cast<const float4*>(beta + c4);
  float v0 = elu_f((xv.x - mean) * rstd * gv.x + bv.x);
  float v1 = elu_f((xv.y - mean) * rstd * gv.y + bv.y);
  float v2 = elu_f((xv.z - mean) * rstd * gv.z + bv.z);
  float v3 = elu_f((xv.w - mean) * rstd * gv.w + bv.w);
  u16 h0 = f2b(v0), h1 = f2b(v1), h2 = f2b(v2), h3 = f2b(v3);
  uint2 hi = {(u32)h0 | ((u32)h1 << 16), (u32)h2 | ((u32)h3 << 16)};
  uint2 lo = {(u32)f2b(v0 - bf2f(h0)) | ((u32)f2b(v1 - bf2f(h1)) << 16),
              (u32)f2b(v2 - bf2f(h2)) | ((u32)f2b(v3 - bf2f(h3)) << 16)};
  *reinterpret_cast<uint2*>(out_hi + (size_t)n * 128 + c4) = hi;
  *reinterpret_cast<uint2*>(out_lo + (size_t)n * 128 + c4) = lo;
}

// ---------------- per-layer weight transforms ----------------
__global__ void build_wqe(const float* __restrict__ wq, const float* __restrict__ bq,
                          const float* __restrict__ we, float* __restrict__ WQE,
                          float* __restrict__ bqe) {
  int col = threadIdx.x;
  int row = blockIdx.x;
  int hh = col >> 6, j = col & 63;
  const float* wrow = (row < 128) ? (wq + (size_t)row * 128) : bq;
  float acc = 0.f;
  for (int c = 0; c < 64; ++c) acc += wrow[hh * 64 + c] * we[(size_t)j * 128 + hh * 64 + c];
  if (row < 128) WQE[(size_t)row * 128 + col] = acc;
  else bqe[col] = acc;
}

// fused: [wq|wk|wv|WQE|wsk] -> split bf16 MFMA B-fragments + ball
__global__ void build_wfrag2(const float* __restrict__ wq, const float* __restrict__ wk,
                             const float* __restrict__ wv, const float* __restrict__ WQE,
                             const float* __restrict__ wsk,
                             const float* __restrict__ bq, const float* __restrict__ bk,
                             const float* __restrict__ bv, const float* __restrict__ bqe,
                             const float* __restrict__ bsk,
                             u16* __restrict__ Wfrag_hi, u16* __restrict__ Wfrag_lo,
                             float* __restrict__ ball) {
  int idx = blockIdx.x * 256 + threadIdx.x;  // 81920 total
  if (idx < 81920) {
    int j = idx & 7, lane = (idx >> 3) & 63, rest = idx >> 9;
    int tg = rest % 40, s = rest / 40;
    int k = s * 32 + (lane >> 4) * 8 + j;
    int col = tg * 16 + (lane & 15);
    int sel = col >> 7, c = col & 127;
    const float* src = sel == 0 ? wq : sel == 1 ? wk : sel == 2 ? wv : sel == 3 ? WQE : wsk;
    float w = src[(size_t)k * 128 + c];
    u16 hi = f2b(w);
    Wfrag_hi[idx] = hi;
    Wfrag_lo[idx] = f2b(w - bf2f(hi));
  }
  if (idx < 640) {
    int sel = idx >> 7, c = idx & 127;
    const float* s2 = sel == 0 ? bq : sel == 1 ? bk : sel == 2 ? bv : sel == 3 ? bqe : bsk;
    ball[idx] = s2[c];
  }
}

// we[64x128] -> split bf16 fragments for bd_gemm
__global__ void build_wefrag(const float* __restrict__ we, u16* __restrict__ wef_hi,
                             u16* __restrict__ wef_lo) {
  int idx = blockIdx.x * 256 + threadIdx.x;  // 8192
  if (idx >= 8192) return;
  int j = idx & 7, lane = (idx >> 3) & 63, rest = idx >> 9;
  int t = rest & 3, hh = (rest >> 2) & 1, s = rest >> 3;
  int k = s * 32 + (lane >> 4) * 8 + j;
  int col = hh * 64 + t * 16 + (lane & 15);
  float w = we[(size_t)k * 128 + col];
  u16 hi = f2b(w);
  wef_hi[idx] = hi;
  wef_lo[idx] = f2b(w - bf2f(hi));
}

// up[64x64] f32 -> bf16 fragments
__global__ void build_upfrag(const float* __restrict__ up, u16* __restrict__ upfrag) {
  int idx = blockIdx.x * 256 + threadIdx.x;
  if (idx >= 4096) return;
  int j = idx & 7, lane = (idx >> 3) & 63, st = idx >> 9;
  int s = st >> 2, t = st & 3;
  int k = s * 32 + (lane >> 4) * 8 + j;
  int c = t * 16 + (lane & 15);
  upfrag[idx] = f2b(up[k * 64 + c]);
}

// W2 = up @ re_w [64x128]; bvec = ub @ re_w [128]
__global__ void build_w2(const float* __restrict__ up, const float* __restrict__ ub,
                         const float* __restrict__ re_w, float* __restrict__ W2,
                         float* __restrict__ bvec) {
  int idx = blockIdx.x * 256 + threadIdx.x;
  if (idx < 64 * 128) {
    int k_ = idx >> 7, c = idx & 127;
    float a = 0.f;
    for (int j = 0; j < 64; ++j) a = fmaf(up[k_ * 64 + j], re_w[j * 128 + c], a);
    W2[idx] = a;
  } else if (idx < 64 * 128 + 128) {
    int c = idx - 64 * 128;
    float a = 0.f;
    for (int j = 0; j < 64; ++j) a = fmaf(ub[j], re_w[j * 128 + c], a);
    bvec[c] = a;
  }
}

// ---------------- split-precision MFMA node GEMM ----------------
// nodebuf row layout (u16 idx): q[0..127] | qe[128..255] | kv interleaved [256..511]
__global__ __launch_bounds__(256) void node_gemm(const u16* __restrict__ h_hi,
                                                 const u16* __restrict__ h_lo,
                                                 const u16* __restrict__ Wfrag_hi,
                                                 const u16* __restrict__ Wfrag_lo,
                                                 const float* __restrict__ ball,
                                                 u16* __restrict__ nodebuf,
                                                 float* __restrict__ hn) {
  int tid = threadIdx.x;
  int lane = tid & 63;
  int wv = tid >> 6;
  int cb = blockIdx.x;
  int rbase = blockIdx.y * 64 + wv * 16;
  int rif = lane & 15, kg = lane >> 4;
  f32x4 acc[4] = {};
  int arow = rbase + rif;
  bool rowok = arow < NN;
  const u16* aph = h_hi + (size_t)arow * 128 + kg * 8;
  const u16* apl = h_lo + (size_t)arow * 128 + kg * 8;
#pragma unroll
  for (int s = 0; s < 4; ++s) {
    bf16x8 ah = {}, al = {};
    if (rowok) {
      ah = *reinterpret_cast<const bf16x8*>(aph + s * 32);
      al = *reinterpret_cast<const bf16x8*>(apl + s * 32);
    }
#pragma unroll
    for (int t = 0; t < 4; ++t) {
      size_t fo = ((size_t)((s * 40 + cb * 4 + t) * 64 + lane)) * 8;
      bf16x8 bh = *reinterpret_cast<const bf16x8*>(Wfrag_hi + fo);
      bf16x8 bl = *reinterpret_cast<const bf16x8*>(Wfrag_lo + fo);
      acc[t] = __builtin_amdgcn_mfma_f32_16x16x32_bf16(ah, bh, acc[t], 0, 0, 0);
      acc[t] = __builtin_amdgcn_mfma_f32_16x16x32_bf16(ah, bl, acc[t], 0, 0, 0);
      acc[t] = __builtin_amdgcn_mfma_f32_16x16x32_bf16(al, bh, acc[t], 0, 0, 0);
    }
  }
#pragma unroll
  for (int t = 0; t < 4; ++t) {
    int col = (cb * 4 + t) * 16 + rif;
    float bia = ball[col];
#pragma unroll
    for (int rg = 0; rg < 4; ++rg) {
      int row = rbase + kg * 4 + rg;
      if (row < NN) {
        float val = acc[t][rg] + bia;
        if (col < 512) {
          int idx;
          if (col < 128) idx = col;
          else if (col < 256) { int c1 = col - 128; idx = 256 + ((c1 >> 1) << 2) + (c1 & 1); }
          else if (col < 384) { int c2 = col - 256; idx = 256 + ((c2 >> 1) << 2) + 2 + (c2 & 1); }
          else idx = 128 + (col - 384);
          nodebuf[(size_t)row * 512 + idx] = f2b(val);
        } else {
          hn[(size_t)row * 128 + col - 512] = val;
        }
      }
    }
  }
}

// ---------------- MFMA edge GEMM: ea = elu(ea @ up + ub), in place ----------------
__global__ __launch_bounds__(256) void edge_gemm(u16* __restrict__ ea,
                                                 const u16* __restrict__ upfrag,
                                                 const float* __restrict__ ub) {
  int lane = threadIdx.x & 63;
  int gwave = (blockIdx.x * 256 + threadIdx.x) >> 6;
  int nwaves = (gridDim.x * 256) >> 6;
  bf16x8 bfrag[2][4];
#pragma unroll
  for (int s = 0; s < 2; ++s)
#pragma unroll
    for (int t = 0; t < 4; ++t)
      bfrag[s][t] = *reinterpret_cast<const bf16x8*>(upfrag + ((size_t)((s * 4 + t) * 64 + lane)) * 8);
  float bias_c[4];
#pragma unroll
  for (int t = 0; t < 4; ++t) bias_c[t] = ub[t * 16 + (lane & 15)];
  const int rif = lane & 15;
  const int kg = lane >> 4;
  for (int mt = gwave; mt < EE / 16; mt += nwaves) {
    size_t rowbase = (size_t)mt * 16;
    const u16* arow = ea + (rowbase + rif) * 64;
    bf16x8 a0 = *reinterpret_cast<const bf16x8*>(arow + kg * 8);
    bf16x8 a1 = *reinterpret_cast<const bf16x8*>(arow + 32 + kg * 8);
    f32x4 acc[4] = {};
#pragma unroll
    for (int t = 0; t < 4; ++t) {
      acc[t] = __builtin_amdgcn_mfma_f32_16x16x32_bf16(a0, bfrag[0][t], acc[t], 0, 0, 0);
      acc[t] = __builtin_amdgcn_mfma_f32_16x16x32_bf16(a1, bfrag[1][t], acc[t], 0, 0, 0);
    }
#pragma unroll
    for (int t = 0; t < 4; ++t)
#pragma unroll
      for (int rg = 0; rg < 4; ++rg) {
        float val = acc[t][rg] + bias_c[t];
        ea[(rowbase + kg * 4 + rg) * 64 + t * 16 + rif] = f2b(elu_f(val));
      }
  }
}

// ---------------- split-precision MFMA BD GEMM: hn += r @ BD (per-head we) ----------------
__global__ __launch_bounds__(256) void bd_gemm(const u16* __restrict__ r_hi,
                                               const u16* __restrict__ r_lo,
                                               const u16* __restrict__ wef_hi,
                                               const u16* __restrict__ wef_lo,
                                               float* __restrict__ hn) {
  int tid = threadIdx.x;
  int lane = tid & 63;
  int w = blockIdx.x * 4 + (tid >> 6);
  if (w >= NN / 16) return;
  int rif = lane & 15, kg = lane >> 4;
  size_t rowbase = (size_t)w * 16;
  const u16* ahb = r_hi + (rowbase + rif) * 128;
  const u16* alb = r_lo + (rowbase + rif) * 128;
  f32x4 acc[2][4] = {};
#pragma unroll
  for (int hh = 0; hh < 2; ++hh)
#pragma unroll
    for (int s = 0; s < 2; ++s) {
      int ko = hh * 64 + s * 32 + kg * 8;
      bf16x8 ah = *reinterpret_cast<const bf16x8*>(ahb + ko);
      bf16x8 al = *reinterpret_cast<const bf16x8*>(alb + ko);
#pragma unroll
      for (int t = 0; t < 4; ++t) {
        size_t fo = ((size_t)((((s * 2 + hh) * 4 + t)) * 64 + lane)) * 8;
        bf16x8 bh = *reinterpret_cast<const bf16x8*>(wef_hi + fo);
        bf16x8 bl = *reinterpret_cast<const bf16x8*>(wef_lo + fo);
        acc[hh][t] = __builtin_amdgcn_mfma_f32_16x16x32_bf16(ah, bh, acc[hh][t], 0, 0, 0);
        acc[hh][t] = __builtin_amdgcn_mfma_f32_16x16x32_bf16(ah, bl, acc[hh][t], 0, 0, 0);
        acc[hh][t] = __builtin_amdgcn_mfma_f32_16x16x32_bf16(al, bh, acc[hh][t], 0, 0, 0);
      }
    }
#pragma unroll
  for (int hh = 0; hh < 2; ++hh)
#pragma unroll
    for (int t = 0; t < 4; ++t)
#pragma unroll
      for (int rg = 0; rg < 4; ++rg) {
        size_t row = rowbase + kg * 4 + rg;
        int col = hh * 64 + t * 16 + rif;
        hn[row * 128 + col] += acc[hh][t][rg];
      }
}

// per-src-graph sum of current ea rows, 16 chunks per graph + atomic merge
__global__ __launch_bounds__(256) void gsum_pre(const u16* __restrict__ ea,
                                                const int* __restrict__ sg_start,
                                                const int* __restrict__ sg_perm,
                                                float* __restrict__ gsum_in) {
  __shared__ float red[8][64];
  int g = blockIdx.x, t = threadIdx.x;
  int c2 = t & 31;
  int rgrp = t >> 5;
  int gr = blockIdx.y * 8 + rgrp;
  int p0 = sg_start[g], p1 = sg_start[g + 1];
  float slo = 0.f, shi = 0.f;
  for (int i = p0 + gr; i < p1; i += 128) {
    int pos = sg_perm[i];
    u32 w = ((const u32*)ea)[(size_t)pos * 32 + c2];
    slo += lo2f(w);
    shi += hi2f(w);
  }
  red[rgrp][c2 * 2] = slo;
  red[rgrp][c2 * 2 + 1] = shi;
  __syncthreads();
  if (t < 64) {
    float a = 0.f;
#pragma unroll
    for (int rr = 0; rr < 8; ++rr) a += red[rr][t];
    atomicAdd(&gsum_in[(size_t)g * 64 + t], a);
  }
}

// embE = elu(gsum_in @ W2 + cnt*bvec + re_b)
__global__ void emb_e_kernel(const float* __restrict__ gsum_in, const int* __restrict__ sg_start,
                             const float* __restrict__ W2, const float* __restrict__ bvec,
                             const float* __restrict__ re_b, float* __restrict__ embE) {
  int g = blockIdx.x, c = threadIdx.x;
  float cnt = (float)(sg_start[g + 1] - sg_start[g]);
  float a = re_b[c] + cnt * bvec[c];
  for (int k_ = 0; k_ < 64; ++k_) a = fmaf(gsum_in[(size_t)g * 64 + k_], W2[k_ * 128 + c], a);
  embE[(size_t)g * 128 + c] = elu_f(a);
}

// ---------------- fused flash attention, one wave per dst node, dual chains ----------------
__global__ __launch_bounds__(256) void attn_node(const u32* __restrict__ nodebuf,
                                                 const u16* __restrict__ ea,
                                                 const int* __restrict__ row_start,
                                                 const int* __restrict__ csr_src,
                                                 float* __restrict__ hn,
                                                 u32* __restrict__ r_hi,
                                                 u32* __restrict__ r_lo) {
  int d = (blockIdx.x * blockDim.x + threadIdx.x) >> 6;
  if (d >= NN) return;
  int lane = threadIdx.x & 63;
  int p0 = row_start[d], p1 = row_start[d + 1];
  if (p0 == p1) {
    r_hi[(size_t)d * 64 + lane] = 0u;
    r_lo[(size_t)d * 64 + lane] = 0u;
    return;
  }
  int cnt = p1 - p0;
  size_t dbase = (size_t)d * 256;
  u32 qv = nodebuf[dbase + lane];
  u32 qev = nodebuf[dbase + 64 + lane];
  const int lea = lane & 31;
  float mA = -3.4e38f, sA = 0.f, a0A = 0.f, a1A = 0.f, r0A = 0.f, r1A = 0.f;
  float mB = -3.4e38f, sB = 0.f, a0B = 0.f, a1B = 0.f, r0B = 0.f, r1B = 0.f;
  // preload first pair
  int sa = csr_src[p0];
  uint2 kvA = *((const uint2*)(nodebuf + (size_t)sa * 256 + 128) + lane);
  u32 eaA = ((const u32*)ea)[(size_t)p0 * 32 + lea];
  int pB0 = (cnt > 1) ? p0 + 1 : p0;
  int sb = csr_src[pB0];
  uint2 kvB = *((const uint2*)(nodebuf + (size_t)sb * 256 + 128) + lane);
  u32 eaB = ((const u32*)ea)[(size_t)pB0 * 32 + lea];
  for (int i = 0; i < cnt; i += 2) {
    int ni = i + 2;
    int nA = (ni < cnt) ? p0 + ni : p0;
    int nB = (ni + 1 < cnt) ? p0 + ni + 1 : p0;
    int sa2 = csr_src[nA];
    uint2 kvA2 = *((const uint2*)(nodebuf + (size_t)sa2 * 256 + 128) + lane);
    u32 eaA2 = ((const u32*)ea)[(size_t)nA * 32 + lea];
    int sb2 = csr_src[nB];
    uint2 kvB2 = *((const uint2*)(nodebuf + (size_t)sb2 * 256 + 128) + lane);
    u32 eaB2 = ((const u32*)ea)[(size_t)nB * 32 + lea];
    float pA = lo2f(qv) * lo2f(kvA.x) + hi2f(qv) * hi2f(kvA.x) +
               lo2f(qev) * lo2f(eaA) + hi2f(qev) * hi2f(eaA);
    float pB = lo2f(qv) * lo2f(kvB.x) + hi2f(qv) * hi2f(kvB.x) +
               lo2f(qev) * lo2f(eaB) + hi2f(qev) * hi2f(eaB);
#pragma unroll
    for (int mm = 16; mm; mm >>= 1) {
      pA += __shfl_xor(pA, mm, 64);
      pB += __shfl_xor(pB, mm, 64);
    }
    {
      float l = pA * 0.125f;
      float mn = fmaxf(mA, l);
      float f = __expf(mA - mn), w = __expf(l - mn);
      sA = sA * f + w;
      a0A = a0A * f + w * lo2f(kvA.y); a1A = a1A * f + w * hi2f(kvA.y);
      r0A = r0A * f + w * lo2f(eaA);   r1A = r1A * f + w * hi2f(eaA);
      mA = mn;
    }
    if (i + 1 < cnt) {
      float l = pB * 0.125f;
      float mn = fmaxf(mB, l);
      float f = __expf(mB - mn), w = __expf(l - mn);
      sB = sB * f + w;
      a0B = a0B * f + w * lo2f(kvB.y); a1B = a1B * f + w * hi2f(kvB.y);
      r0B = r0B * f + w * lo2f(eaB);   r1B = r1B * f + w * hi2f(eaB);
      mB = mn;
    }
    kvA = kvA2; eaA = eaA2; kvB = kvB2; eaB = eaB2;
  }
  // merge chains
  float mn = fmaxf(mA, mB);
  float fA = __expf(mA - mn);
  float fB = (cnt > 1) ? __expf(mB - mn) : 0.f;
  float ssum = sA * fA + sB * fB;
  float a0 = a0A * fA + a0B * fB, a1 = a1A * fA + a1B * fB;
  float r0 = r0A * fA + r0B * fB, r1 = r1A * fA + r1B * fB;
  float inv = 1.f / ssum;
  size_t ob = (size_t)d * 128 + lane * 2;
  hn[ob] += a0 * inv;
  hn[ob + 1] += a1 * inv;
  float rv0 = r0 * inv, rv1 = r1 * inv;
  u16 h0 = f2b(rv0), h1 = f2b(rv1);
  r_hi[(size_t)d * 64 + lane] = (u32)h0 | ((u32)h1 << 16);
  r_lo[(size_t)d * 64 + lane] = (u32)f2b(rv0 - bf2f(h0)) | ((u32)f2b(rv1 - bf2f(h1)) << 16);
}

// ---------------- SAG pooling ----------------
__global__ __launch_bounds__(256) void node_dots(const float* __restrict__ hn,
                                                 const float* __restrict__ wrel,
                                                 const float* __restrict__ wroot,
                                                 float* __restrict__ hrel,
                                                 float* __restrict__ troot) {
  int n = (blockIdx.x * blockDim.x + threadIdx.x) >> 6;
  if (n >= NN) return;
  int lane = threadIdx.x & 63;
  float x0 = hn[(size_t)n * 128 + lane], x1 = hn[(size_t)n * 128 + 64 + lane];
  float tr = wred64(x0 * wrel[lane] + x1 * wrel[64 + lane]);
  float tt = wred64(x0 * wroot[lane] + x1 * wroot[64 + lane]);
  if (lane == 0) { hrel[n] = tr; troot[n] = tt; }
}

__global__ __launch_bounds__(256) void sag_gather(const float* __restrict__ hrel,
                                                  const float* __restrict__ troot,
                                                  const float* __restrict__ brel,
                                                  const int* __restrict__ row_start,
                                                  const int* __restrict__ csr_src,
                                                  const int* __restrict__ batch,
                                                  float* __restrict__ sc, unsigned* __restrict__ gm) {
  int n = blockIdx.x * blockDim.x + threadIdx.x;
  if (n >= NN) return;
  float s = 0.f;
  int p1 = row_start[n + 1];
  for (int pos = row_start[n]; pos < p1; ++pos) s += hrel[csr_src[pos]];
  float v = s + troot[n] + brel[0];
  sc[n] = v;
  atomicMax(&gm[batch[n]], fenc(v));
}

__global__ __launch_bounds__(256) void sag_exp(const float* __restrict__ sc,
                                               const int* __restrict__ batch,
                                               const unsigned* __restrict__ gm,
                                               float* __restrict__ gs, float* __restrict__ scp) {
  int n = blockIdx.x * blockDim.x + threadIdx.x;
  if (n >= NN) return;
  int g = batch[n];
  float p = __expf(sc[n] - fdec(gm[g]));
  scp[n] = p;
  atomicAdd(&gs[g], p);
}

__global__ void emb_block(const float* __restrict__ hn, const float* __restrict__ scp,
                          const float* __restrict__ gs, const int* __restrict__ gstart,
                          const float* __restrict__ embE, float* __restrict__ dstv) {
  __shared__ float part[2];
  int g = blockIdx.x, c = threadIdx.x;
  int n0 = gstart[g], n1 = gstart[g + 1];
  float invg = 1.f / gs[g];
  float acc = 0.f;
  for (int n = n0; n < n1; ++n) acc = fmaf(hn[(size_t)n * 128 + c], scp[n] * invg, acc);
  float val = acc * embE[(size_t)g * 128 + c];
  float sq = val * val;
#pragma unroll
  for (int mm = 32; mm; mm >>= 1) sq += __shfl_xor(sq, mm, 64);
  if ((c & 63) == 0) part[c >> 6] = sq;
  __syncthreads();
  float nrm = sqrtf(part[0] + part[1]);
  dstv[(size_t)g * 128 + c] = elu_f(val / fmaxf(nrm, 1e-12f));
}

__global__ void final_combine(const float* __restrict__ e0, const float* __restrict__ e1,
                              float* __restrict__ out) {
  int idx = blockIdx.x * blockDim.x + threadIdx.x;
  if (idx >= GG * 128) return;
  out[idx] = 0.6f * e0[idx] + 0.4f * e1[idx];
}

// =====================================================================
extern "C" void kernel_launch(void* const* d_in, const int* in_sizes, int n_in,
                              void* d_out, int out_size, void* d_ws, size_t ws_size,
                              hipStream_t stream) {
  const float* x = (const float*)d_in[0];
  const float* edge_attr = (const float*)d_in[1];
  const int* edge_index = (const int*)d_in[2];
  const int* batch = (const int*)d_in[3];
  const float* w0 = (const float*)d_in[4];
  const float* b0 = (const float*)d_in[5];
  const float* we0 = (const float*)d_in[6];
  const float* be0 = (const float*)d_in[7];
  const float* ln0_g = (const float*)d_in[8];
  const float* ln0_b = (const float*)d_in[9];
  const float* qkv_w = (const float*)d_in[10];
  const float* qkv_b = (const float*)d_in[11];
  const float* edge_w = (const float*)d_in[12];
  const float* skip_w = (const float*)d_in[13];
  const float* skip_b = (const float*)d_in[14];
  const float* up_w = (const float*)d_in[15];
  const float* up_b = (const float*)d_in[16];
  const float* ng = (const float*)d_in[17];
  const float* nbeta = (const float*)d_in[18];
  const float* sag_wrel = (const float*)d_in[19];
  const float* sag_brel = (const float*)d_in[20];
  const float* sag_wroot = (const float*)d_in[21];
  const float* re_w = (const float*)d_in[22];
  const float* re_b = (const float*)d_in[23];
  const int* srcp = edge_index;
  const int* dstp = edge_index + EE;
  float* out = (float*)d_out;
  (void)in_sizes; (void)n_in;

  float* ws = (float*)d_ws;
  size_t o = 0;
  auto alloc = [&](size_t n) { n = (n + 3) & ~(size_t)3; float* p = ws + o; o += n; return p; };
  u16* h_hi = (u16*)alloc((size_t)NN * 64);
  u16* h_lo = (u16*)alloc((size_t)NN * 64);
  float* hn = alloc((size_t)NN * 128);
  u32* r_hi = (u32*)alloc((size_t)NN * 64);
  u32* r_lo = (u32*)alloc((size_t)NN * 64);
  u16* nodebuf = (u16*)alloc((size_t)NN * 256);   // NN x 512 bf16 (q|qe|kv)
  u16* ea = (u16*)alloc((size_t)EE * 32);         // EE x 64 bf16, dst-CSR order
  int* csr_src = (int*)alloc(EE);
  int* epos = (int*)alloc(EE);
  int* deg = (int*)alloc(NN);
  int* row_start = (int*)alloc(NN + 1);
  int* cursor = (int*)alloc(NN);
  int* out_start = (int*)alloc(NN + 1);
  int* gstart = (int*)alloc(GG + 1);
  int* sg_perm = (int*)alloc(EE);
  int* sg_start = (int*)alloc(GG + 1);
  float* gsum_in = alloc(GG * 64);
  float* W2 = alloc(64 * 128);
  float* bvec = alloc(128);
  u16* upfrag = (u16*)alloc(2048);
  u16* Wfrag_hi = (u16*)alloc(40960);
  u16* Wfrag_lo = (u16*)alloc(40960);
  u16* wef_hi = (u16*)alloc(4096);
  u16* wef_lo = (u16*)alloc(4096);
  u16* wef0_hi = (u16*)alloc(1024);               // 2048 u16
  u16* wef0_lo = (u16*)alloc(1024);
  unsigned* gm = (unsigned*)alloc(GG);            // zero-block (gm, gs)
  float* gs = alloc(GG);
  float* gmean = alloc(GG);
  float* grstd = alloc(GG);
  float* WQE = alloc(128 * 128);
  float* bqe = alloc(128);
  float* ball = alloc(640);
  float* hrel = alloc(NN);
  float* troot = alloc(NN);
  float* sc = alloc(NN);
  float* scp = alloc(NN);
  float* embE = alloc(GG * 128);
  float* embs0 = alloc(GG * 128);
  float* embs1 = alloc(GG * 128);

  const size_t need = o * sizeof(float);
  if (ws_size < need) {
    hipMemsetAsync(d_out, 0, (size_t)out_size * sizeof(float), stream);
    return;
  }

  auto gemm = [&](const float* A, const float* B, const float* bias, float* C,
                  int M, int Nn, int K, int act, int accum) {
    dim3 g((Nn + 63) / 64, (M + 63) / 64);
    gemm_kernel<<<g, 256, 0, stream>>>(A, B, bias, C, M, Nn, K, act, accum);
  };
  auto graph_ln = [&](const float* in, const float* gamma, const float* beta) {
    ln_stats_block<<<GG, 256, 0, stream>>>(in, gstart, gmean, grstd);
    ln_apply<<<NN * 32 / 256, 256, 0, stream>>>(in, h_hi, h_lo, batch, gmean, grstd, gamma, beta);
  };
  auto tconv = [&](int il) {
    const float* wq = qkv_w + (size_t)(il * 3 + 0) * 128 * 128;
    const float* wk = qkv_w + (size_t)(il * 3 + 1) * 128 * 128;
    const float* wv = qkv_w + (size_t)(il * 3 + 2) * 128 * 128;
    const float* bq = qkv_b + (il * 3 + 0) * 128;
    const float* bk = qkv_b + (il * 3 + 1) * 128;
    const float* bv = qkv_b + (il * 3 + 2) * 128;
    const float* we = edge_w + (size_t)il * 64 * 128;
    const float* wsk = skip_w + (size_t)il * 128 * 128;
    const float* bsk = skip_b + il * 128;
    build_wqe<<<129, 128, 0, stream>>>(wq, bq, we, WQE, bqe);
    build_wfrag2<<<320, 256, 0, stream>>>(wq, wk, wv, WQE, wsk, bq, bk, bv, bqe, bsk,
                                          Wfrag_hi, Wfrag_lo, ball);
    build_wefrag<<<32, 256, 0, stream>>>(we, wef_hi, wef_lo);
    dim3 ng2(10, (NN + 63) / 64);
    node_gemm<<<ng2, 256, 0, stream>>>(h_hi, h_lo, Wfrag_hi, Wfrag_lo, ball, nodebuf, hn);
    attn_node<<<NN / 4, 256, 0, stream>>>((const u32*)nodebuf, ea, row_start, csr_src, hn,
                                          r_hi, r_lo);
    bd_gemm<<<(NN / 16 + 3) / 4, 256, 0, stream>>>((const u16*)r_hi, (const u16*)r_lo,
                                                   wef_hi, wef_lo, hn);
  };
  auto ea_mlp = [&](int il) {
    build_upfrag<<<16, 256, 0, stream>>>(up_w + (size_t)il * 4096, upfrag);
    edge_gemm<<<2048, 256, 0, stream>>>(ea, upfrag, up_b + il * 64);
  };

  // one-time topology structures
  hipMemsetAsync(deg, 0, NN * sizeof(int), stream);
  csr_hist<<<(EE + 255) / 256, 256, 0, stream>>>(dstp, deg);
  csr_scan<<<1, 256, 0, stream>>>(deg, row_start, cursor);
  gstart_build<<<(NN + 256) / 256, 256, 0, stream>>>(batch, gstart);
  csr_pos<<<(EE + 255) / 256, 256, 0, stream>>>(srcp, dstp, cursor, csr_src, epos);
  build_we0frag<<<8, 256, 0, stream>>>(we0, wef0_hi, wef0_lo);
  ea_enc_mfma<<<2048, 256, 0, stream>>>(edge_attr, wef0_hi, wef0_lo, be0, epos, ea);
  hipMemsetAsync(deg, 0, NN * sizeof(int), stream);
  out_hist<<<(EE + 255) / 256, 256, 0, stream>>>(csr_src, deg);
  csr_scan<<<1, 256, 0, stream>>>(deg, out_start, cursor);
  out_fill<<<(EE + 255) / 256, 256, 0, stream>>>(csr_src, cursor, sg_perm);
  sgstart_build<<<2, 256, 0, stream>>>(out_start, gstart, sg_start);
  // node encoder + first LN
  gemm(x, w0, b0, hn, NN, 128, 64, 0, 0);
  graph_ln(hn, ln0_g, ln0_b);

  for (int i = 0; i < 2; ++i) {
    tconv(i * 2 + 0);
    graph_ln(hn, ng + (i * 2) * 128, nbeta + (i * 2) * 128);
    ea_mlp(i * 2);
    tconv(i * 2 + 1);
    // SAG pooling on pre-LN conv2 output hn; edge emb via linearity
    hipMemsetAsync(gm, 0, 2 * GG * sizeof(float), stream);       // gm, gs
    hipMemsetAsync(gsum_in, 0, GG * 64 * sizeof(float), stream);
    dim3 gsg(GG, 16);
    gsum_pre<<<gsg, 256, 0, stream>>>(ea, sg_start, sg_perm, gsum_in);
    build_w2<<<33, 256, 0, stream>>>(up_w + (size_t)(i * 2 + 1) * 4096,
                                     up_b + (i * 2 + 1) * 64,
                                     re_w + (size_t)i * 64 * 128, W2, bvec);
    ea_mlp(i * 2 + 1);
    node_dots<<<NN / 4, 256, 0, stream>>>(hn, sag_wrel + i * 128, sag_wroot + i * 128, hrel, troot);
    sag_gather<<<(NN + 255) / 256, 256, 0, stream>>>(hrel, troot, sag_brel + i, row_start,
                                                     csr_src, batch, sc, gm);
    sag_exp<<<(NN + 255) / 256, 256, 0, stream>>>(sc, batch, gm, gs, scp);
    emb_e_kernel<<<GG, 128, 0, stream>>>(gsum_in, sg_start, W2, bvec, re_b + i * 128, embE);
    emb_block<<<GG, 128, 0, stream>>>(hn, scp, gs, gstart, embE, i == 0 ? embs0 : embs1);
    graph_ln(hn, ng + (i * 2 + 1) * 128, nbeta + (i * 2 + 1) * 128);
  }
  final_combine<<<GG * 128 / 256, 256, 0, stream>>>(embs0, embs1, out);
}

// Round 9
// 1763.720 us; speedup vs baseline: 6.7348x; 1.1836x over previous
//
#include <hip/hip_runtime.h>
#include <math.h>

#define NN 50000
#define EE 800000
#define GG 256

typedef unsigned short u16;
typedef unsigned int u32;
typedef __attribute__((ext_vector_type(4))) float f32x4;
typedef __attribute__((ext_vector_type(8))) short bf16x8;

__device__ __forceinline__ float elu_f(float x) { return x > 0.f ? x : expm1f(x); }

__device__ __forceinline__ unsigned fenc(float f) {
  unsigned b = __float_as_uint(f);
  return (b & 0x80000000u) ? ~b : (b | 0x80000000u);
}
__device__ __forceinline__ float fdec(unsigned u) {
  return __uint_as_float((u & 0x80000000u) ? (u ^ 0x80000000u) : ~u);
}
__device__ __forceinline__ u16 f2b(float f) {
  u32 u = __float_as_uint(f);
  u32 r = (u + 0x7fffu + ((u >> 16) & 1u)) >> 16;
  return (u16)r;
}
__device__ __forceinline__ float bf2f(u16 u) { return __uint_as_float(((u32)u) << 16); }
__device__ __forceinline__ float lo2f(u32 p) { return __uint_as_float(p << 16); }
__device__ __forceinline__ float hi2f(u32 p) { return __uint_as_float(p & 0xffff0000u); }

__device__ __forceinline__ float wred64(float v) {
#pragma unroll
  for (int m = 32; m; m >>= 1) v += __shfl_xor(v, m, 64);
  return v;
}

// ---------------- generic tiled f32 GEMM: C = act(A@B + bias (+C)) ----------------
__global__ __launch_bounds__(256) void gemm_kernel(
    const float* __restrict__ A, const float* __restrict__ B,
    const float* __restrict__ bias, float* __restrict__ C,
    int M, int Nn, int K, int act, int accum) {
  __shared__ float As[16][68];
  __shared__ float Bs[16][68];
  const int bm = blockIdx.y * 64;
  const int bn = blockIdx.x * 64;
  const int tid = threadIdx.x;
  const int tx = tid & 15, ty = tid >> 4;
  const int lr = tid >> 2;
  const int lk = (tid & 3) << 2;
  float acc[4][4] = {};
  for (int k0 = 0; k0 < K; k0 += 16) {
    int arow = bm + lr;
    float4 a4 = {0.f, 0.f, 0.f, 0.f};
    if (arow < M) a4 = *reinterpret_cast<const float4*>(A + (size_t)arow * K + k0 + lk);
    As[lk + 0][lr] = a4.x; As[lk + 1][lr] = a4.y;
    As[lk + 2][lr] = a4.z; As[lk + 3][lr] = a4.w;
    float4 b4 = *reinterpret_cast<const float4*>(B + (size_t)(k0 + ty) * Nn + bn + tx * 4);
    *reinterpret_cast<float4*>(&Bs[ty][tx * 4]) = b4;
    __syncthreads();
#pragma unroll
    for (int kk = 0; kk < 16; ++kk) {
      float4 av = *reinterpret_cast<const float4*>(&As[kk][ty * 4]);
      float4 bv = *reinterpret_cast<const float4*>(&Bs[kk][tx * 4]);
      float a_[4] = {av.x, av.y, av.z, av.w};
      float b_[4] = {bv.x, bv.y, bv.z, bv.w};
#pragma unroll
      for (int ii = 0; ii < 4; ++ii)
#pragma unroll
        for (int jj = 0; jj < 4; ++jj)
          acc[ii][jj] = fmaf(a_[ii], b_[jj], acc[ii][jj]);
    }
    __syncthreads();
  }
#pragma unroll
  for (int ii = 0; ii < 4; ++ii) {
    int row = bm + ty * 4 + ii;
    if (row >= M) continue;
#pragma unroll
    for (int jj = 0; jj < 4; ++jj) {
      int col = bn + tx * 4 + jj;
      float val = acc[ii][jj];
      if (bias) val += bias[col];
      if (accum) val += C[(size_t)row * Nn + col];
      if (act) val = elu_f(val);
      C[(size_t)row * Nn + col] = val;
    }
  }
}

// ---------------- CSR build ----------------
__global__ void csr_hist(const int* __restrict__ dst, int* __restrict__ deg) {
  int e = blockIdx.x * blockDim.x + threadIdx.x;
  if (e < EE) atomicAdd(&deg[dst[e]], 1);
}

// hierarchical exclusive scan over n<=65536 ints: scan1 (per-block), scan2 (block sums), scan3 (combine)
__global__ void scan1(const int* __restrict__ deg, int* __restrict__ pre,
                      int* __restrict__ bsum, int n) {
  __shared__ int s[256];
  int t = threadIdx.x;
  int i = blockIdx.x * 256 + t;
  int v = (i < n) ? deg[i] : 0;
  s[t] = v;
  __syncthreads();
  for (int off = 1; off < 256; off <<= 1) {
    int tmp = (t >= off) ? s[t - off] : 0;
    __syncthreads();
    s[t] += tmp;
    __syncthreads();
  }
  if (i < n) pre[i] = s[t] - v;  // exclusive within block
  if (t == 255) bsum[blockIdx.x] = s[255];
}

__global__ void scan2(int* __restrict__ bsum, int nb) {
  __shared__ int s[256];
  int t = threadIdx.x;
  int v = (t < nb) ? bsum[t] : 0;
  s[t] = v;
  __syncthreads();
  for (int off = 1; off < 256; off <<= 1) {
    int tmp = (t >= off) ? s[t - off] : 0;
    __syncthreads();
    s[t] += tmp;
    __syncthreads();
  }
  if (t < nb) bsum[t] = s[t] - v;  // exclusive
}

__global__ void scan3(const int* __restrict__ pre, const int* __restrict__ bsum,
                      const int* __restrict__ deg, int* __restrict__ row_start,
                      int* __restrict__ cursor, int n) {
  int i = blockIdx.x * 256 + threadIdx.x;
  if (i < n) {
    int v = pre[i] + bsum[blockIdx.x];
    row_start[i] = v;
    cursor[i] = v;
    if (i == n - 1) row_start[n] = v + deg[i];
  }
}

__global__ void gstart_build(const int* __restrict__ batch, int* __restrict__ gstart) {
  int n = blockIdx.x * blockDim.x + threadIdx.x;
  if (n > NN) return;
  int b = (n < NN) ? batch[n] : GG;
  int pb = (n == 0) ? -1 : batch[n - 1];
  for (int g = pb + 1; g <= b; ++g) gstart[g] = n;
}

// per-edge CSR position + record
__global__ void csr_pos(const int* __restrict__ src, const int* __restrict__ dst,
                        int* __restrict__ cursor, int* __restrict__ csr_src,
                        int* __restrict__ epos) {
  int e = blockIdx.x * blockDim.x + threadIdx.x;
  if (e >= EE) return;
  int pos = atomicAdd(&cursor[dst[e]], 1);
  csr_src[pos] = src[e];
  epos[e] = pos;
}

__global__ void out_hist(const int* __restrict__ csr_src, int* __restrict__ odeg) {
  int pos = blockIdx.x * blockDim.x + threadIdx.x;
  if (pos < EE) atomicAdd(&odeg[csr_src[pos]], 1);
}

__global__ void out_fill(const int* __restrict__ csr_src, int* __restrict__ ocursor,
                         int* __restrict__ operm) {
  int pos = blockIdx.x * blockDim.x + threadIdx.x;
  if (pos < EE) {
    int slot = atomicAdd(&ocursor[csr_src[pos]], 1);
    operm[slot] = pos;
  }
}

__global__ void sgstart_build(const int* __restrict__ out_start, const int* __restrict__ gstart,
                              int* __restrict__ sg_start) {
  int t = blockIdx.x * blockDim.x + threadIdx.x;
  if (t <= GG) sg_start[t] = out_start[gstart[t]];
}

// we0[16x64] -> split bf16 fragments, K padded to 32 (k>=16 -> 0)
__global__ void build_we0frag(const float* __restrict__ we0, u16* __restrict__ wf_hi,
                              u16* __restrict__ wf_lo) {
  int idx = blockIdx.x * 256 + threadIdx.x;  // 2048
  if (idx >= 2048) return;
  int j = idx & 7, lane = (idx >> 3) & 63, t = idx >> 9;
  int k = (lane >> 4) * 8 + j;
  int c = t * 16 + (lane & 15);
  float w = (k < 16) ? we0[(size_t)k * 64 + c] : 0.f;
  u16 hi = f2b(w);
  wf_hi[idx] = hi;
  wf_lo[idx] = f2b(w - bf2f(hi));
}

// MFMA edge encoder: ea[epos[e]] = elu(edge_attr[e] @ we0 + be0), 16 edges/wave
__global__ __launch_bounds__(256) void ea_enc_mfma(const float* __restrict__ edge_attr,
                                                   const u16* __restrict__ wf_hi,
                                                   const u16* __restrict__ wf_lo,
                                                   const float* __restrict__ be0,
                                                   const int* __restrict__ epos,
                                                   u16* __restrict__ ea) {
  int lane = threadIdx.x & 63;
  int gwave = (blockIdx.x * 256 + threadIdx.x) >> 6;
  int nwaves = (gridDim.x * 256) >> 6;
  bf16x8 bh[4], bl[4];
#pragma unroll
  for (int t = 0; t < 4; ++t) {
    bh[t] = *reinterpret_cast<const bf16x8*>(wf_hi + ((size_t)(t * 64 + lane)) * 8);
    bl[t] = *reinterpret_cast<const bf16x8*>(wf_lo + ((size_t)(t * 64 + lane)) * 8);
  }
  float bias_c[4];
#pragma unroll
  for (int t = 0; t < 4; ++t) bias_c[t] = be0[t * 16 + (lane & 15)];
  const int rif = lane & 15;
  const int kg = lane >> 4;
  for (int mt = gwave; mt < EE / 16; mt += nwaves) {
    int base = mt * 16;
    bf16x8 ah = {}, al = {};
    if (kg < 2) {
      const float* ap = edge_attr + (size_t)(base + rif) * 16 + kg * 8;
      float4 f0 = *reinterpret_cast<const float4*>(ap);
      float4 f1 = *reinterpret_cast<const float4*>(ap + 4);
      float fv[8] = {f0.x, f0.y, f0.z, f0.w, f1.x, f1.y, f1.z, f1.w};
#pragma unroll
      for (int jj = 0; jj < 8; ++jj) {
        u16 hi = f2b(fv[jj]);
        ah[jj] = (short)hi;
        al[jj] = (short)f2b(fv[jj] - bf2f(hi));
      }
    }
    f32x4 acc[4] = {};
#pragma unroll
    for (int t = 0; t < 4; ++t) {
      acc[t] = __builtin_amdgcn_mfma_f32_16x16x32_bf16(ah, bh[t], acc[t], 0, 0, 0);
      acc[t] = __builtin_amdgcn_mfma_f32_16x16x32_bf16(ah, bl[t], acc[t], 0, 0, 0);
      acc[t] = __builtin_amdgcn_mfma_f32_16x16x32_bf16(al, bh[t], acc[t], 0, 0, 0);
    }
#pragma unroll
    for (int rg = 0; rg < 4; ++rg) {
      int pr = epos[base + kg * 4 + rg];
#pragma unroll
      for (int t = 0; t < 4; ++t)
        ea[(size_t)pr * 64 + t * 16 + rif] = f2b(elu_f(acc[t][rg] + bias_c[t]));
    }
  }
}

// ---------------- graph LayerNorm ----------------
__global__ __launch_bounds__(256) void ln_stats_block(const float* __restrict__ h,
                                                      const int* __restrict__ gstart,
                                                      float* __restrict__ gmean,
                                                      float* __restrict__ grstd) {
  __shared__ float ls[4], lss[4];
  int g = blockIdx.x, t = threadIdx.x;
  int n0 = gstart[g], n1 = gstart[g + 1];
  int total4 = (n1 - n0) * 32;
  const float4* base = (const float4*)(h + (size_t)n0 * 128);
  float s = 0.f, ss = 0.f;
  for (int i = t; i < total4; i += 256) {
    float4 v = base[i];
    s += v.x + v.y + v.z + v.w;
    ss += v.x * v.x + v.y * v.y + v.z * v.z + v.w * v.w;
  }
  s = wred64(s);
  ss = wred64(ss);
  if ((t & 63) == 0) { ls[t >> 6] = s; lss[t >> 6] = ss; }
  __syncthreads();
  if (t == 0) {
    float S = ls[0] + ls[1] + ls[2] + ls[3];
    float SS = lss[0] + lss[1] + lss[2] + lss[3];
    float cnt = fmaxf((float)(n1 - n0) * 128.f, 1.0f);
    float mean = S / cnt;
    float var = fmaxf(SS / cnt - mean * mean, 0.f);
    gmean[g] = mean;
    grstd[g] = rsqrtf(var + 1e-5f);
  }
}

// LN apply -> split bf16 (hi + lo residual)
__global__ __launch_bounds__(256) void ln_apply(const float* __restrict__ in,
                                                u16* __restrict__ out_hi,
                                                u16* __restrict__ out_lo,
                                                const int* __restrict__ batch,
                                                const float* __restrict__ gmean,
                                                const float* __restrict__ grstd,
                                                const float* __restrict__ gamma,
                                                const float* __restrict__ beta) {
  int idx = blockIdx.x * blockDim.x + threadIdx.x;
  if (idx >= NN * 32) return;
  int n = idx >> 5, c4 = (idx & 31) * 4;
  int g = batch[n];
  float mean = gmean[g], rstd = grstd[g];
  float4 xv = *reinterpret_cast<const float4*>(in + (size_t)n * 128 + c4);
  float4 gv = *reinterpret_cast<const float4*>(gamma + c4);
  float4 bv = *reinterpret_cast<const float4*>(beta + c4);
  float v0 = elu_f((xv.x - mean) * rstd * gv.x + bv.x);
  float v1 = elu_f((xv.y - mean) * rstd * gv.y + bv.y);
  float v2 = elu_f((xv.z - mean) * rstd * gv.z + bv.z);
  float v3 = elu_f((xv.w - mean) * rstd * gv.w + bv.w);
  u16 h0 = f2b(v0), h1 = f2b(v1), h2 = f2b(v2), h3 = f2b(v3);
  uint2 hi = {(u32)h0 | ((u32)h1 << 16), (u32)h2 | ((u32)h3 << 16)};
  uint2 lo = {(u32)f2b(v0 - bf2f(h0)) | ((u32)f2b(v1 - bf2f(h1)) << 16),
              (u32)f2b(v2 - bf2f(h2)) | ((u32)f2b(v3 - bf2f(h3)) << 16)};
  *reinterpret_cast<uint2*>(out_hi + (size_t)n * 128 + c4) = hi;
  *reinterpret_cast<uint2*>(out_lo + (size_t)n * 128 + c4) = lo;
}

// ---------------- per-layer weight transforms ----------------
__global__ void build_wqe(const float* __restrict__ wq, const float* __restrict__ bq,
                          const float* __restrict__ we, float* __restrict__ WQE,
                          float* __restrict__ bqe) {
  int col = threadIdx.x;
  int row = blockIdx.x;
  int hh = col >> 6, j = col & 63;
  const float* wrow = (row < 128) ? (wq + (size_t)row * 128) : bq;
  float acc = 0.f;
  for (int c = 0; c < 64; ++c) acc += wrow[hh * 64 + c] * we[(size_t)j * 128 + hh * 64 + c];
  if (row < 128) WQE[(size_t)row * 128 + col] = acc;
  else bqe[col] = acc;
}

// fused: [wq|wk|wv|WQE|wsk] -> split bf16 MFMA B-fragments + ball
__global__ void build_wfrag2(const float* __restrict__ wq, const float* __restrict__ wk,
                             const float* __restrict__ wv, const float* __restrict__ WQE,
                             const float* __restrict__ wsk,
                             const float* __restrict__ bq, const float* __restrict__ bk,
                             const float* __restrict__ bv, const float* __restrict__ bqe,
                             const float* __restrict__ bsk,
                             u16* __restrict__ Wfrag_hi, u16* __restrict__ Wfrag_lo,
                             float* __restrict__ ball) {
  int idx = blockIdx.x * 256 + threadIdx.x;  // 81920 total
  if (idx < 81920) {
    int j = idx & 7, lane = (idx >> 3) & 63, rest = idx >> 9;
    int tg = rest % 40, s = rest / 40;
    int k = s * 32 + (lane >> 4) * 8 + j;
    int col = tg * 16 + (lane & 15);
    int sel = col >> 7, c = col & 127;
    const float* src = sel == 0 ? wq : sel == 1 ? wk : sel == 2 ? wv : sel == 3 ? WQE : wsk;
    float w = src[(size_t)k * 128 + c];
    u16 hi = f2b(w);
    Wfrag_hi[idx] = hi;
    Wfrag_lo[idx] = f2b(w - bf2f(hi));
  }
  if (idx < 640) {
    int sel = idx >> 7, c = idx & 127;
    const float* s2 = sel == 0 ? bq : sel == 1 ? bk : sel == 2 ? bv : sel == 3 ? bqe : bsk;
    ball[idx] = s2[c];
  }
}

// we[64x128] -> split bf16 fragments for bd_gemm
__global__ void build_wefrag(const float* __restrict__ we, u16* __restrict__ wef_hi,
                             u16* __restrict__ wef_lo) {
  int idx = blockIdx.x * 256 + threadIdx.x;  // 8192
  if (idx >= 8192) return;
  int j = idx & 7, lane = (idx >> 3) & 63, rest = idx >> 9;
  int t = rest & 3, hh = (rest >> 2) & 1, s = rest >> 3;
  int k = s * 32 + (lane >> 4) * 8 + j;
  int col = hh * 64 + t * 16 + (lane & 15);
  float w = we[(size_t)k * 128 + col];
  u16 hi = f2b(w);
  wef_hi[idx] = hi;
  wef_lo[idx] = f2b(w - bf2f(hi));
}

// up[64x64] f32 -> bf16 fragments
__global__ void build_upfrag(const float* __restrict__ up, u16* __restrict__ upfrag) {
  int idx = blockIdx.x * 256 + threadIdx.x;
  if (idx >= 4096) return;
  int j = idx & 7, lane = (idx >> 3) & 63, st = idx >> 9;
  int s = st >> 2, t = st & 3;
  int k = s * 32 + (lane >> 4) * 8 + j;
  int c = t * 16 + (lane & 15);
  upfrag[idx] = f2b(up[k * 64 + c]);
}

// W2 = up @ re_w [64x128]; bvec = ub @ re_w [128]
__global__ void build_w2(const float* __restrict__ up, const float* __restrict__ ub,
                         const float* __restrict__ re_w, float* __restrict__ W2,
                         float* __restrict__ bvec) {
  int idx = blockIdx.x * 256 + threadIdx.x;
  if (idx < 64 * 128) {
    int k_ = idx >> 7, c = idx & 127;
    float a = 0.f;
    for (int j = 0; j < 64; ++j) a = fmaf(up[k_ * 64 + j], re_w[j * 128 + c], a);
    W2[idx] = a;
  } else if (idx < 64 * 128 + 128) {
    int c = idx - 64 * 128;
    float a = 0.f;
    for (int j = 0; j < 64; ++j) a = fmaf(ub[j], re_w[j * 128 + c], a);
    bvec[c] = a;
  }
}

// ---------------- split-precision MFMA node GEMM ----------------
// nodebuf row layout (u16 idx): q[0..127] | qe[128..255] | kv interleaved [256..511]
__global__ __launch_bounds__(256) void node_gemm(const u16* __restrict__ h_hi,
                                                 const u16* __restrict__ h_lo,
                                                 const u16* __restrict__ Wfrag_hi,
                                                 const u16* __restrict__ Wfrag_lo,
                                                 const float* __restrict__ ball,
                                                 u16* __restrict__ nodebuf,
                                                 float* __restrict__ hn) {
  int tid = threadIdx.x;
  int lane = tid & 63;
  int wv = tid >> 6;
  int cb = blockIdx.x;
  int rbase = blockIdx.y * 64 + wv * 16;
  int rif = lane & 15, kg = lane >> 4;
  f32x4 acc[4] = {};
  int arow = rbase + rif;
  bool rowok = arow < NN;
  const u16* aph = h_hi + (size_t)arow * 128 + kg * 8;
  const u16* apl = h_lo + (size_t)arow * 128 + kg * 8;
#pragma unroll
  for (int s = 0; s < 4; ++s) {
    bf16x8 ah = {}, al = {};
    if (rowok) {
      ah = *reinterpret_cast<const bf16x8*>(aph + s * 32);
      al = *reinterpret_cast<const bf16x8*>(apl + s * 32);
    }
#pragma unroll
    for (int t = 0; t < 4; ++t) {
      size_t fo = ((size_t)((s * 40 + cb * 4 + t) * 64 + lane)) * 8;
      bf16x8 bh = *reinterpret_cast<const bf16x8*>(Wfrag_hi + fo);
      bf16x8 bl = *reinterpret_cast<const bf16x8*>(Wfrag_lo + fo);
      acc[t] = __builtin_amdgcn_mfma_f32_16x16x32_bf16(ah, bh, acc[t], 0, 0, 0);
      acc[t] = __builtin_amdgcn_mfma_f32_16x16x32_bf16(ah, bl, acc[t], 0, 0, 0);
      acc[t] = __builtin_amdgcn_mfma_f32_16x16x32_bf16(al, bh, acc[t], 0, 0, 0);
    }
  }
#pragma unroll
  for (int t = 0; t < 4; ++t) {
    int col = (cb * 4 + t) * 16 + rif;
    float bia = ball[col];
#pragma unroll
    for (int rg = 0; rg < 4; ++rg) {
      int row = rbase + kg * 4 + rg;
      if (row < NN) {
        float val = acc[t][rg] + bia;
        if (col < 512) {
          int idx;
          if (col < 128) idx = col;
          else if (col < 256) { int c1 = col - 128; idx = 256 + ((c1 >> 1) << 2) + (c1 & 1); }
          else if (col < 384) { int c2 = col - 256; idx = 256 + ((c2 >> 1) << 2) + 2 + (c2 & 1); }
          else idx = 128 + (col - 384);
          nodebuf[(size_t)row * 512 + idx] = f2b(val);
        } else {
          hn[(size_t)row * 128 + col - 512] = val;
        }
      }
    }
  }
}

// ---------------- MFMA edge GEMM: ea = elu(ea @ up + ub), in place ----------------
__global__ __launch_bounds__(256) void edge_gemm(u16* __restrict__ ea,
                                                 const u16* __restrict__ upfrag,
                                                 const float* __restrict__ ub) {
  int lane = threadIdx.x & 63;
  int gwave = (blockIdx.x * 256 + threadIdx.x) >> 6;
  int nwaves = (gridDim.x * 256) >> 6;
  bf16x8 bfrag[2][4];
#pragma unroll
  for (int s = 0; s < 2; ++s)
#pragma unroll
    for (int t = 0; t < 4; ++t)
      bfrag[s][t] = *reinterpret_cast<const bf16x8*>(upfrag + ((size_t)((s * 4 + t) * 64 + lane)) * 8);
  float bias_c[4];
#pragma unroll
  for (int t = 0; t < 4; ++t) bias_c[t] = ub[t * 16 + (lane & 15)];
  const int rif = lane & 15;
  const int kg = lane >> 4;
  for (int mt = gwave; mt < EE / 16; mt += nwaves) {
    size_t rowbase = (size_t)mt * 16;
    const u16* arow = ea + (rowbase + rif) * 64;
    bf16x8 a0 = *reinterpret_cast<const bf16x8*>(arow + kg * 8);
    bf16x8 a1 = *reinterpret_cast<const bf16x8*>(arow + 32 + kg * 8);
    f32x4 acc[4] = {};
#pragma unroll
    for (int t = 0; t < 4; ++t) {
      acc[t] = __builtin_amdgcn_mfma_f32_16x16x32_bf16(a0, bfrag[0][t], acc[t], 0, 0, 0);
      acc[t] = __builtin_amdgcn_mfma_f32_16x16x32_bf16(a1, bfrag[1][t], acc[t], 0, 0, 0);
    }
#pragma unroll
    for (int t = 0; t < 4; ++t)
#pragma unroll
      for (int rg = 0; rg < 4; ++rg) {
        float val = acc[t][rg] + bias_c[t];
        ea[(rowbase + kg * 4 + rg) * 64 + t * 16 + rif] = f2b(elu_f(val));
      }
  }
}

// ---------------- split-precision MFMA BD GEMM: hn += r @ BD (per-head we) ----------------
__global__ __launch_bounds__(256) void bd_gemm(const u16* __restrict__ r_hi,
                                               const u16* __restrict__ r_lo,
                                               const u16* __restrict__ wef_hi,
                                               const u16* __restrict__ wef_lo,
                                               float* __restrict__ hn) {
  int tid = threadIdx.x;
  int lane = tid & 63;
  int w = blockIdx.x * 4 + (tid >> 6);
  if (w >= NN / 16) return;
  int rif = lane & 15, kg = lane >> 4;
  size_t rowbase = (size_t)w * 16;
  const u16* ahb = r_hi + (rowbase + rif) * 128;
  const u16* alb = r_lo + (rowbase + rif) * 128;
  f32x4 acc[2][4] = {};
#pragma unroll
  for (int hh = 0; hh < 2; ++hh)
#pragma unroll
    for (int s = 0; s < 2; ++s) {
      int ko = hh * 64 + s * 32 + kg * 8;
      bf16x8 ah = *reinterpret_cast<const bf16x8*>(ahb + ko);
      bf16x8 al = *reinterpret_cast<const bf16x8*>(alb + ko);
#pragma unroll
      for (int t = 0; t < 4; ++t) {
        size_t fo = ((size_t)((((s * 2 + hh) * 4 + t)) * 64 + lane)) * 8;
        bf16x8 bh = *reinterpret_cast<const bf16x8*>(wef_hi + fo);
        bf16x8 bl = *reinterpret_cast<const bf16x8*>(wef_lo + fo);
        acc[hh][t] = __builtin_amdgcn_mfma_f32_16x16x32_bf16(ah, bh, acc[hh][t], 0, 0, 0);
        acc[hh][t] = __builtin_amdgcn_mfma_f32_16x16x32_bf16(ah, bl, acc[hh][t], 0, 0, 0);
        acc[hh][t] = __builtin_amdgcn_mfma_f32_16x16x32_bf16(al, bh, acc[hh][t], 0, 0, 0);
      }
    }
#pragma unroll
  for (int hh = 0; hh < 2; ++hh)
#pragma unroll
    for (int t = 0; t < 4; ++t)
#pragma unroll
      for (int rg = 0; rg < 4; ++rg) {
        size_t row = rowbase + kg * 4 + rg;
        int col = hh * 64 + t * 16 + rif;
        hn[row * 128 + col] += acc[hh][t][rg];
      }
}

// per-src-graph sum of current ea rows, chunked + atomic merge
__global__ __launch_bounds__(256) void gsum_pre(const u16* __restrict__ ea,
                                                const int* __restrict__ sg_start,
                                                const int* __restrict__ sg_perm,
                                                float* __restrict__ gsum_in) {
  __shared__ float red[8][64];
  int g = blockIdx.x, t = threadIdx.x;
  int c2 = t & 31;
  int rgrp = t >> 5;
  int gr = blockIdx.y * 8 + rgrp;
  int p0 = sg_start[g], p1 = sg_start[g + 1];
  float slo = 0.f, shi = 0.f;
  for (int i = p0 + gr; i < p1; i += 128) {
    int pos = sg_perm[i];
    u32 w = ((const u32*)ea)[(size_t)pos * 32 + c2];
    slo += lo2f(w);
    shi += hi2f(w);
  }
  red[rgrp][c2 * 2] = slo;
  red[rgrp][c2 * 2 + 1] = shi;
  __syncthreads();
  if (t < 64) {
    float a = 0.f;
#pragma unroll
    for (int rr = 0; rr < 8; ++rr) a += red[rr][t];
    atomicAdd(&gsum_in[(size_t)g * 64 + t], a);
  }
}

// embE = elu(gsum_in @ W2 + cnt*bvec + re_b)
__global__ void emb_e_kernel(const float* __restrict__ gsum_in, const int* __restrict__ sg_start,
                             const float* __restrict__ W2, const float* __restrict__ bvec,
                             const float* __restrict__ re_b, float* __restrict__ embE) {
  int g = blockIdx.x, c = threadIdx.x;
  float cnt = (float)(sg_start[g + 1] - sg_start[g]);
  float a = re_b[c] + cnt * bvec[c];
  for (int k_ = 0; k_ < 64; ++k_) a = fmaf(gsum_in[(size_t)g * 64 + k_], W2[k_ * 128 + c], a);
  embE[(size_t)g * 128 + c] = elu_f(a);
}

// ---------------- fused flash attention, one wave per dst node, dual chains ----------------
__global__ __launch_bounds__(256) void attn_node(const u32* __restrict__ nodebuf,
                                                 const u16* __restrict__ ea,
                                                 const int* __restrict__ row_start,
                                                 const int* __restrict__ csr_src,
                                                 float* __restrict__ hn,
                                                 u32* __restrict__ r_hi,
                                                 u32* __restrict__ r_lo) {
  int d = (blockIdx.x * blockDim.x + threadIdx.x) >> 6;
  if (d >= NN) return;
  int lane = threadIdx.x & 63;
  int p0 = row_start[d], p1 = row_start[d + 1];
  if (p0 == p1) {
    r_hi[(size_t)d * 64 + lane] = 0u;
    r_lo[(size_t)d * 64 + lane] = 0u;
    return;
  }
  int cnt = p1 - p0;
  size_t dbase = (size_t)d * 256;
  u32 qv = nodebuf[dbase + lane];
  u32 qev = nodebuf[dbase + 64 + lane];
  const int lea = lane & 31;
  float mA = -3.4e38f, sA = 0.f, a0A = 0.f, a1A = 0.f, r0A = 0.f, r1A = 0.f;
  float mB = -3.4e38f, sB = 0.f, a0B = 0.f, a1B = 0.f, r0B = 0.f, r1B = 0.f;
  int sa = csr_src[p0];
  uint2 kvA = *((const uint2*)(nodebuf + (size_t)sa * 256 + 128) + lane);
  u32 eaA = ((const u32*)ea)[(size_t)p0 * 32 + lea];
  int pB0 = (cnt > 1) ? p0 + 1 : p0;
  int sb = csr_src[pB0];
  uint2 kvB = *((const uint2*)(nodebuf + (size_t)sb * 256 + 128) + lane);
  u32 eaB = ((const u32*)ea)[(size_t)pB0 * 32 + lea];
  for (int i = 0; i < cnt; i += 2) {
    int ni = i + 2;
    int nA = (ni < cnt) ? p0 + ni : p0;
    int nB = (ni + 1 < cnt) ? p0 + ni + 1 : p0;
    int sa2 = csr_src[nA];
    uint2 kvA2 = *((const uint2*)(nodebuf + (size_t)sa2 * 256 + 128) + lane);
    u32 eaA2 = ((const u32*)ea)[(size_t)nA * 32 + lea];
    int sb2 = csr_src[nB];
    uint2 kvB2 = *((const uint2*)(nodebuf + (size_t)sb2 * 256 + 128) + lane);
    u32 eaB2 = ((const u32*)ea)[(size_t)nB * 32 + lea];
    float pA = lo2f(qv) * lo2f(kvA.x) + hi2f(qv) * hi2f(kvA.x) +
               lo2f(qev) * lo2f(eaA) + hi2f(qev) * hi2f(eaA);
    float pB = lo2f(qv) * lo2f(kvB.x) + hi2f(qv) * hi2f(kvB.x) +
               lo2f(qev) * lo2f(eaB) + hi2f(qev) * hi2f(eaB);
#pragma unroll
    for (int mm = 16; mm; mm >>= 1) {
      pA += __shfl_xor(pA, mm, 64);
      pB += __shfl_xor(pB, mm, 64);
    }
    {
      float l = pA * 0.125f;
      float mn = fmaxf(mA, l);
      float f = __expf(mA - mn), w = __expf(l - mn);
      sA = sA * f + w;
      a0A = a0A * f + w * lo2f(kvA.y); a1A = a1A * f + w * hi2f(kvA.y);
      r0A = r0A * f + w * lo2f(eaA);   r1A = r1A * f + w * hi2f(eaA);
      mA = mn;
    }
    if (i + 1 < cnt) {
      float l = pB * 0.125f;
      float mn = fmaxf(mB, l);
      float f = __expf(mB - mn), w = __expf(l - mn);
      sB = sB * f + w;
      a0B = a0B * f + w * lo2f(kvB.y); a1B = a1B * f + w * hi2f(kvB.y);
      r0B = r0B * f + w * lo2f(eaB);   r1B = r1B * f + w * hi2f(eaB);
      mB = mn;
    }
    kvA = kvA2; eaA = eaA2; kvB = kvB2; eaB = eaB2;
  }
  float mn = fmaxf(mA, mB);
  float fA = __expf(mA - mn);
  float fB = (cnt > 1) ? __expf(mB - mn) : 0.f;
  float ssum = sA * fA + sB * fB;
  float a0 = a0A * fA + a0B * fB, a1 = a1A * fA + a1B * fB;
  float r0 = r0A * fA + r0B * fB, r1 = r1A * fA + r1B * fB;
  float inv = 1.f / ssum;
  size_t ob = (size_t)d * 128 + lane * 2;
  hn[ob] += a0 * inv;
  hn[ob + 1] += a1 * inv;
  float rv0 = r0 * inv, rv1 = r1 * inv;
  u16 h0 = f2b(rv0), h1 = f2b(rv1);
  r_hi[(size_t)d * 64 + lane] = (u32)h0 | ((u32)h1 << 16);
  r_lo[(size_t)d * 64 + lane] = (u32)f2b(rv0 - bf2f(h0)) | ((u32)f2b(rv1 - bf2f(h1)) << 16);
}

// ---------------- SAG pooling ----------------
__global__ __launch_bounds__(256) void node_dots(const float* __restrict__ hn,
                                                 const float* __restrict__ wrel,
                                                 const float* __restrict__ wroot,
                                                 float* __restrict__ hrel,
                                                 float* __restrict__ troot) {
  int n = (blockIdx.x * blockDim.x + threadIdx.x) >> 6;
  if (n >= NN) return;
  int lane = threadIdx.x & 63;
  float x0 = hn[(size_t)n * 128 + lane], x1 = hn[(size_t)n * 128 + 64 + lane];
  float tr = wred64(x0 * wrel[lane] + x1 * wrel[64 + lane]);
  float tt = wred64(x0 * wroot[lane] + x1 * wroot[64 + lane]);
  if (lane == 0) { hrel[n] = tr; troot[n] = tt; }
}

__global__ __launch_bounds__(256) void sag_gather(const float* __restrict__ hrel,
                                                  const float* __restrict__ troot,
                                                  const float* __restrict__ brel,
                                                  const int* __restrict__ row_start,
                                                  const int* __restrict__ csr_src,
                                                  const int* __restrict__ batch,
                                                  float* __restrict__ sc, unsigned* __restrict__ gm) {
  int n = blockIdx.x * blockDim.x + threadIdx.x;
  if (n >= NN) return;
  float s = 0.f;
  int p1 = row_start[n + 1];
  for (int pos = row_start[n]; pos < p1; ++pos) s += hrel[csr_src[pos]];
  float v = s + troot[n] + brel[0];
  sc[n] = v;
  atomicMax(&gm[batch[n]], fenc(v));
}

__global__ __launch_bounds__(256) void sag_exp(const float* __restrict__ sc,
                                               const int* __restrict__ batch,
                                               const unsigned* __restrict__ gm,
                                               float* __restrict__ gs, float* __restrict__ scp) {
  int n = blockIdx.x * blockDim.x + threadIdx.x;
  if (n >= NN) return;
  int g = batch[n];
  float p = __expf(sc[n] - fdec(gm[g]));
  scp[n] = p;
  atomicAdd(&gs[g], p);
}

__global__ void emb_block(const float* __restrict__ hn, const float* __restrict__ scp,
                          const float* __restrict__ gs, const int* __restrict__ gstart,
                          const float* __restrict__ embE, float* __restrict__ dstv) {
  __shared__ float part[2];
  int g = blockIdx.x, c = threadIdx.x;
  int n0 = gstart[g], n1 = gstart[g + 1];
  float invg = 1.f / gs[g];
  float acc = 0.f;
  for (int n = n0; n < n1; ++n) acc = fmaf(hn[(size_t)n * 128 + c], scp[n] * invg, acc);
  float val = acc * embE[(size_t)g * 128 + c];
  float sq = val * val;
#pragma unroll
  for (int mm = 32; mm; mm >>= 1) sq += __shfl_xor(sq, mm, 64);
  if ((c & 63) == 0) part[c >> 6] = sq;
  __syncthreads();
  float nrm = sqrtf(part[0] + part[1]);
  dstv[(size_t)g * 128 + c] = elu_f(val / fmaxf(nrm, 1e-12f));
}

__global__ void final_combine(const float* __restrict__ e0, const float* __restrict__ e1,
                              float* __restrict__ out) {
  int idx = blockIdx.x * blockDim.x + threadIdx.x;
  if (idx >= GG * 128) return;
  out[idx] = 0.6f * e0[idx] + 0.4f * e1[idx];
}

// =====================================================================
extern "C" void kernel_launch(void* const* d_in, const int* in_sizes, int n_in,
                              void* d_out, int out_size, void* d_ws, size_t ws_size,
                              hipStream_t stream) {
  const float* x = (const float*)d_in[0];
  const float* edge_attr = (const float*)d_in[1];
  const int* edge_index = (const int*)d_in[2];
  const int* batch = (const int*)d_in[3];
  const float* w0 = (const float*)d_in[4];
  const float* b0 = (const float*)d_in[5];
  const float* we0 = (const float*)d_in[6];
  const float* be0 = (const float*)d_in[7];
  const float* ln0_g = (const float*)d_in[8];
  const float* ln0_b = (const float*)d_in[9];
  const float* qkv_w = (const float*)d_in[10];
  const float* qkv_b = (const float*)d_in[11];
  const float* edge_w = (const float*)d_in[12];
  const float* skip_w = (const float*)d_in[13];
  const float* skip_b = (const float*)d_in[14];
  const float* up_w = (const float*)d_in[15];
  const float* up_b = (const float*)d_in[16];
  const float* ng = (const float*)d_in[17];
  const float* nbeta = (const float*)d_in[18];
  const float* sag_wrel = (const float*)d_in[19];
  const float* sag_brel = (const float*)d_in[20];
  const float* sag_wroot = (const float*)d_in[21];
  const float* re_w = (const float*)d_in[22];
  const float* re_b = (const float*)d_in[23];
  const int* srcp = edge_index;
  const int* dstp = edge_index + EE;
  float* out = (float*)d_out;
  (void)in_sizes; (void)n_in;

  float* ws = (float*)d_ws;
  size_t o = 0;
  auto alloc = [&](size_t n) { n = (n + 3) & ~(size_t)3; float* p = ws + o; o += n; return p; };
  u16* h_hi = (u16*)alloc((size_t)NN * 64);
  u16* h_lo = (u16*)alloc((size_t)NN * 64);
  float* hn = alloc((size_t)NN * 128);
  u32* r_hi = (u32*)alloc((size_t)NN * 64);
  u32* r_lo = (u32*)alloc((size_t)NN * 64);
  u16* nodebuf = (u16*)alloc((size_t)NN * 256);   // NN x 512 bf16 (q|qe|kv)
  u16* ea = (u16*)alloc((size_t)EE * 32);         // EE x 64 bf16, dst-CSR order
  int* csr_src = (int*)alloc(EE);
  int* epos = (int*)alloc(EE);
  int* deg = (int*)alloc(NN);
  int* pre = (int*)alloc(NN);
  int* bsum = (int*)alloc(256);
  int* row_start = (int*)alloc(NN + 1);
  int* cursor = (int*)alloc(NN);
  int* out_start = (int*)alloc(NN + 1);
  int* gstart = (int*)alloc(GG + 1);
  int* sg_perm = (int*)alloc(EE);
  int* sg_start = (int*)alloc(GG + 1);
  float* gsum_in = alloc(GG * 64);
  float* W2 = alloc(64 * 128);
  float* bvec = alloc(128);
  u16* upfrag = (u16*)alloc(2048);
  u16* Wfrag_hi = (u16*)alloc(40960);
  u16* Wfrag_lo = (u16*)alloc(40960);
  u16* wef_hi = (u16*)alloc(4096);
  u16* wef_lo = (u16*)alloc(4096);
  u16* wef0_hi = (u16*)alloc(1024);
  u16* wef0_lo = (u16*)alloc(1024);
  unsigned* gm = (unsigned*)alloc(GG);            // zero-block (gm, gs)
  float* gs = alloc(GG);
  float* gmean = alloc(GG);
  float* grstd = alloc(GG);
  float* WQE = alloc(128 * 128);
  float* bqe = alloc(128);
  float* ball = alloc(640);
  float* hrel = alloc(NN);
  float* troot = alloc(NN);
  float* sc = alloc(NN);
  float* scp = alloc(NN);
  float* embE = alloc(GG * 128);
  float* embs0 = alloc(GG * 128);
  float* embs1 = alloc(GG * 128);

  const size_t need = o * sizeof(float);
  if (ws_size < need) {
    hipMemsetAsync(d_out, 0, (size_t)out_size * sizeof(float), stream);
    return;
  }
  const int NSCAN = (NN + 255) / 256;  // 196

  auto gemm = [&](const float* A, const float* B, const float* bias, float* C,
                  int M, int Nn, int K, int act, int accum) {
    dim3 g((Nn + 63) / 64, (M + 63) / 64);
    gemm_kernel<<<g, 256, 0, stream>>>(A, B, bias, C, M, Nn, K, act, accum);
  };
  auto ex_scan = [&](const int* degp, int* startp, int* curp) {
    scan1<<<NSCAN, 256, 0, stream>>>(degp, pre, bsum, NN);
    scan2<<<1, 256, 0, stream>>>(bsum, NSCAN);
    scan3<<<NSCAN, 256, 0, stream>>>(pre, bsum, degp, startp, curp, NN);
  };
  auto graph_ln = [&](const float* in, const float* gamma, const float* beta) {
    ln_stats_block<<<GG, 256, 0, stream>>>(in, gstart, gmean, grstd);
    ln_apply<<<NN * 32 / 256, 256, 0, stream>>>(in, h_hi, h_lo, batch, gmean, grstd, gamma, beta);
  };
  auto tconv = [&](int il) {
    const float* wq = qkv_w + (size_t)(il * 3 + 0) * 128 * 128;
    const float* wk = qkv_w + (size_t)(il * 3 + 1) * 128 * 128;
    const float* wv = qkv_w + (size_t)(il * 3 + 2) * 128 * 128;
    const float* bq = qkv_b + (il * 3 + 0) * 128;
    const float* bk = qkv_b + (il * 3 + 1) * 128;
    const float* bv = qkv_b + (il * 3 + 2) * 128;
    const float* we = edge_w + (size_t)il * 64 * 128;
    const float* wsk = skip_w + (size_t)il * 128 * 128;
    const float* bsk = skip_b + il * 128;
    build_wqe<<<129, 128, 0, stream>>>(wq, bq, we, WQE, bqe);
    build_wfrag2<<<320, 256, 0, stream>>>(wq, wk, wv, WQE, wsk, bq, bk, bv, bqe, bsk,
                                          Wfrag_hi, Wfrag_lo, ball);
    build_wefrag<<<32, 256, 0, stream>>>(we, wef_hi, wef_lo);
    dim3 ng2(10, (NN + 63) / 64);
    node_gemm<<<ng2, 256, 0, stream>>>(h_hi, h_lo, Wfrag_hi, Wfrag_lo, ball, nodebuf, hn);
    attn_node<<<NN / 4, 256, 0, stream>>>((const u32*)nodebuf, ea, row_start, csr_src, hn,
                                          r_hi, r_lo);
    bd_gemm<<<(NN / 16 + 3) / 4, 256, 0, stream>>>((const u16*)r_hi, (const u16*)r_lo,
                                                   wef_hi, wef_lo, hn);
  };
  auto ea_mlp = [&](int il) {
    build_upfrag<<<16, 256, 0, stream>>>(up_w + (size_t)il * 4096, upfrag);
    edge_gemm<<<2048, 256, 0, stream>>>(ea, upfrag, up_b + il * 64);
  };

  // one-time topology structures
  hipMemsetAsync(deg, 0, NN * sizeof(int), stream);
  csr_hist<<<(EE + 255) / 256, 256, 0, stream>>>(dstp, deg);
  ex_scan(deg, row_start, cursor);
  gstart_build<<<(NN + 256) / 256, 256, 0, stream>>>(batch, gstart);
  csr_pos<<<(EE + 255) / 256, 256, 0, stream>>>(srcp, dstp, cursor, csr_src, epos);
  build_we0frag<<<8, 256, 0, stream>>>(we0, wef0_hi, wef0_lo);
  ea_enc_mfma<<<2048, 256, 0, stream>>>(edge_attr, wef0_hi, wef0_lo, be0, epos, ea);
  hipMemsetAsync(deg, 0, NN * sizeof(int), stream);
  out_hist<<<(EE + 255) / 256, 256, 0, stream>>>(csr_src, deg);
  ex_scan(deg, out_start, cursor);
  out_fill<<<(EE + 255) / 256, 256, 0, stream>>>(csr_src, cursor, sg_perm);
  sgstart_build<<<2, 256, 0, stream>>>(out_start, gstart, sg_start);
  // node encoder + first LN
  gemm(x, w0, b0, hn, NN, 128, 64, 0, 0);
  graph_ln(hn, ln0_g, ln0_b);

  for (int i = 0; i < 2; ++i) {
    tconv(i * 2 + 0);
    graph_ln(hn, ng + (i * 2) * 128, nbeta + (i * 2) * 128);
    ea_mlp(i * 2);
    tconv(i * 2 + 1);
    // SAG pooling on pre-LN conv2 output hn; edge emb via linearity
    hipMemsetAsync(gm, 0, 2 * GG * sizeof(float), stream);       // gm, gs
    hipMemsetAsync(gsum_in, 0, GG * 64 * sizeof(float), stream);
    dim3 gsg(GG, 16);
    gsum_pre<<<gsg, 256, 0, stream>>>(ea, sg_start, sg_perm, gsum_in);
    build_w2<<<33, 256, 0, stream>>>(up_w + (size_t)(i * 2 + 1) * 4096,
                                     up_b + (i * 2 + 1) * 64,
                                     re_w + (size_t)i * 64 * 128, W2, bvec);
    if (i == 0) ea_mlp(i * 2 + 1);  // ea after last SAG is never consumed
    node_dots<<<NN / 4, 256, 0, stream>>>(hn, sag_wrel + i * 128, sag_wroot + i * 128, hrel, troot);
    sag_gather<<<(NN + 255) / 256, 256, 0, stream>>>(hrel, troot, sag_brel + i, row_start,
                                                     csr_src, batch, sc, gm);
    sag_exp<<<(NN + 255) / 256, 256, 0, stream>>>(sc, batch, gm, gs, scp);
    emb_e_kernel<<<GG, 128, 0, stream>>>(gsum_in, sg_start, W2, bvec, re_b + i * 128, embE);
    emb_block<<<GG, 128, 0, stream>>>(hn, scp, gs, gstart, embE, i == 0 ? embs0 : embs1);
    if (i == 0) graph_ln(hn, ng + (i * 2 + 1) * 128, nbeta + (i * 2 + 1) * 128);  // last LN is dead work
  }
  final_combine<<<GG * 128 / 256, 256, 0, stream>>>(embs0, embs1, out);
}